// Round 1
// baseline (1639.314 us; speedup 1.0000x reference)
//
#include <hip/hip_runtime.h>
#include <math.h>

// ---------------------------------------------------------------------------
// Hyperbolic GCN forward. Wave(64)-per-row layout: lane holds ambient dims
// (2*lane, 2*lane+1); dim 0 is the time component.
// ---------------------------------------------------------------------------

__device__ __forceinline__ float wsum(float x){
  x += __shfl_xor(x, 32);
  x += __shfl_xor(x, 16);
  x += __shfl_xor(x, 8);
  x += __shfl_xor(x, 4);
  x += __shfl_xor(x, 2);
  x += __shfl_xor(x, 1);
  return x;
}

__device__ __forceinline__ void get_c(const float* rc, float& K, float& sK){
  float c = log1pf(expf(rc[0])) + 1e-5f;   // softplus(raw_c) + 1e-5
  K  = 1.0f / c;
  sK = sqrtf(K);
}

// proj(expmap0(u)) for 128-dim ambient vectors; comp0 of u is ignored.
__device__ __forceinline__ float2 hexpmap0(float2 u, int lane, float K, float sK){
  float sx  = lane ? u.x : 0.0f;
  float xn2 = wsum(sx*sx + u.y*u.y);
  float xn  = fmaxf(sqrtf(xn2), 1e-15f);
  float th  = xn / sK;
  float s   = sK * sinhf(th) / xn;
  float rx  = sx * s, ry = u.y * s;
  float rn2 = wsum(rx*rx + ry*ry);
  float p0  = sqrtf(fmaxf(K + rn2, 1e-7f));      // proj recomputes comp0
  return make_float2(lane ? rx : p0, ry);
}

__device__ __forceinline__ float2 hlogmap0(float2 p, int lane, float K, float sK){
  float p0  = __shfl(p.x, 0);
  float sx  = lane ? p.x : 0.0f;
  float yn2 = wsum(sx*sx + p.y*p.y);
  float yn  = fmaxf(sqrtf(yn2), 1e-15f);
  float th  = fmaxf(p0 / sK, 1.0f + 1e-7f);
  float r   = sK * acoshf(th) / yn;
  return make_float2(lane ? sx*r : 0.0f, p.y * r);
}

// mobius_add(p, bias) where u = logmap0(bias point) is precomputed (u0 == 0).
__device__ __forceinline__ float2 hmobius_add_u(float2 p, float2 u, int lane, float K, float sK){
  float p0  = __shfl(p.x, 0);
  float sx  = lane ? p.x : 0.0f;
  float yn2 = wsum(sx*sx + p.y*p.y);
  float yn  = fmaxf(sqrtf(yn2), 1e-15f);
  float inv = 1.0f / yn;
  float yhx = sx * inv, yhy = p.y * inv;
  float ux  = lane ? u.x : 0.0f;
  float alpha = wsum(yhx*ux + yhy*u.y) / sK;
  float coef  = alpha * (sK - p0);
  float wx = ux  - coef * yhx;                 // lane0 -> 0 naturally
  float wy = u.y - coef * yhy;
  // proj_tan: replace comp0
  float pdw = wsum(sx*wx + p.y*wy);
  float w0  = pdw / fmaxf(p0, 1e-7f);
  // expmap(w, p)
  float spsq  = wsum(wx*wx + wy*wy);
  float md    = spsq - w0*w0;                  // minkowski dot
  float normu = fminf(sqrtf(fmaxf(md, 1e-7f)), 1e6f);
  float th    = fmaxf(normu / sK, 1e-15f);
  float ch    = coshf(th);
  float sd    = sinhf(th) / th;
  float rx = ch*p.x + sd*(lane ? wx : w0);
  float ry = ch*p.y + sd*wy;
  // proj
  float rsx = lane ? rx : 0.0f;
  float rn2 = wsum(rsx*rsx + ry*ry);
  float r0  = sqrtf(fmaxf(K + rn2, 1e-7f));
  return make_float2(lane ? rx : r0, ry);
}

// --------------------------- bias prep -------------------------------------
// u_b = logmap0(proj(expmap0(proj_tan0(b)))) for the three biases.
__global__ void bias_prep(const float* __restrict__ b0, const float* __restrict__ b1,
                          const float* __restrict__ b2, float* __restrict__ ubias,
                          const float* __restrict__ raw_c){
  int lane = threadIdx.x;  // 64 threads
  float K, sK; get_c(raw_c, K, sK);
  const float* bs[3] = {b0, b1, b2};
  for (int k = 0; k < 3; ++k){
    float2 u = make_float2(bs[k][2*lane], bs[k][2*lane+1]);
    float2 p = hexpmap0(u, lane, K, sK);      // masks comp0 == proj_tan0
    float2 L = hlogmap0(p, lane, K, sK);
    *(float2*)&ubias[k*128 + 2*lane] = L;
  }
}

// --------------------------- stage A ---------------------------------------
// L[n,j] = spatial logmap0(proj(expmap0(proj_tan0(A1[n])))) , j in 0..127
// corresponds to ambient col j+1 of the 129-dim point.
__global__ __launch_bounds__(256) void stage_a(const float* __restrict__ A1,
                                               float* __restrict__ L,
                                               const float* __restrict__ raw_c, int n){
  int row  = (int)((blockIdx.x * blockDim.x + threadIdx.x) >> 6);
  int lane = threadIdx.x & 63;
  if (row >= n) return;
  float K, sK; get_c(raw_c, K, sK);
  const float* rp = A1 + (size_t)row * 129;
  float x0 = rp[1 + 2*lane];
  float x1 = rp[2 + 2*lane];
  float xn2 = wsum(x0*x0 + x1*x1);
  float xn  = fmaxf(sqrtf(xn2), 1e-15f);
  float th  = xn / sK;
  float s   = sK * sinhf(th) / xn;
  float rx = x0*s, ry = x1*s;
  float rn2 = wsum(rx*rx + ry*ry);
  float a0  = sqrtf(fmaxf(K + rn2, 1e-7f));
  float yn  = fmaxf(sqrtf(rn2), 1e-15f);
  float th2 = fmaxf(a0 / sK, 1.0f + 1e-7f);
  float r   = sK * acoshf(th2) / yn;
  *(float2*)&L[(size_t)row*128 + 2*lane] = make_float2(rx*r, ry*r);
}

// --------------------------- GEMM  C = A(N,128) @ W(128,128) ---------------
__global__ __launch_bounds__(256) void gemm128(const float* __restrict__ A,
                                               const float* __restrict__ W,
                                               float* __restrict__ C, int nrows){
  __shared__ float Wl[128*128];
  int tid = threadIdx.x;
  {
    const float4* W4 = (const float4*)W;
    float4* L4 = (float4*)Wl;
    #pragma unroll
    for (int i = 0; i < 16; ++i) L4[tid + 256*i] = W4[tid + 256*i];
  }
  __syncthreads();
  int cg = tid & 31, rg = tid >> 5;
  int c0 = cg * 4;
  int rbase = blockIdx.x * 64 + rg * 8;
  float acc[8][4];
  #pragma unroll
  for (int i = 0; i < 8; ++i){ acc[i][0]=0.f; acc[i][1]=0.f; acc[i][2]=0.f; acc[i][3]=0.f; }
  for (int k = 0; k < 128; k += 4){
    float4 w0 = *(const float4*)&Wl[(k+0)*128 + c0];
    float4 w1 = *(const float4*)&Wl[(k+1)*128 + c0];
    float4 w2 = *(const float4*)&Wl[(k+2)*128 + c0];
    float4 w3 = *(const float4*)&Wl[(k+3)*128 + c0];
    #pragma unroll
    for (int i = 0; i < 8; ++i){
      int r = rbase + i;
      if (r < nrows){
        float4 a = *(const float4*)&A[(size_t)r*128 + k];
        acc[i][0] = fmaf(a.x,w0.x,fmaf(a.y,w1.x,fmaf(a.z,w2.x,fmaf(a.w,w3.x,acc[i][0]))));
        acc[i][1] = fmaf(a.x,w0.y,fmaf(a.y,w1.y,fmaf(a.z,w2.y,fmaf(a.w,w3.y,acc[i][1]))));
        acc[i][2] = fmaf(a.x,w0.z,fmaf(a.y,w1.z,fmaf(a.z,w2.z,fmaf(a.w,w3.z,acc[i][2]))));
        acc[i][3] = fmaf(a.x,w0.w,fmaf(a.y,w1.w,fmaf(a.z,w2.w,fmaf(a.w,w3.w,acc[i][3]))));
      }
    }
  }
  #pragma unroll
  for (int i = 0; i < 8; ++i){
    int r = rbase + i;
    if (r < nrows){
      *(float4*)&C[(size_t)r*128 + c0] = make_float4(acc[i][0],acc[i][1],acc[i][2],acc[i][3]);
    }
  }
}

// --------------------------- stage C ---------------------------------------
// From T1 row: a1 = mobius_add(proj(expmap0(T1)), bias_lin1); loga1 = logmap0(a1)
// From Tg1 row: h1 = logmap0(mobius_add(proj(expmap0(Tg1)), bias_gc1))
__global__ __launch_bounds__(256) void stage_c(const float* __restrict__ T1,
                                               const float* __restrict__ Tg1,
                                               const float* __restrict__ ubias,
                                               float* __restrict__ loga1,
                                               float* __restrict__ h1,
                                               const float* __restrict__ raw_c, int n){
  int row  = (int)((blockIdx.x * blockDim.x + threadIdx.x) >> 6);
  int lane = threadIdx.x & 63;
  if (row >= n) return;
  float K, sK; get_c(raw_c, K, sK);
  size_t base = (size_t)row*128 + 2*lane;
  float2 ul = *(const float2*)&ubias[2*lane];
  float2 ug = *(const float2*)&ubias[128 + 2*lane];

  float2 t1 = *(const float2*)&T1[base];
  float2 p  = hexpmap0(t1, lane, K, sK);
  float2 a1 = hmobius_add_u(p, ul, lane, K, sK);
  float2 la = hlogmap0(a1, lane, K, sK);
  *(float2*)&loga1[base] = la;

  float2 tg = *(const float2*)&Tg1[base];
  float2 pg = hexpmap0(tg, lane, K, sK);
  float2 g  = hmobius_add_u(pg, ug, lane, K, sK);
  float2 hh = hlogmap0(g, lane, K, sK);
  *(float2*)&h1[base] = hh;
}

// --------------------------- CSR build -------------------------------------
__global__ void hist_k(const int* __restrict__ rows, int* __restrict__ cnt, int e){
  int i = blockIdx.x * blockDim.x + threadIdx.x;
  if (i < e) atomicAdd(&cnt[rows[i]], 1);
}

#define SCAN_ITEMS 4
__global__ __launch_bounds__(256) void scan1(const int* __restrict__ cnt,
                                             int* __restrict__ off,
                                             int* __restrict__ bsum, int n){
  __shared__ int sh[256];
  int tid = threadIdx.x;
  int base = blockIdx.x * 256 * SCAN_ITEMS + tid * SCAN_ITEMS;
  int v[SCAN_ITEMS]; int s = 0;
  #pragma unroll
  for (int i = 0; i < SCAN_ITEMS; ++i){ int idx = base+i; v[i] = (idx < n) ? cnt[idx] : 0; s += v[i]; }
  sh[tid] = s; __syncthreads();
  for (int o = 1; o < 256; o <<= 1){
    int t = (tid >= o) ? sh[tid - o] : 0; __syncthreads();
    sh[tid] += t; __syncthreads();
  }
  int excl = sh[tid] - s;
  if (tid == 255) bsum[blockIdx.x] = sh[tid];
  int run = excl;
  #pragma unroll
  for (int i = 0; i < SCAN_ITEMS; ++i){ int idx = base+i; if (idx < n) off[idx] = run; run += v[i]; }
}

__global__ void scan2(int* bsum, int G){
  if (threadIdx.x == 0 && blockIdx.x == 0){
    int run = 0;
    for (int i = 0; i < G; ++i){ int t = bsum[i]; bsum[i] = run; run += t; }
  }
}

__global__ void scan3(int* __restrict__ off, int* __restrict__ cursor,
                      const int* __restrict__ bsum, int n){
  int i = blockIdx.x * blockDim.x + threadIdx.x;
  if (i < n){ int o = off[i] + bsum[i / (256*SCAN_ITEMS)]; off[i] = o; cursor[i] = o; }
}

__global__ void fill_k(const int* __restrict__ rows, const int* __restrict__ cols,
                       const float* __restrict__ vals, int* __restrict__ cursor,
                       int* __restrict__ ecol, float* __restrict__ eval_, int e){
  int i = blockIdx.x * blockDim.x + threadIdx.x;
  if (i < e){
    int pos = atomicAdd(&cursor[rows[i]], 1);
    ecol[pos] = cols[i];
    eval_[pos] = vals[i];
  }
}

// --------------------------- seg-sum helper --------------------------------
__device__ __forceinline__ float2 seg_gather(const float* __restrict__ h,
                                             const int* __restrict__ off,
                                             const int* __restrict__ cnt,
                                             const int* __restrict__ ecol,
                                             const float* __restrict__ eval_,
                                             int row, int lane){
  float2 acc = make_float2(0.f, 0.f);
  int st = off[row], deg = cnt[row];
  for (int b = 0; b < deg; b += 64){
    int k = b + lane;
    int cc = 0; float vv = 0.f;
    if (k < deg){ cc = ecol[st+k]; vv = eval_[st+k]; }
    int m = min(64, deg - b);
    for (int j = 0; j < m; ++j){
      int c  = __shfl(cc, j);
      float v = __shfl(vv, j);
      float2 hr = *(const float2*)&h[(size_t)c*128 + 2*lane];
      acc.x = fmaf(v, hr.x, acc.x);
      acc.y = fmaf(v, hr.y, acc.y);
    }
  }
  return acc;
}

// --------------------------- seg + x1 chain --------------------------------
__global__ __launch_bounds__(256) void seg_x1(const float* __restrict__ h1,
                                              const int* __restrict__ off,
                                              const int* __restrict__ cnt,
                                              const int* __restrict__ ecol,
                                              const float* __restrict__ eval_,
                                              const float* __restrict__ loga1,
                                              const float* __restrict__ nparam,
                                              float* __restrict__ Lx1,
                                              const float* __restrict__ raw_c, int n){
  int row  = (int)((blockIdx.x * blockDim.x + threadIdx.x) >> 6);
  int lane = threadIdx.x & 63;
  if (row >= n) return;
  float K, sK; get_c(raw_c, K, sK);

  float2 acc = seg_gather(h1, off, cnt, ecol, eval_, row, lane);
  // x_1 = proj(expmap0(acc))
  float2 x1 = hexpmap0(acc, lane, K, sK);
  // mobius_matvec0(1-n, x_1)
  float2 l1 = hlogmap0(x1, lane, K, sK);
  float nv = nparam[row];
  float2 u1 = make_float2((1.f-nv)*l1.x, (1.f-nv)*l1.y);
  float2 x1b = hexpmap0(u1, lane, K, sK);
  // a2 = expmap0(n * loga1); loga2 = logmap0(a2)
  float2 l1b = hlogmap0(x1b, lane, K, sK);
  float2 la1 = *(const float2*)&loga1[(size_t)row*128 + 2*lane];
  float2 ua2 = make_float2(nv*la1.x, nv*la1.y);
  float2 a2  = hexpmap0(ua2, lane, K, sK);
  float2 la2 = hlogmap0(a2, lane, K, sK);
  // mobius_add0(x_1b, a2)
  float2 su  = make_float2(l1b.x + la2.x, l1b.y + la2.y);
  float2 x1c = hexpmap0(su, lane, K, sK);
  float2 lx1 = hlogmap0(x1c, lane, K, sK);
  *(float2*)&Lx1[(size_t)row*128 + 2*lane] = lx1;
}

// --------------------------- stage G ---------------------------------------
__global__ __launch_bounds__(256) void stage_g(const float* __restrict__ T2,
                                               const float* __restrict__ ubias,
                                               float* __restrict__ h2,
                                               const float* __restrict__ raw_c, int n){
  int row  = (int)((blockIdx.x * blockDim.x + threadIdx.x) >> 6);
  int lane = threadIdx.x & 63;
  if (row >= n) return;
  float K, sK; get_c(raw_c, K, sK);
  size_t base = (size_t)row*128 + 2*lane;
  float2 ug = *(const float2*)&ubias[256 + 2*lane];
  float2 t2 = *(const float2*)&T2[base];
  float2 p  = hexpmap0(t2, lane, K, sK);
  float2 g  = hmobius_add_u(p, ug, lane, K, sK);
  float2 hh = hlogmap0(g, lane, K, sK);
  *(float2*)&h2[base] = hh;
}

// --------------------------- seg + x2 chain --------------------------------
__global__ __launch_bounds__(256) void seg_x2(const float* __restrict__ h2,
                                              const int* __restrict__ off,
                                              const int* __restrict__ cnt,
                                              const int* __restrict__ ecol,
                                              const float* __restrict__ eval_,
                                              float* __restrict__ Lx2,
                                              const float* __restrict__ raw_c, int n){
  int row  = (int)((blockIdx.x * blockDim.x + threadIdx.x) >> 6);
  int lane = threadIdx.x & 63;
  if (row >= n) return;
  float K, sK; get_c(raw_c, K, sK);
  float2 acc = seg_gather(h2, off, cnt, ecol, eval_, row, lane);
  float2 x2  = hexpmap0(acc, lane, K, sK);
  float2 lx2 = hlogmap0(x2, lane, K, sK);
  *(float2*)&Lx2[(size_t)row*128 + 2*lane] = lx2;
}

// --------------------------- batch head ------------------------------------
// g2[b,:] = sum_l conv1_w[l]*Lx2[flat[b,l],:]   -> s2 = g2 @ weight  + c1b
// g3[b,:] = sum_l conv2_w[l]*loga1[flat[b,l],:] -> s3 = g3 @ weight2 + c2b
// sel = [s2|s3]; pre = sel @ cls + clsb; out[b] = argmax(pre)
__global__ __launch_bounds__(128) void batch_head(const float* __restrict__ Lx2,
                                                  const float* __restrict__ loga1,
                                                  const int* __restrict__ bidx,
                                                  const float* __restrict__ weight,
                                                  const float* __restrict__ weight2,
                                                  const float* __restrict__ c1w,
                                                  const float* __restrict__ c1b,
                                                  const float* __restrict__ c2w,
                                                  const float* __restrict__ c2b,
                                                  const float* __restrict__ cls,
                                                  const float* __restrict__ clsb,
                                                  float* __restrict__ out, int Bn){
  __shared__ float sg2[128], sg3[128], ssel[100], spre[5];
  int b = blockIdx.x, d = threadIdx.x;
  const int* bi = bidx + (size_t)b * 50;
  float g2 = 0.f, g3 = 0.f;
  for (int l = 0; l < 50; ++l){
    int idx = bi[l];
    size_t base = (size_t)idx * 128 + d;
    g2 = fmaf(c1w[l], Lx2[base],  g2);
    g3 = fmaf(c2w[l], loga1[base], g3);
  }
  sg2[d] = g2; sg3[d] = g3;
  __syncthreads();
  if (d < 50){
    float s = 0.f;
    for (int k = 0; k < 128; ++k) s = fmaf(sg2[k], weight[k*50 + d], s);
    s += c1b[0];
    ssel[d] = s;
    out[(size_t)Bn + (size_t)b*100 + d] = s;
  } else if (d >= 64 && d < 114){
    int t = d - 64;
    float s = 0.f;
    for (int k = 0; k < 128; ++k) s = fmaf(sg3[k], weight2[k*50 + t], s);
    s += c2b[0];
    ssel[50 + t] = s;
    out[(size_t)Bn + (size_t)b*100 + 50 + t] = s;
  }
  __syncthreads();
  if (d < 5){
    float s = clsb[d];
    for (int j = 0; j < 100; ++j) s = fmaf(ssel[j], cls[j*5 + d], s);
    spre[d] = s;
  }
  __syncthreads();
  if (d == 0){
    int best = 0; float bv = spre[0];
    #pragma unroll
    for (int k = 1; k < 5; ++k) if (spre[k] > bv){ bv = spre[k]; best = k; }
    out[b] = (float)best;
  }
}

// ---------------------------------------------------------------------------
extern "C" void kernel_launch(void* const* d_in, const int* in_sizes, int n_in,
                              void* d_out, int out_size, void* d_ws, size_t ws_size,
                              hipStream_t stream) {
  const float* A1     = (const float*)d_in[0];
  const int*   rows   = (const int*)  d_in[1];
  const int*   cols   = (const int*)  d_in[2];
  const float* vals   = (const float*)d_in[3];
  const int*   bidx   = (const int*)  d_in[4];
  const float* raw_c  = (const float*)d_in[5];
  const float* nparam = (const float*)d_in[6];
  const float* Lin1   = (const float*)d_in[7];
  const float* Lin1_b = (const float*)d_in[8];
  const float* gc1_w  = (const float*)d_in[9];
  const float* gc1_b  = (const float*)d_in[10];
  const float* gc2_w  = (const float*)d_in[11];
  const float* gc2_b  = (const float*)d_in[12];
  const float* weight = (const float*)d_in[13];
  const float* weight2= (const float*)d_in[14];
  const float* c1w    = (const float*)d_in[15];
  const float* c1b    = (const float*)d_in[16];
  const float* c2w    = (const float*)d_in[17];
  const float* c2b    = (const float*)d_in[18];
  const float* cls    = (const float*)d_in[19];
  const float* clsb   = (const float*)d_in[20];

  int N  = in_sizes[0] / 129;
  int E  = in_sizes[1];
  int Bn = in_sizes[4] / 50;
  size_t NF = (size_t)N * 128;

  // workspace layout (fp32 slots reused across pipeline stages)
  float* S0 = (float*)d_ws;        // L -> h1 -> h2
  float* S1 = S0 + NF;             // T1 -> Lx1
  float* S2 = S1 + NF;             // Tg1 -> T2 -> Lx2
  float* S3 = S2 + NF;             // loga1 (lives to the end)
  int* cnt    = (int*)(S3 + NF);
  int* off    = cnt + N;
  int* cursor = off + N;
  int* bsum   = cursor + N;        // up to 4096 scan partials
  int* ecol   = bsum + 4096;
  float* eval_ = (float*)(ecol + E);
  float* ubias = eval_ + E;        // 3 * 128 floats

  int rowBlocks  = (N + 3) / 4;    // 4 waves (rows) per 256-thread block
  int gemmBlocks = (N + 63) / 64;
  int G = (N + 256*SCAN_ITEMS - 1) / (256*SCAN_ITEMS);

  hipMemsetAsync(cnt, 0, (size_t)N * sizeof(int), stream);
  bias_prep<<<1, 64, 0, stream>>>(Lin1_b, gc1_b, gc2_b, ubias, raw_c);
  stage_a<<<rowBlocks, 256, 0, stream>>>(A1, S0, raw_c, N);

  hist_k<<<(E+255)/256, 256, 0, stream>>>(rows, cnt, E);
  scan1<<<G, 256, 0, stream>>>(cnt, off, bsum, N);
  scan2<<<1, 64, 0, stream>>>(bsum, G);
  scan3<<<(N+255)/256, 256, 0, stream>>>(off, cursor, bsum, N);
  fill_k<<<(E+255)/256, 256, 0, stream>>>(rows, cols, vals, cursor, ecol, eval_, E);

  // logmap0 col0 == 0  =>  (N,129) @ (129,128) reduces to L @ W[1:,:]
  gemm128<<<gemmBlocks, 256, 0, stream>>>(S0, Lin1 + 128, S1, N);   // T1
  gemm128<<<gemmBlocks, 256, 0, stream>>>(S0, gc1_w + 128, S2, N);  // Tg1
  stage_c<<<rowBlocks, 256, 0, stream>>>(S1, S2, ubias, S3, S0, raw_c, N); // loga1->S3, h1->S0
  seg_x1<<<rowBlocks, 256, 0, stream>>>(S0, off, cnt, ecol, eval_, S3, nparam, S1, raw_c, N); // Lx1->S1
  gemm128<<<gemmBlocks, 256, 0, stream>>>(S1, gc2_w, S2, N);        // T2->S2
  stage_g<<<rowBlocks, 256, 0, stream>>>(S2, ubias, S0, raw_c, N);  // h2->S0
  seg_x2<<<rowBlocks, 256, 0, stream>>>(S0, off, cnt, ecol, eval_, S2, raw_c, N); // Lx2->S2
  batch_head<<<Bn, 128, 0, stream>>>(S2, S3, bidx, weight, weight2, c1w, c1b,
                                     c2w, c2b, cls, clsb, (float*)d_out, Bn);
}

// Round 2
// 1572.257 us; speedup vs baseline: 1.0427x; 1.0427x over previous
//
#include <hip/hip_runtime.h>
#include <math.h>

// ---------------------------------------------------------------------------
// Hyperbolic GCN forward. Wave(64)-per-row layout: lane holds ambient dims
// (2*lane, 2*lane+1); dim 0 is the time component.
// ---------------------------------------------------------------------------

__device__ __forceinline__ float wsum(float x){
  x += __shfl_xor(x, 32);
  x += __shfl_xor(x, 16);
  x += __shfl_xor(x, 8);
  x += __shfl_xor(x, 4);
  x += __shfl_xor(x, 2);
  x += __shfl_xor(x, 1);
  return x;
}

__device__ __forceinline__ void get_c(const float* rc, float& K, float& sK){
  float c = log1pf(expf(rc[0])) + 1e-5f;   // softplus(raw_c) + 1e-5
  K  = 1.0f / c;
  sK = sqrtf(K);
}

// proj(expmap0(u)) for 128-dim ambient vectors; comp0 of u is ignored.
__device__ __forceinline__ float2 hexpmap0(float2 u, int lane, float K, float sK){
  float sx  = lane ? u.x : 0.0f;
  float xn2 = wsum(sx*sx + u.y*u.y);
  float xn  = fmaxf(sqrtf(xn2), 1e-15f);
  float th  = xn / sK;
  float s   = sK * sinhf(th) / xn;
  float rx  = sx * s, ry = u.y * s;
  float rn2 = wsum(rx*rx + ry*ry);
  float p0  = sqrtf(fmaxf(K + rn2, 1e-7f));      // proj recomputes comp0
  return make_float2(lane ? rx : p0, ry);
}

__device__ __forceinline__ float2 hlogmap0(float2 p, int lane, float K, float sK){
  float p0  = __shfl(p.x, 0);
  float sx  = lane ? p.x : 0.0f;
  float yn2 = wsum(sx*sx + p.y*p.y);
  float yn  = fmaxf(sqrtf(yn2), 1e-15f);
  float th  = fmaxf(p0 / sK, 1.0f + 1e-7f);
  float r   = sK * acoshf(th) / yn;
  return make_float2(lane ? sx*r : 0.0f, p.y * r);
}

// mobius_add(p, bias) where u = logmap0(bias point) is precomputed (u0 == 0).
__device__ __forceinline__ float2 hmobius_add_u(float2 p, float2 u, int lane, float K, float sK){
  float p0  = __shfl(p.x, 0);
  float sx  = lane ? p.x : 0.0f;
  float yn2 = wsum(sx*sx + p.y*p.y);
  float yn  = fmaxf(sqrtf(yn2), 1e-15f);
  float inv = 1.0f / yn;
  float yhx = sx * inv, yhy = p.y * inv;
  float ux  = lane ? u.x : 0.0f;
  float alpha = wsum(yhx*ux + yhy*u.y) / sK;
  float coef  = alpha * (sK - p0);
  float wx = ux  - coef * yhx;                 // lane0 -> 0 naturally
  float wy = u.y - coef * yhy;
  // proj_tan: replace comp0
  float pdw = wsum(sx*wx + p.y*wy);
  float w0  = pdw / fmaxf(p0, 1e-7f);
  // expmap(w, p)
  float spsq  = wsum(wx*wx + wy*wy);
  float md    = spsq - w0*w0;                  // minkowski dot
  float normu = fminf(sqrtf(fmaxf(md, 1e-7f)), 1e6f);
  float th    = fmaxf(normu / sK, 1e-15f);
  float ch    = coshf(th);
  float sd    = sinhf(th) / th;
  float rx = ch*p.x + sd*(lane ? wx : w0);
  float ry = ch*p.y + sd*wy;
  // proj
  float rsx = lane ? rx : 0.0f;
  float rn2 = wsum(rsx*rsx + ry*ry);
  float r0  = sqrtf(fmaxf(K + rn2, 1e-7f));
  return make_float2(lane ? rx : r0, ry);
}

// --------------------------- bias prep -------------------------------------
__global__ void bias_prep(const float* __restrict__ b0, const float* __restrict__ b1,
                          const float* __restrict__ b2, float* __restrict__ ubias,
                          const float* __restrict__ raw_c){
  int lane = threadIdx.x;  // 64 threads
  float K, sK; get_c(raw_c, K, sK);
  const float* bs[3] = {b0, b1, b2};
  for (int k = 0; k < 3; ++k){
    float2 u = make_float2(bs[k][2*lane], bs[k][2*lane+1]);
    float2 p = hexpmap0(u, lane, K, sK);      // masks comp0 == proj_tan0
    float2 L = hlogmap0(p, lane, K, sK);
    *(float2*)&ubias[k*128 + 2*lane] = L;
  }
}

// --------------------------- stage A ---------------------------------------
__global__ __launch_bounds__(256) void stage_a(const float* __restrict__ A1,
                                               float* __restrict__ L,
                                               const float* __restrict__ raw_c, int n){
  int row  = (int)((blockIdx.x * blockDim.x + threadIdx.x) >> 6);
  int lane = threadIdx.x & 63;
  if (row >= n) return;
  float K, sK; get_c(raw_c, K, sK);
  const float* rp = A1 + (size_t)row * 129;
  float x0 = rp[1 + 2*lane];
  float x1 = rp[2 + 2*lane];
  float xn2 = wsum(x0*x0 + x1*x1);
  float xn  = fmaxf(sqrtf(xn2), 1e-15f);
  float th  = xn / sK;
  float s   = sK * sinhf(th) / xn;
  float rx = x0*s, ry = x1*s;
  float rn2 = wsum(rx*rx + ry*ry);
  float a0  = sqrtf(fmaxf(K + rn2, 1e-7f));
  float yn  = fmaxf(sqrtf(rn2), 1e-15f);
  float th2 = fmaxf(a0 / sK, 1.0f + 1e-7f);
  float r   = sK * acoshf(th2) / yn;
  *(float2*)&L[(size_t)row*128 + 2*lane] = make_float2(rx*r, ry*r);
}

// --------------------------- GEMM  C = A(N,128) @ W(128,128) ---------------
__global__ __launch_bounds__(256) void gemm128(const float* __restrict__ A,
                                               const float* __restrict__ W,
                                               float* __restrict__ C, int nrows){
  __shared__ float Wl[128*128];
  int tid = threadIdx.x;
  {
    const float4* W4 = (const float4*)W;
    float4* L4 = (float4*)Wl;
    #pragma unroll
    for (int i = 0; i < 16; ++i) L4[tid + 256*i] = W4[tid + 256*i];
  }
  __syncthreads();
  int cg = tid & 31, rg = tid >> 5;
  int c0 = cg * 4;
  int rbase = blockIdx.x * 64 + rg * 8;
  float acc[8][4];
  #pragma unroll
  for (int i = 0; i < 8; ++i){ acc[i][0]=0.f; acc[i][1]=0.f; acc[i][2]=0.f; acc[i][3]=0.f; }
  for (int k = 0; k < 128; k += 4){
    float4 w0 = *(const float4*)&Wl[(k+0)*128 + c0];
    float4 w1 = *(const float4*)&Wl[(k+1)*128 + c0];
    float4 w2 = *(const float4*)&Wl[(k+2)*128 + c0];
    float4 w3 = *(const float4*)&Wl[(k+3)*128 + c0];
    #pragma unroll
    for (int i = 0; i < 8; ++i){
      int r = rbase + i;
      if (r < nrows){
        float4 a = *(const float4*)&A[(size_t)r*128 + k];
        acc[i][0] = fmaf(a.x,w0.x,fmaf(a.y,w1.x,fmaf(a.z,w2.x,fmaf(a.w,w3.x,acc[i][0]))));
        acc[i][1] = fmaf(a.x,w0.y,fmaf(a.y,w1.y,fmaf(a.z,w2.y,fmaf(a.w,w3.y,acc[i][1]))));
        acc[i][2] = fmaf(a.x,w0.z,fmaf(a.y,w1.z,fmaf(a.z,w2.z,fmaf(a.w,w3.z,acc[i][2]))));
        acc[i][3] = fmaf(a.x,w0.w,fmaf(a.y,w1.w,fmaf(a.z,w2.w,fmaf(a.w,w3.w,acc[i][3]))));
      }
    }
  }
  #pragma unroll
  for (int i = 0; i < 8; ++i){
    int r = rbase + i;
    if (r < nrows){
      *(float4*)&C[(size_t)r*128 + c0] = make_float4(acc[i][0],acc[i][1],acc[i][2],acc[i][3]);
    }
  }
}

// --------------------------- stage C ---------------------------------------
__global__ __launch_bounds__(256) void stage_c(const float* __restrict__ T1,
                                               const float* __restrict__ Tg1,
                                               const float* __restrict__ ubias,
                                               float* __restrict__ loga1,
                                               float* __restrict__ h1,
                                               const float* __restrict__ raw_c, int n){
  int row  = (int)((blockIdx.x * blockDim.x + threadIdx.x) >> 6);
  int lane = threadIdx.x & 63;
  if (row >= n) return;
  float K, sK; get_c(raw_c, K, sK);
  size_t base = (size_t)row*128 + 2*lane;
  float2 ul = *(const float2*)&ubias[2*lane];
  float2 ug = *(const float2*)&ubias[128 + 2*lane];

  float2 t1 = *(const float2*)&T1[base];
  float2 p  = hexpmap0(t1, lane, K, sK);
  float2 a1 = hmobius_add_u(p, ul, lane, K, sK);
  float2 la = hlogmap0(a1, lane, K, sK);
  *(float2*)&loga1[base] = la;

  float2 tg = *(const float2*)&Tg1[base];
  float2 pg = hexpmap0(tg, lane, K, sK);
  float2 g  = hmobius_add_u(pg, ug, lane, K, sK);
  float2 hh = hlogmap0(g, lane, K, sK);
  *(float2*)&h1[base] = hh;
}

// --------------------------- CSR build -------------------------------------
__global__ void hist_k(const int* __restrict__ rows, int* __restrict__ cnt, int e){
  int i = blockIdx.x * blockDim.x + threadIdx.x;
  if (i < e) atomicAdd(&cnt[rows[i]], 1);
}

#define SCAN_ITEMS 4
__global__ __launch_bounds__(256) void scan1(const int* __restrict__ cnt,
                                             int* __restrict__ off,
                                             int* __restrict__ bsum, int n){
  __shared__ int sh[256];
  int tid = threadIdx.x;
  int base = blockIdx.x * 256 * SCAN_ITEMS + tid * SCAN_ITEMS;
  int v[SCAN_ITEMS]; int s = 0;
  #pragma unroll
  for (int i = 0; i < SCAN_ITEMS; ++i){ int idx = base+i; v[i] = (idx < n) ? cnt[idx] : 0; s += v[i]; }
  sh[tid] = s; __syncthreads();
  for (int o = 1; o < 256; o <<= 1){
    int t = (tid >= o) ? sh[tid - o] : 0; __syncthreads();
    sh[tid] += t; __syncthreads();
  }
  int excl = sh[tid] - s;
  if (tid == 255) bsum[blockIdx.x] = sh[tid];
  int run = excl;
  #pragma unroll
  for (int i = 0; i < SCAN_ITEMS; ++i){ int idx = base+i; if (idx < n) off[idx] = run; run += v[i]; }
}

__global__ void scan2(int* bsum, int G){
  if (threadIdx.x == 0 && blockIdx.x == 0){
    int run = 0;
    for (int i = 0; i < G; ++i){ int t = bsum[i]; bsum[i] = run; run += t; }
  }
}

__global__ void scan3(int* __restrict__ off, int* __restrict__ cursor,
                      const int* __restrict__ bsum, int n){
  int i = blockIdx.x * blockDim.x + threadIdx.x;
  if (i < n){ int o = off[i] + bsum[i / (256*SCAN_ITEMS)]; off[i] = o; cursor[i] = o; }
}

__global__ void fill_k(const int* __restrict__ rows, const int* __restrict__ cols,
                       const float* __restrict__ vals, int* __restrict__ cursor,
                       int* __restrict__ ecol, float* __restrict__ eval_, int e){
  int i = blockIdx.x * blockDim.x + threadIdx.x;
  if (i < e){
    int pos = atomicAdd(&cursor[rows[i]], 1);
    ecol[pos] = cols[i];
    eval_[pos] = vals[i];
  }
}

// --------------------------- seg-sum helper --------------------------------
// 8-deep software pipeline. Lanes with k>=deg hold (c=0, v=0), so overrunning
// the group to a multiple of 8 adds v*h[0] with v==0 (row 0 stays L1-hot):
// no tail loop, 8 gather loads in flight per wave.
__device__ __forceinline__ float2 seg_gather(const float* __restrict__ h,
                                             const int* __restrict__ off,
                                             const int* __restrict__ cnt,
                                             const int* __restrict__ ecol,
                                             const float* __restrict__ eval_,
                                             int row, int lane){
  float ax = 0.f, ay = 0.f, bx = 0.f, by = 0.f;
  int st = off[row], deg = cnt[row];
  const float2* __restrict__ hb = (const float2*)h + lane;  // row stride = 64 float2
  for (int b = 0; b < deg; b += 64){
    int k = b + lane;
    int cc = 0; float vv = 0.f;
    if (k < deg){ cc = ecol[st+k]; vv = eval_[st+k]; }
    int m = min(64, deg - b);
    for (int j = 0; j < m; j += 8){
      int   c0=__shfl(cc,j+0), c1=__shfl(cc,j+1), c2=__shfl(cc,j+2), c3=__shfl(cc,j+3);
      int   c4=__shfl(cc,j+4), c5=__shfl(cc,j+5), c6=__shfl(cc,j+6), c7=__shfl(cc,j+7);
      float v0=__shfl(vv,j+0), v1=__shfl(vv,j+1), v2=__shfl(vv,j+2), v3=__shfl(vv,j+3);
      float v4=__shfl(vv,j+4), v5=__shfl(vv,j+5), v6=__shfl(vv,j+6), v7=__shfl(vv,j+7);
      float2 h0 = hb[(size_t)c0*64];
      float2 h1 = hb[(size_t)c1*64];
      float2 h2 = hb[(size_t)c2*64];
      float2 h3 = hb[(size_t)c3*64];
      float2 h4 = hb[(size_t)c4*64];
      float2 h5 = hb[(size_t)c5*64];
      float2 h6 = hb[(size_t)c6*64];
      float2 h7 = hb[(size_t)c7*64];
      ax = fmaf(v0,h0.x,ax); ay = fmaf(v0,h0.y,ay);
      bx = fmaf(v1,h1.x,bx); by = fmaf(v1,h1.y,by);
      ax = fmaf(v2,h2.x,ax); ay = fmaf(v2,h2.y,ay);
      bx = fmaf(v3,h3.x,bx); by = fmaf(v3,h3.y,by);
      ax = fmaf(v4,h4.x,ax); ay = fmaf(v4,h4.y,ay);
      bx = fmaf(v5,h5.x,bx); by = fmaf(v5,h5.y,by);
      ax = fmaf(v6,h6.x,ax); ay = fmaf(v6,h6.y,ay);
      bx = fmaf(v7,h7.x,bx); by = fmaf(v7,h7.y,by);
    }
  }
  return make_float2(ax + bx, ay + by);
}

// --------------------------- seg + x1 chain --------------------------------
__global__ __launch_bounds__(256) void seg_x1(const float* __restrict__ h1,
                                              const int* __restrict__ off,
                                              const int* __restrict__ cnt,
                                              const int* __restrict__ ecol,
                                              const float* __restrict__ eval_,
                                              const float* __restrict__ loga1,
                                              const float* __restrict__ nparam,
                                              float* __restrict__ Lx1,
                                              const float* __restrict__ raw_c, int n){
  int row  = (int)((blockIdx.x * blockDim.x + threadIdx.x) >> 6);
  int lane = threadIdx.x & 63;
  if (row >= n) return;
  float K, sK; get_c(raw_c, K, sK);

  float2 acc = seg_gather(h1, off, cnt, ecol, eval_, row, lane);
  // x_1 = proj(expmap0(acc))
  float2 x1 = hexpmap0(acc, lane, K, sK);
  // mobius_matvec0(1-n, x_1)
  float2 l1 = hlogmap0(x1, lane, K, sK);
  float nv = nparam[row];
  float2 u1 = make_float2((1.f-nv)*l1.x, (1.f-nv)*l1.y);
  float2 x1b = hexpmap0(u1, lane, K, sK);
  // a2 = expmap0(n * loga1); loga2 = logmap0(a2)
  float2 l1b = hlogmap0(x1b, lane, K, sK);
  float2 la1 = *(const float2*)&loga1[(size_t)row*128 + 2*lane];
  float2 ua2 = make_float2(nv*la1.x, nv*la1.y);
  float2 a2  = hexpmap0(ua2, lane, K, sK);
  float2 la2 = hlogmap0(a2, lane, K, sK);
  // mobius_add0(x_1b, a2)
  float2 su  = make_float2(l1b.x + la2.x, l1b.y + la2.y);
  float2 x1c = hexpmap0(su, lane, K, sK);
  float2 lx1 = hlogmap0(x1c, lane, K, sK);
  *(float2*)&Lx1[(size_t)row*128 + 2*lane] = lx1;
}

// --------------------------- stage G ---------------------------------------
__global__ __launch_bounds__(256) void stage_g(const float* __restrict__ T2,
                                               const float* __restrict__ ubias,
                                               float* __restrict__ h2,
                                               const float* __restrict__ raw_c, int n){
  int row  = (int)((blockIdx.x * blockDim.x + threadIdx.x) >> 6);
  int lane = threadIdx.x & 63;
  if (row >= n) return;
  float K, sK; get_c(raw_c, K, sK);
  size_t base = (size_t)row*128 + 2*lane;
  float2 ug = *(const float2*)&ubias[256 + 2*lane];
  float2 t2 = *(const float2*)&T2[base];
  float2 p  = hexpmap0(t2, lane, K, sK);
  float2 g  = hmobius_add_u(p, ug, lane, K, sK);
  float2 hh = hlogmap0(g, lane, K, sK);
  *(float2*)&h2[base] = hh;
}

// --------------------------- seg + x2 chain --------------------------------
__global__ __launch_bounds__(256) void seg_x2(const float* __restrict__ h2,
                                              const int* __restrict__ off,
                                              const int* __restrict__ cnt,
                                              const int* __restrict__ ecol,
                                              const float* __restrict__ eval_,
                                              float* __restrict__ Lx2,
                                              const float* __restrict__ raw_c, int n){
  int row  = (int)((blockIdx.x * blockDim.x + threadIdx.x) >> 6);
  int lane = threadIdx.x & 63;
  if (row >= n) return;
  float K, sK; get_c(raw_c, K, sK);
  float2 acc = seg_gather(h2, off, cnt, ecol, eval_, row, lane);
  float2 x2  = hexpmap0(acc, lane, K, sK);
  float2 lx2 = hlogmap0(x2, lane, K, sK);
  *(float2*)&Lx2[(size_t)row*128 + 2*lane] = lx2;
}

// --------------------------- batch head ------------------------------------
__global__ __launch_bounds__(128) void batch_head(const float* __restrict__ Lx2,
                                                  const float* __restrict__ loga1,
                                                  const int* __restrict__ bidx,
                                                  const float* __restrict__ weight,
                                                  const float* __restrict__ weight2,
                                                  const float* __restrict__ c1w,
                                                  const float* __restrict__ c1b,
                                                  const float* __restrict__ c2w,
                                                  const float* __restrict__ c2b,
                                                  const float* __restrict__ cls,
                                                  const float* __restrict__ clsb,
                                                  float* __restrict__ out, int Bn){
  __shared__ float sg2[128], sg3[128], ssel[100], spre[5];
  __shared__ int sbi[50];
  __shared__ float sc1[50], sc2[50];
  int b = blockIdx.x, d = threadIdx.x;
  const int* bi = bidx + (size_t)b * 50;
  if (d < 50){ sbi[d] = bi[d]; sc1[d] = c1w[d]; sc2[d] = c2w[d]; }
  __syncthreads();
  float g2 = 0.f, g3 = 0.f;
  #pragma unroll
  for (int l = 0; l < 50; l += 5){
    int i0 = sbi[l+0], i1 = sbi[l+1], i2 = sbi[l+2], i3 = sbi[l+3], i4 = sbi[l+4];
    float a0 = Lx2[(size_t)i0*128 + d];
    float a1 = Lx2[(size_t)i1*128 + d];
    float a2 = Lx2[(size_t)i2*128 + d];
    float a3 = Lx2[(size_t)i3*128 + d];
    float a4 = Lx2[(size_t)i4*128 + d];
    float e0 = loga1[(size_t)i0*128 + d];
    float e1 = loga1[(size_t)i1*128 + d];
    float e2 = loga1[(size_t)i2*128 + d];
    float e3 = loga1[(size_t)i3*128 + d];
    float e4 = loga1[(size_t)i4*128 + d];
    g2 = fmaf(sc1[l+0], a0, g2); g3 = fmaf(sc2[l+0], e0, g3);
    g2 = fmaf(sc1[l+1], a1, g2); g3 = fmaf(sc2[l+1], e1, g3);
    g2 = fmaf(sc1[l+2], a2, g2); g3 = fmaf(sc2[l+2], e2, g3);
    g2 = fmaf(sc1[l+3], a3, g2); g3 = fmaf(sc2[l+3], e3, g3);
    g2 = fmaf(sc1[l+4], a4, g2); g3 = fmaf(sc2[l+4], e4, g3);
  }
  sg2[d] = g2; sg3[d] = g3;
  __syncthreads();
  if (d < 50){
    float s = 0.f;
    for (int k = 0; k < 128; ++k) s = fmaf(sg2[k], weight[k*50 + d], s);
    s += c1b[0];
    ssel[d] = s;
    out[(size_t)Bn + (size_t)b*100 + d] = s;
  } else if (d >= 64 && d < 114){
    int t = d - 64;
    float s = 0.f;
    for (int k = 0; k < 128; ++k) s = fmaf(sg3[k], weight2[k*50 + t], s);
    s += c2b[0];
    ssel[50 + t] = s;
    out[(size_t)Bn + (size_t)b*100 + 50 + t] = s;
  }
  __syncthreads();
  if (d < 5){
    float s = clsb[d];
    for (int j = 0; j < 100; ++j) s = fmaf(ssel[j], cls[j*5 + d], s);
    spre[d] = s;
  }
  __syncthreads();
  if (d == 0){
    int best = 0; float bv = spre[0];
    #pragma unroll
    for (int k = 1; k < 5; ++k) if (spre[k] > bv){ bv = spre[k]; best = k; }
    out[b] = (float)best;
  }
}

// ---------------------------------------------------------------------------
extern "C" void kernel_launch(void* const* d_in, const int* in_sizes, int n_in,
                              void* d_out, int out_size, void* d_ws, size_t ws_size,
                              hipStream_t stream) {
  const float* A1     = (const float*)d_in[0];
  const int*   rows   = (const int*)  d_in[1];
  const int*   cols   = (const int*)  d_in[2];
  const float* vals   = (const float*)d_in[3];
  const int*   bidx   = (const int*)  d_in[4];
  const float* raw_c  = (const float*)d_in[5];
  const float* nparam = (const float*)d_in[6];
  const float* Lin1   = (const float*)d_in[7];
  const float* Lin1_b = (const float*)d_in[8];
  const float* gc1_w  = (const float*)d_in[9];
  const float* gc1_b  = (const float*)d_in[10];
  const float* gc2_w  = (const float*)d_in[11];
  const float* gc2_b  = (const float*)d_in[12];
  const float* weight = (const float*)d_in[13];
  const float* weight2= (const float*)d_in[14];
  const float* c1w    = (const float*)d_in[15];
  const float* c1b    = (const float*)d_in[16];
  const float* c2w    = (const float*)d_in[17];
  const float* c2b    = (const float*)d_in[18];
  const float* cls    = (const float*)d_in[19];
  const float* clsb   = (const float*)d_in[20];

  int N  = in_sizes[0] / 129;
  int E  = in_sizes[1];
  int Bn = in_sizes[4] / 50;
  size_t NF = (size_t)N * 128;

  // workspace layout (fp32 slots reused across pipeline stages)
  float* S0 = (float*)d_ws;        // L -> h1 -> h2
  float* S1 = S0 + NF;             // T1 -> Lx1
  float* S2 = S1 + NF;             // Tg1 -> T2 -> Lx2
  float* S3 = S2 + NF;             // loga1 (lives to the end)
  int* cnt    = (int*)(S3 + NF);
  int* off    = cnt + N;
  int* cursor = off + N;
  int* bsum   = cursor + N;        // up to 4096 scan partials
  int* ecol   = bsum + 4096;
  float* eval_ = (float*)(ecol + E);
  float* ubias = eval_ + E;        // 3 * 128 floats

  int rowBlocks  = (N + 3) / 4;    // 4 waves (rows) per 256-thread block
  int gemmBlocks = (N + 63) / 64;
  int G = (N + 256*SCAN_ITEMS - 1) / (256*SCAN_ITEMS);

  hipMemsetAsync(cnt, 0, (size_t)N * sizeof(int), stream);
  bias_prep<<<1, 64, 0, stream>>>(Lin1_b, gc1_b, gc2_b, ubias, raw_c);
  stage_a<<<rowBlocks, 256, 0, stream>>>(A1, S0, raw_c, N);

  hist_k<<<(E+255)/256, 256, 0, stream>>>(rows, cnt, E);
  scan1<<<G, 256, 0, stream>>>(cnt, off, bsum, N);
  scan2<<<1, 64, 0, stream>>>(bsum, G);
  scan3<<<(N+255)/256, 256, 0, stream>>>(off, cursor, bsum, N);
  fill_k<<<(E+255)/256, 256, 0, stream>>>(rows, cols, vals, cursor, ecol, eval_, E);

  // logmap0 col0 == 0  =>  (N,129) @ (129,128) reduces to L @ W[1:,:]
  gemm128<<<gemmBlocks, 256, 0, stream>>>(S0, Lin1 + 128, S1, N);   // T1
  gemm128<<<gemmBlocks, 256, 0, stream>>>(S0, gc1_w + 128, S2, N);  // Tg1
  stage_c<<<rowBlocks, 256, 0, stream>>>(S1, S2, ubias, S3, S0, raw_c, N); // loga1->S3, h1->S0
  seg_x1<<<rowBlocks, 256, 0, stream>>>(S0, off, cnt, ecol, eval_, S3, nparam, S1, raw_c, N); // Lx1->S1
  gemm128<<<gemmBlocks, 256, 0, stream>>>(S1, gc2_w, S2, N);        // T2->S2
  stage_g<<<rowBlocks, 256, 0, stream>>>(S2, ubias, S0, raw_c, N);  // h2->S0
  seg_x2<<<rowBlocks, 256, 0, stream>>>(S0, off, cnt, ecol, eval_, S2, raw_c, N); // Lx2->S2
  batch_head<<<Bn, 128, 0, stream>>>(S2, S3, bidx, weight, weight2, c1w, c1b,
                                     c2w, c2b, cls, clsb, (float*)d_out, Bn);
}

// Round 3
// 1227.371 us; speedup vs baseline: 1.3356x; 1.2810x over previous
//
#include <hip/hip_runtime.h>
#include <math.h>

// ---------------------------------------------------------------------------
// Hyperbolic GCN forward, algebraically collapsed:
//   logmap0(proj(expmap0(u))) == u  (tangent-at-origin roundtrips cancel)
// so only the bias mobius_add chains need hyperbolic math; those use HW
// transcendentals (v_exp/v_log/v_rcp) instead of libm.
// Wave(64)-per-row layout: lane holds dims (2*lane, 2*lane+1); dim0 = time.
// ---------------------------------------------------------------------------

__device__ __forceinline__ float wsum(float x){
  x += __shfl_xor(x, 32);
  x += __shfl_xor(x, 16);
  x += __shfl_xor(x, 8);
  x += __shfl_xor(x, 4);
  x += __shfl_xor(x, 2);
  x += __shfl_xor(x, 1);
  return x;
}

__device__ __forceinline__ void get_c(const float* rc, float& K, float& sK){
  float c = log1pf(expf(rc[0])) + 1e-5f;   // softplus(raw_c) + 1e-5 (once/wave, keep libm)
  K  = 1.0f / c;
  sK = sqrtf(K);
}

// sinh(x)/x for x >= 0, HW exp + rcp, Taylor-guarded (x is wave-uniform).
__device__ __forceinline__ float sinhx_over_x(float x){
  if (x > 1e-3f){
    float e  = __expf(x);
    float em = __builtin_amdgcn_rcpf(e);
    return 0.5f*(e - em) * __builtin_amdgcn_rcpf(x);
  }
  return 1.0f + x*x*(1.0f/6.0f);
}

__device__ __forceinline__ float fcosh(float x){
  float e  = __expf(x);
  float em = __builtin_amdgcn_rcpf(e);
  return 0.5f*(e + em);
}

__device__ __forceinline__ float facosh(float x){   // x >= 1+1e-7
  return __logf(x + sqrtf(fmaxf(fmaf(x, x, -1.0f), 0.0f)));
}

// proj(expmap0(u)); comp0 of u ignored.
__device__ __forceinline__ float2 hexpmap0(float2 u, int lane, float K, float sK){
  float sx  = lane ? u.x : 0.0f;
  float xn2 = wsum(sx*sx + u.y*u.y);
  float xn  = fmaxf(sqrtf(xn2), 1e-15f);
  float th  = xn / sK;
  float s   = sinhx_over_x(th);          // == sK*sinh(th)/xn
  float rx  = sx * s, ry = u.y * s;
  float rn2 = wsum(rx*rx + ry*ry);
  float p0  = sqrtf(fmaxf(K + rn2, 1e-7f));
  return make_float2(lane ? rx : p0, ry);
}

__device__ __forceinline__ float2 hlogmap0(float2 p, int lane, float K, float sK){
  float p0  = __shfl(p.x, 0);
  float sx  = lane ? p.x : 0.0f;
  float yn2 = wsum(sx*sx + p.y*p.y);
  float yn  = fmaxf(sqrtf(yn2), 1e-15f);
  float th  = fmaxf(p0 / sK, 1.0f + 1e-7f);
  float r   = sK * facosh(th) * __builtin_amdgcn_rcpf(yn);
  return make_float2(lane ? sx*r : 0.0f, p.y * r);
}

// mobius_add(p, bias_pt) where u = logmap0(bias_pt) == spatial(b) (roundtrip).
// u.x is masked for lane 0 inside.
__device__ __forceinline__ float2 hmobius_add_u(float2 p, float2 u, int lane, float K, float sK){
  float p0  = __shfl(p.x, 0);
  float sx  = lane ? p.x : 0.0f;
  float yn2 = wsum(sx*sx + p.y*p.y);
  float yn  = fmaxf(sqrtf(yn2), 1e-15f);
  float inv = __builtin_amdgcn_rcpf(yn);
  float yhx = sx * inv, yhy = p.y * inv;
  float ux  = lane ? u.x : 0.0f;
  float alpha = wsum(yhx*ux + yhy*u.y) / sK;
  float coef  = alpha * (sK - p0);
  float wx = ux  - coef * yhx;
  float wy = u.y - coef * yhy;
  // proj_tan: comp0 = <spatial(p), spatial(w)> / p0
  float pdw = wsum(sx*wx + p.y*wy);
  float w0  = pdw / fmaxf(p0, 1e-7f);
  // expmap(w, p)
  float spsq  = wsum(wx*wx + wy*wy);
  float md    = spsq - w0*w0;
  float normu = fminf(sqrtf(fmaxf(md, 1e-7f)), 1e6f);
  float th    = fmaxf(normu / sK, 1e-15f);
  float ch    = fcosh(th);
  float sd    = sinhx_over_x(th);
  float rx = ch*p.x + sd*(lane ? wx : w0);
  float ry = ch*p.y + sd*wy;
  // proj
  float rsx = lane ? rx : 0.0f;
  float rn2 = wsum(rsx*rsx + ry*ry);
  float r0  = sqrtf(fmaxf(K + rn2, 1e-7f));
  return make_float2(lane ? rx : r0, ry);
}

// --------------------------- stage A: L = A1[:,1:] --------------------------
__global__ __launch_bounds__(256) void stage_a(const float* __restrict__ A1,
                                               float* __restrict__ L, int n){
  size_t i = (size_t)blockIdx.x * 256 + threadIdx.x;
  size_t total = (size_t)n * 128;
  if (i < total){
    size_t row = i >> 7; int j = (int)(i & 127);
    L[i] = A1[row*129 + 1 + j];
  }
}

// --------------------------- GEMM  C = A(N,128) @ W(128,128) ---------------
__global__ __launch_bounds__(256) void gemm128(const float* __restrict__ A,
                                               const float* __restrict__ W,
                                               float* __restrict__ C, int nrows){
  __shared__ float Wl[128*128];
  int tid = threadIdx.x;
  {
    const float4* W4 = (const float4*)W;
    float4* L4 = (float4*)Wl;
    #pragma unroll
    for (int i = 0; i < 16; ++i) L4[tid + 256*i] = W4[tid + 256*i];
  }
  __syncthreads();
  int cg = tid & 31, rg = tid >> 5;
  int c0 = cg * 4;
  int rbase = blockIdx.x * 64 + rg * 8;
  float acc[8][4];
  #pragma unroll
  for (int i = 0; i < 8; ++i){ acc[i][0]=0.f; acc[i][1]=0.f; acc[i][2]=0.f; acc[i][3]=0.f; }
  for (int k = 0; k < 128; k += 4){
    float4 w0 = *(const float4*)&Wl[(k+0)*128 + c0];
    float4 w1 = *(const float4*)&Wl[(k+1)*128 + c0];
    float4 w2 = *(const float4*)&Wl[(k+2)*128 + c0];
    float4 w3 = *(const float4*)&Wl[(k+3)*128 + c0];
    #pragma unroll
    for (int i = 0; i < 8; ++i){
      int r = rbase + i;
      if (r < nrows){
        float4 a = *(const float4*)&A[(size_t)r*128 + k];
        acc[i][0] = fmaf(a.x,w0.x,fmaf(a.y,w1.x,fmaf(a.z,w2.x,fmaf(a.w,w3.x,acc[i][0]))));
        acc[i][1] = fmaf(a.x,w0.y,fmaf(a.y,w1.y,fmaf(a.z,w2.y,fmaf(a.w,w3.y,acc[i][1]))));
        acc[i][2] = fmaf(a.x,w0.z,fmaf(a.y,w1.z,fmaf(a.z,w2.z,fmaf(a.w,w3.z,acc[i][2]))));
        acc[i][3] = fmaf(a.x,w0.w,fmaf(a.y,w1.w,fmaf(a.z,w2.w,fmaf(a.w,w3.w,acc[i][3]))));
      }
    }
  }
  #pragma unroll
  for (int i = 0; i < 8; ++i){
    int r = rbase + i;
    if (r < nrows){
      *(float4*)&C[(size_t)r*128 + c0] = make_float4(acc[i][0],acc[i][1],acc[i][2],acc[i][3]);
    }
  }
}

// --------------------------- stage C ---------------------------------------
// loga1 = logmap0(mobius_add(proj(expmap0(T1)), bias_lin1))
// h1    = logmap0(mobius_add(proj(expmap0(Tg1)), bias_gc1))
// bias tangents are the raw bias vectors (roundtrip identity), comp0 masked.
__global__ __launch_bounds__(256) void stage_c(const float* __restrict__ T1,
                                               const float* __restrict__ Tg1,
                                               const float* __restrict__ bl,
                                               const float* __restrict__ bg,
                                               float* __restrict__ loga1,
                                               float* __restrict__ h1,
                                               const float* __restrict__ raw_c, int n){
  int row  = (int)((blockIdx.x * blockDim.x + threadIdx.x) >> 6);
  int lane = threadIdx.x & 63;
  if (row >= n) return;
  float K, sK; get_c(raw_c, K, sK);
  size_t base = (size_t)row*128 + 2*lane;
  float2 ul = *(const float2*)&bl[2*lane];
  float2 ug = *(const float2*)&bg[2*lane];

  float2 t1 = *(const float2*)&T1[base];
  float2 p  = hexpmap0(t1, lane, K, sK);
  float2 a1 = hmobius_add_u(p, ul, lane, K, sK);
  float2 la = hlogmap0(a1, lane, K, sK);
  *(float2*)&loga1[base] = la;

  float2 tg = *(const float2*)&Tg1[base];
  float2 pg = hexpmap0(tg, lane, K, sK);
  float2 g  = hmobius_add_u(pg, ug, lane, K, sK);
  float2 hh = hlogmap0(g, lane, K, sK);
  *(float2*)&h1[base] = hh;
}

// --------------------------- stage G ---------------------------------------
__global__ __launch_bounds__(256) void stage_g(const float* __restrict__ T2,
                                               const float* __restrict__ bg2,
                                               float* __restrict__ h2,
                                               const float* __restrict__ raw_c, int n){
  int row  = (int)((blockIdx.x * blockDim.x + threadIdx.x) >> 6);
  int lane = threadIdx.x & 63;
  if (row >= n) return;
  float K, sK; get_c(raw_c, K, sK);
  size_t base = (size_t)row*128 + 2*lane;
  float2 ug = *(const float2*)&bg2[2*lane];
  float2 t2 = *(const float2*)&T2[base];
  float2 p  = hexpmap0(t2, lane, K, sK);
  float2 g  = hmobius_add_u(p, ug, lane, K, sK);
  float2 hh = hlogmap0(g, lane, K, sK);
  *(float2*)&h2[base] = hh;
}

// --------------------------- CSR build -------------------------------------
__global__ void hist_k(const int* __restrict__ rows, int* __restrict__ cnt, int e){
  int i = blockIdx.x * blockDim.x + threadIdx.x;
  if (i < e) atomicAdd(&cnt[rows[i]], 1);
}

#define SCAN_ITEMS 4
__global__ __launch_bounds__(256) void scan1(const int* __restrict__ cnt,
                                             int* __restrict__ off,
                                             int* __restrict__ bsum, int n){
  __shared__ int sh[256];
  int tid = threadIdx.x;
  int base = blockIdx.x * 256 * SCAN_ITEMS + tid * SCAN_ITEMS;
  int v[SCAN_ITEMS]; int s = 0;
  #pragma unroll
  for (int i = 0; i < SCAN_ITEMS; ++i){ int idx = base+i; v[i] = (idx < n) ? cnt[idx] : 0; s += v[i]; }
  sh[tid] = s; __syncthreads();
  for (int o = 1; o < 256; o <<= 1){
    int t = (tid >= o) ? sh[tid - o] : 0; __syncthreads();
    sh[tid] += t; __syncthreads();
  }
  int excl = sh[tid] - s;
  if (tid == 255) bsum[blockIdx.x] = sh[tid];
  int run = excl;
  #pragma unroll
  for (int i = 0; i < SCAN_ITEMS; ++i){ int idx = base+i; if (idx < n) off[idx] = run; run += v[i]; }
}

__global__ void scan2(int* bsum, int G){
  if (threadIdx.x == 0 && blockIdx.x == 0){
    int run = 0;
    for (int i = 0; i < G; ++i){ int t = bsum[i]; bsum[i] = run; run += t; }
  }
}

__global__ void scan3(int* __restrict__ off, int* __restrict__ cursor,
                      const int* __restrict__ bsum, int n){
  int i = blockIdx.x * blockDim.x + threadIdx.x;
  if (i < n){ int o = off[i] + bsum[i / (256*SCAN_ITEMS)]; off[i] = o; cursor[i] = o; }
}

__global__ void fill_k(const int* __restrict__ rows, const int* __restrict__ cols,
                       const float* __restrict__ vals, int* __restrict__ cursor,
                       int* __restrict__ ecol, float* __restrict__ eval_, int e){
  int i = blockIdx.x * blockDim.x + threadIdx.x;
  if (i < e){
    int pos = atomicAdd(&cursor[rows[i]], 1);
    ecol[pos] = cols[i];
    eval_[pos] = vals[i];
  }
}

// --------------------------- seg-sum helper --------------------------------
// 8-deep pipeline; padded lanes carry (c=0,v=0) so no tail (adds 0*row0).
__device__ __forceinline__ float2 seg_gather(const float* __restrict__ h,
                                             const int* __restrict__ off,
                                             const int* __restrict__ cnt,
                                             const int* __restrict__ ecol,
                                             const float* __restrict__ eval_,
                                             int row, int lane){
  float ax = 0.f, ay = 0.f, bx = 0.f, by = 0.f;
  int st = off[row], deg = cnt[row];
  const float2* __restrict__ hb = (const float2*)h + lane;  // row stride = 64 float2
  for (int b = 0; b < deg; b += 64){
    int k = b + lane;
    int cc = 0; float vv = 0.f;
    if (k < deg){ cc = ecol[st+k]; vv = eval_[st+k]; }
    int m = min(64, deg - b);
    for (int j = 0; j < m; j += 8){
      int   c0=__shfl(cc,j+0), c1=__shfl(cc,j+1), c2=__shfl(cc,j+2), c3=__shfl(cc,j+3);
      int   c4=__shfl(cc,j+4), c5=__shfl(cc,j+5), c6=__shfl(cc,j+6), c7=__shfl(cc,j+7);
      float v0=__shfl(vv,j+0), v1=__shfl(vv,j+1), v2=__shfl(vv,j+2), v3=__shfl(vv,j+3);
      float v4=__shfl(vv,j+4), v5=__shfl(vv,j+5), v6=__shfl(vv,j+6), v7=__shfl(vv,j+7);
      float2 h0 = hb[(size_t)c0*64];
      float2 h1 = hb[(size_t)c1*64];
      float2 h2 = hb[(size_t)c2*64];
      float2 h3 = hb[(size_t)c3*64];
      float2 h4 = hb[(size_t)c4*64];
      float2 h5 = hb[(size_t)c5*64];
      float2 h6 = hb[(size_t)c6*64];
      float2 h7 = hb[(size_t)c7*64];
      ax = fmaf(v0,h0.x,ax); ay = fmaf(v0,h0.y,ay);
      bx = fmaf(v1,h1.x,bx); by = fmaf(v1,h1.y,by);
      ax = fmaf(v2,h2.x,ax); ay = fmaf(v2,h2.y,ay);
      bx = fmaf(v3,h3.x,bx); by = fmaf(v3,h3.y,by);
      ax = fmaf(v4,h4.x,ax); ay = fmaf(v4,h4.y,ay);
      bx = fmaf(v5,h5.x,bx); by = fmaf(v5,h5.y,by);
      ax = fmaf(v6,h6.x,ax); ay = fmaf(v6,h6.y,ay);
      bx = fmaf(v7,h7.x,bx); by = fmaf(v7,h7.y,by);
    }
  }
  return make_float2(ax + bx, ay + by);
}

// --------------------------- seg_x1: Lx1 = (1-n)*segsum(h1) + n*loga1 -------
__global__ __launch_bounds__(256) void seg_x1(const float* __restrict__ h1,
                                              const int* __restrict__ off,
                                              const int* __restrict__ cnt,
                                              const int* __restrict__ ecol,
                                              const float* __restrict__ eval_,
                                              const float* __restrict__ loga1,
                                              const float* __restrict__ nparam,
                                              float* __restrict__ Lx1, int n){
  int row  = (int)((blockIdx.x * blockDim.x + threadIdx.x) >> 6);
  int lane = threadIdx.x & 63;
  if (row >= n) return;
  float2 acc = seg_gather(h1, off, cnt, ecol, eval_, row, lane);
  float nv = nparam[row];
  float2 la1 = *(const float2*)&loga1[(size_t)row*128 + 2*lane];
  float ox = (1.f-nv)*acc.x + nv*la1.x;
  float oy = (1.f-nv)*acc.y + nv*la1.y;
  *(float2*)&Lx1[(size_t)row*128 + 2*lane] = make_float2(ox, oy);
}

// --------------------------- seg_x2: Lx2 = segsum(h2) -----------------------
__global__ __launch_bounds__(256) void seg_x2(const float* __restrict__ h2,
                                              const int* __restrict__ off,
                                              const int* __restrict__ cnt,
                                              const int* __restrict__ ecol,
                                              const float* __restrict__ eval_,
                                              float* __restrict__ Lx2, int n){
  int row  = (int)((blockIdx.x * blockDim.x + threadIdx.x) >> 6);
  int lane = threadIdx.x & 63;
  if (row >= n) return;
  float2 acc = seg_gather(h2, off, cnt, ecol, eval_, row, lane);
  *(float2*)&Lx2[(size_t)row*128 + 2*lane] = acc;
}

// --------------------------- batch head ------------------------------------
__global__ __launch_bounds__(128) void batch_head(const float* __restrict__ Lx2,
                                                  const float* __restrict__ loga1,
                                                  const int* __restrict__ bidx,
                                                  const float* __restrict__ weight,
                                                  const float* __restrict__ weight2,
                                                  const float* __restrict__ c1w,
                                                  const float* __restrict__ c1b,
                                                  const float* __restrict__ c2w,
                                                  const float* __restrict__ c2b,
                                                  const float* __restrict__ cls,
                                                  const float* __restrict__ clsb,
                                                  float* __restrict__ out, int Bn){
  __shared__ float sg2[128], sg3[128], ssel[100], spre[5];
  __shared__ int sbi[50];
  __shared__ float sc1[50], sc2[50];
  int b = blockIdx.x, d = threadIdx.x;
  const int* bi = bidx + (size_t)b * 50;
  if (d < 50){ sbi[d] = bi[d]; sc1[d] = c1w[d]; sc2[d] = c2w[d]; }
  __syncthreads();
  float g2 = 0.f, g3 = 0.f;
  #pragma unroll
  for (int l = 0; l < 50; l += 5){
    int i0 = sbi[l+0], i1 = sbi[l+1], i2 = sbi[l+2], i3 = sbi[l+3], i4 = sbi[l+4];
    float a0 = Lx2[(size_t)i0*128 + d];
    float a1 = Lx2[(size_t)i1*128 + d];
    float a2 = Lx2[(size_t)i2*128 + d];
    float a3 = Lx2[(size_t)i3*128 + d];
    float a4 = Lx2[(size_t)i4*128 + d];
    float e0 = loga1[(size_t)i0*128 + d];
    float e1 = loga1[(size_t)i1*128 + d];
    float e2 = loga1[(size_t)i2*128 + d];
    float e3 = loga1[(size_t)i3*128 + d];
    float e4 = loga1[(size_t)i4*128 + d];
    g2 = fmaf(sc1[l+0], a0, g2); g3 = fmaf(sc2[l+0], e0, g3);
    g2 = fmaf(sc1[l+1], a1, g2); g3 = fmaf(sc2[l+1], e1, g3);
    g2 = fmaf(sc1[l+2], a2, g2); g3 = fmaf(sc2[l+2], e2, g3);
    g2 = fmaf(sc1[l+3], a3, g2); g3 = fmaf(sc2[l+3], e3, g3);
    g2 = fmaf(sc1[l+4], a4, g2); g3 = fmaf(sc2[l+4], e4, g3);
  }
  sg2[d] = g2; sg3[d] = g3;
  __syncthreads();
  if (d < 50){
    float s = 0.f;
    for (int k = 0; k < 128; ++k) s = fmaf(sg2[k], weight[k*50 + d], s);
    s += c1b[0];
    ssel[d] = s;
    out[(size_t)Bn + (size_t)b*100 + d] = s;
  } else if (d >= 64 && d < 114){
    int t = d - 64;
    float s = 0.f;
    for (int k = 0; k < 128; ++k) s = fmaf(sg3[k], weight2[k*50 + t], s);
    s += c2b[0];
    ssel[50 + t] = s;
    out[(size_t)Bn + (size_t)b*100 + 50 + t] = s;
  }
  __syncthreads();
  if (d < 5){
    float s = clsb[d];
    for (int j = 0; j < 100; ++j) s = fmaf(ssel[j], cls[j*5 + d], s);
    spre[d] = s;
  }
  __syncthreads();
  if (d == 0){
    int best = 0; float bv = spre[0];
    #pragma unroll
    for (int k = 1; k < 5; ++k) if (spre[k] > bv){ bv = spre[k]; best = k; }
    out[b] = (float)best;
  }
}

// ---------------------------------------------------------------------------
extern "C" void kernel_launch(void* const* d_in, const int* in_sizes, int n_in,
                              void* d_out, int out_size, void* d_ws, size_t ws_size,
                              hipStream_t stream) {
  const float* A1     = (const float*)d_in[0];
  const int*   rows   = (const int*)  d_in[1];
  const int*   cols   = (const int*)  d_in[2];
  const float* vals   = (const float*)d_in[3];
  const int*   bidx   = (const int*)  d_in[4];
  const float* raw_c  = (const float*)d_in[5];
  const float* nparam = (const float*)d_in[6];
  const float* Lin1   = (const float*)d_in[7];
  const float* Lin1_b = (const float*)d_in[8];
  const float* gc1_w  = (const float*)d_in[9];
  const float* gc1_b  = (const float*)d_in[10];
  const float* gc2_w  = (const float*)d_in[11];
  const float* gc2_b  = (const float*)d_in[12];
  const float* weight = (const float*)d_in[13];
  const float* weight2= (const float*)d_in[14];
  const float* c1w    = (const float*)d_in[15];
  const float* c1b    = (const float*)d_in[16];
  const float* c2w    = (const float*)d_in[17];
  const float* c2b    = (const float*)d_in[18];
  const float* cls    = (const float*)d_in[19];
  const float* clsb   = (const float*)d_in[20];

  int N  = in_sizes[0] / 129;
  int E  = in_sizes[1];
  int Bn = in_sizes[4] / 50;
  size_t NF = (size_t)N * 128;

  // workspace layout (fp32 slots reused across pipeline stages)
  float* S0 = (float*)d_ws;        // L -> h1 -> h2
  float* S1 = S0 + NF;             // T1 -> Lx1
  float* S2 = S1 + NF;             // Tg1 -> T2 -> Lx2
  float* S3 = S2 + NF;             // loga1 (lives to the end)
  int* cnt    = (int*)(S3 + NF);
  int* off    = cnt + N;
  int* cursor = off + N;
  int* bsum   = cursor + N;        // up to 4096 scan partials
  int* ecol   = bsum + 4096;
  float* eval_ = (float*)(ecol + E);

  int rowBlocks  = (N + 3) / 4;    // 4 waves (rows) per 256-thread block
  int gemmBlocks = (N + 63) / 64;
  int G = (N + 256*SCAN_ITEMS - 1) / (256*SCAN_ITEMS);

  hipMemsetAsync(cnt, 0, (size_t)N * sizeof(int), stream);
  stage_a<<<(int)((NF + 255)/256), 256, 0, stream>>>(A1, S0, N);

  hist_k<<<(E+255)/256, 256, 0, stream>>>(rows, cnt, E);
  scan1<<<G, 256, 0, stream>>>(cnt, off, bsum, N);
  scan2<<<1, 64, 0, stream>>>(bsum, G);
  scan3<<<(N+255)/256, 256, 0, stream>>>(off, cursor, bsum, N);
  fill_k<<<(E+255)/256, 256, 0, stream>>>(rows, cols, vals, cursor, ecol, eval_, E);

  // logmap0 col0 == 0  =>  (N,129) @ (129,128) reduces to L @ W[1:,:]
  gemm128<<<gemmBlocks, 256, 0, stream>>>(S0, Lin1 + 128, S1, N);   // T1
  gemm128<<<gemmBlocks, 256, 0, stream>>>(S0, gc1_w + 128, S2, N);  // Tg1
  stage_c<<<rowBlocks, 256, 0, stream>>>(S1, S2, Lin1_b, gc1_b, S3, S0, raw_c, N); // loga1->S3, h1->S0
  seg_x1<<<rowBlocks, 256, 0, stream>>>(S0, off, cnt, ecol, eval_, S3, nparam, S1, N); // Lx1->S1
  gemm128<<<gemmBlocks, 256, 0, stream>>>(S1, gc2_w, S2, N);        // T2->S2
  stage_g<<<rowBlocks, 256, 0, stream>>>(S2, gc2_b, S0, raw_c, N);  // h2->S0
  seg_x2<<<rowBlocks, 256, 0, stream>>>(S0, off, cnt, ecol, eval_, S2, N); // Lx2->S2
  batch_head<<<Bn, 128, 0, stream>>>(S2, S3, bidx, weight, weight2, c1w, c1b,
                                     c2w, c2b, cls, clsb, (float*)d_out, Bn);
}

// Round 4
// 970.782 us; speedup vs baseline: 1.6887x; 1.2643x over previous
//
#include <hip/hip_runtime.h>
#include <math.h>

// ---------------------------------------------------------------------------
// Hyperbolic GCN forward, algebraically collapsed:
//   logmap0(proj(expmap0(u))) == u  (tangent-at-origin roundtrips cancel)
// so only the bias mobius_add chains need hyperbolic math; those use HW
// transcendentals (v_exp/v_log/v_rcp) instead of libm.
// Wave(64)-per-row layout: lane holds dims (2*lane, 2*lane+1); dim0 = time.
// ---------------------------------------------------------------------------

__device__ __forceinline__ float wsum(float x){
  x += __shfl_xor(x, 32);
  x += __shfl_xor(x, 16);
  x += __shfl_xor(x, 8);
  x += __shfl_xor(x, 4);
  x += __shfl_xor(x, 2);
  x += __shfl_xor(x, 1);
  return x;
}

__device__ __forceinline__ void get_c(const float* rc, float& K, float& sK){
  float c = log1pf(expf(rc[0])) + 1e-5f;   // softplus(raw_c) + 1e-5 (once/wave)
  K  = 1.0f / c;
  sK = sqrtf(K);
}

// sinh(x)/x for x >= 0, HW exp + rcp, Taylor-guarded (x is wave-uniform).
__device__ __forceinline__ float sinhx_over_x(float x){
  if (x > 1e-3f){
    float e  = __expf(x);
    float em = __builtin_amdgcn_rcpf(e);
    return 0.5f*(e - em) * __builtin_amdgcn_rcpf(x);
  }
  return 1.0f + x*x*(1.0f/6.0f);
}

__device__ __forceinline__ float fcosh(float x){
  float e  = __expf(x);
  float em = __builtin_amdgcn_rcpf(e);
  return 0.5f*(e + em);
}

__device__ __forceinline__ float facosh(float x){   // x >= 1+1e-7
  return __logf(x + sqrtf(fmaxf(fmaf(x, x, -1.0f), 0.0f)));
}

// proj(expmap0(u)); comp0 of u ignored.
__device__ __forceinline__ float2 hexpmap0(float2 u, int lane, float K, float sK){
  float sx  = lane ? u.x : 0.0f;
  float xn2 = wsum(sx*sx + u.y*u.y);
  float xn  = fmaxf(sqrtf(xn2), 1e-15f);
  float th  = xn / sK;
  float s   = sinhx_over_x(th);          // == sK*sinh(th)/xn
  float rx  = sx * s, ry = u.y * s;
  float rn2 = wsum(rx*rx + ry*ry);
  float p0  = sqrtf(fmaxf(K + rn2, 1e-7f));
  return make_float2(lane ? rx : p0, ry);
}

__device__ __forceinline__ float2 hlogmap0(float2 p, int lane, float K, float sK){
  float p0  = __shfl(p.x, 0);
  float sx  = lane ? p.x : 0.0f;
  float yn2 = wsum(sx*sx + p.y*p.y);
  float yn  = fmaxf(sqrtf(yn2), 1e-15f);
  float th  = fmaxf(p0 / sK, 1.0f + 1e-7f);
  float r   = sK * facosh(th) * __builtin_amdgcn_rcpf(yn);
  return make_float2(lane ? sx*r : 0.0f, p.y * r);
}

// mobius_add(p, bias_pt) where u = logmap0(bias_pt) == spatial(b) (roundtrip).
__device__ __forceinline__ float2 hmobius_add_u(float2 p, float2 u, int lane, float K, float sK){
  float p0  = __shfl(p.x, 0);
  float sx  = lane ? p.x : 0.0f;
  float yn2 = wsum(sx*sx + p.y*p.y);
  float yn  = fmaxf(sqrtf(yn2), 1e-15f);
  float inv = __builtin_amdgcn_rcpf(yn);
  float yhx = sx * inv, yhy = p.y * inv;
  float ux  = lane ? u.x : 0.0f;
  float alpha = wsum(yhx*ux + yhy*u.y) / sK;
  float coef  = alpha * (sK - p0);
  float wx = ux  - coef * yhx;
  float wy = u.y - coef * yhy;
  float pdw = wsum(sx*wx + p.y*wy);
  float w0  = pdw / fmaxf(p0, 1e-7f);
  float spsq  = wsum(wx*wx + wy*wy);
  float md    = spsq - w0*w0;
  float normu = fminf(sqrtf(fmaxf(md, 1e-7f)), 1e6f);
  float th    = fmaxf(normu / sK, 1e-15f);
  float ch    = fcosh(th);
  float sd    = sinhx_over_x(th);
  float rx = ch*p.x + sd*(lane ? wx : w0);
  float ry = ch*p.y + sd*wy;
  float rsx = lane ? rx : 0.0f;
  float rn2 = wsum(rsx*rsx + ry*ry);
  float r0  = sqrtf(fmaxf(K + rn2, 1e-7f));
  return make_float2(lane ? rx : r0, ry);
}

// --------------------------- stage A: L = A1[:,1:] --------------------------
__global__ __launch_bounds__(256) void stage_a(const float* __restrict__ A1,
                                               float* __restrict__ L, int n){
  size_t i = (size_t)blockIdx.x * 256 + threadIdx.x;
  size_t total = (size_t)n * 128;
  if (i < total){
    size_t row = i >> 7; int j = (int)(i & 127);
    L[i] = A1[row*129 + 1 + j];
  }
}

// --------------------------- GEMM  C = A(N,128) @ W(128,128) ---------------
// 128x128 tile / block, 256 threads, 8x8 acc per thread. A stored k-major
// (transposed) in LDS so inner reads are ds_read_b128; k streamed in chunks
// of 16 with register prefetch overlapping compute.
__global__ __launch_bounds__(256) void gemm_tiled(const float* __restrict__ A,
                                                  const float* __restrict__ W,
                                                  float* __restrict__ C, int nrows){
  __shared__ float As[16][132];   // [k][row], +4 pad
  __shared__ float Ws[16][132];   // [k][col], +4 pad (row stride 528B, 16B-aligned)
  int tid = threadIdx.x;
  int r0  = blockIdx.x * 128;
  int tx  = tid & 15, ty = tid >> 4;    // 16x16 thread grid
  float4 aA[2], aW[2];
  int rowA[2], kqA[2], kW[2], cqW[2];
  #pragma unroll
  for (int t = 0; t < 2; ++t){
    int f = tid + t*256;
    rowA[t] = f >> 2; kqA[t] = f & 3;   // A: 128 rows x 4 k-quads
    kW[t]   = f >> 5; cqW[t] = f & 31;  // W: 16 k x 32 col-quads
  }

  auto loadA = [&](int kc){
    #pragma unroll
    for (int t = 0; t < 2; ++t){
      int rg = r0 + rowA[t];
      aA[t] = make_float4(0.f,0.f,0.f,0.f);
      if (rg < nrows) aA[t] = *(const float4*)&A[(size_t)rg*128 + kc*16 + kqA[t]*4];
    }
  };
  auto loadW = [&](int kc){
    #pragma unroll
    for (int t = 0; t < 2; ++t)
      aW[t] = *(const float4*)&W[(size_t)(kc*16 + kW[t])*128 + cqW[t]*4];
  };

  float acc[8][8];
  #pragma unroll
  for (int i = 0; i < 8; ++i)
    #pragma unroll
    for (int j = 0; j < 8; ++j) acc[i][j] = 0.f;

  loadA(0); loadW(0);
  for (int kc = 0; kc < 8; ++kc){
    __syncthreads();
    #pragma unroll
    for (int t = 0; t < 2; ++t){
      As[kqA[t]*4+0][rowA[t]] = aA[t].x;
      As[kqA[t]*4+1][rowA[t]] = aA[t].y;
      As[kqA[t]*4+2][rowA[t]] = aA[t].z;
      As[kqA[t]*4+3][rowA[t]] = aA[t].w;
      *(float4*)&Ws[kW[t]][cqW[t]*4] = aW[t];
    }
    __syncthreads();
    if (kc < 7){ loadA(kc+1); loadW(kc+1); }
    #pragma unroll
    for (int k = 0; k < 16; ++k){
      float4 a0 = *(const float4*)&As[k][ty*8];
      float4 a1 = *(const float4*)&As[k][ty*8+4];
      float4 w0 = *(const float4*)&Ws[k][tx*8];
      float4 w1 = *(const float4*)&Ws[k][tx*8+4];
      float av[8] = {a0.x,a0.y,a0.z,a0.w,a1.x,a1.y,a1.z,a1.w};
      float wv[8] = {w0.x,w0.y,w0.z,w0.w,w1.x,w1.y,w1.z,w1.w};
      #pragma unroll
      for (int i = 0; i < 8; ++i)
        #pragma unroll
        for (int j = 0; j < 8; ++j)
          acc[i][j] = fmaf(av[i], wv[j], acc[i][j]);
    }
  }
  #pragma unroll
  for (int i = 0; i < 8; ++i){
    int rg = r0 + ty*8 + i;
    if (rg < nrows){
      *(float4*)&C[(size_t)rg*128 + tx*8]     = make_float4(acc[i][0],acc[i][1],acc[i][2],acc[i][3]);
      *(float4*)&C[(size_t)rg*128 + tx*8 + 4] = make_float4(acc[i][4],acc[i][5],acc[i][6],acc[i][7]);
    }
  }
}

// --------------------------- stage C ---------------------------------------
__global__ __launch_bounds__(256) void stage_c(const float* __restrict__ T1,
                                               const float* __restrict__ Tg1,
                                               const float* __restrict__ bl,
                                               const float* __restrict__ bg,
                                               float* __restrict__ loga1,
                                               float* __restrict__ h1,
                                               const float* __restrict__ raw_c, int n){
  int row  = (int)((blockIdx.x * blockDim.x + threadIdx.x) >> 6);
  int lane = threadIdx.x & 63;
  if (row >= n) return;
  float K, sK; get_c(raw_c, K, sK);
  size_t base = (size_t)row*128 + 2*lane;
  float2 ul = *(const float2*)&bl[2*lane];
  float2 ug = *(const float2*)&bg[2*lane];

  float2 t1 = *(const float2*)&T1[base];
  float2 p  = hexpmap0(t1, lane, K, sK);
  float2 a1 = hmobius_add_u(p, ul, lane, K, sK);
  float2 la = hlogmap0(a1, lane, K, sK);
  *(float2*)&loga1[base] = la;

  float2 tg = *(const float2*)&Tg1[base];
  float2 pg = hexpmap0(tg, lane, K, sK);
  float2 g  = hmobius_add_u(pg, ug, lane, K, sK);
  float2 hh = hlogmap0(g, lane, K, sK);
  *(float2*)&h1[base] = hh;
}

// --------------------------- stage G ---------------------------------------
__global__ __launch_bounds__(256) void stage_g(const float* __restrict__ T2,
                                               const float* __restrict__ bg2,
                                               float* __restrict__ h2,
                                               const float* __restrict__ raw_c, int n){
  int row  = (int)((blockIdx.x * blockDim.x + threadIdx.x) >> 6);
  int lane = threadIdx.x & 63;
  if (row >= n) return;
  float K, sK; get_c(raw_c, K, sK);
  size_t base = (size_t)row*128 + 2*lane;
  float2 ug = *(const float2*)&bg2[2*lane];
  float2 t2 = *(const float2*)&T2[base];
  float2 p  = hexpmap0(t2, lane, K, sK);
  float2 g  = hmobius_add_u(p, ug, lane, K, sK);
  float2 hh = hlogmap0(g, lane, K, sK);
  *(float2*)&h2[base] = hh;
}

// --------------------------- CSR build -------------------------------------
__global__ void hist_k(const int* __restrict__ rows, int* __restrict__ cnt, int e){
  int i = blockIdx.x * blockDim.x + threadIdx.x;
  if (i < e) atomicAdd(&cnt[rows[i]], 1);
}

#define SCAN_ITEMS 4
__global__ __launch_bounds__(256) void scan1(const int* __restrict__ cnt,
                                             int* __restrict__ off,
                                             int* __restrict__ bsum, int n){
  __shared__ int sh[256];
  int tid = threadIdx.x;
  int base = blockIdx.x * 256 * SCAN_ITEMS + tid * SCAN_ITEMS;
  int v[SCAN_ITEMS]; int s = 0;
  #pragma unroll
  for (int i = 0; i < SCAN_ITEMS; ++i){ int idx = base+i; v[i] = (idx < n) ? cnt[idx] : 0; s += v[i]; }
  sh[tid] = s; __syncthreads();
  for (int o = 1; o < 256; o <<= 1){
    int t = (tid >= o) ? sh[tid - o] : 0; __syncthreads();
    sh[tid] += t; __syncthreads();
  }
  int excl = sh[tid] - s;
  if (tid == 255) bsum[blockIdx.x] = sh[tid];
  int run = excl;
  #pragma unroll
  for (int i = 0; i < SCAN_ITEMS; ++i){ int idx = base+i; if (idx < n) off[idx] = run; run += v[i]; }
}

__global__ void scan2(int* bsum, int G){
  if (threadIdx.x == 0 && blockIdx.x == 0){
    int run = 0;
    for (int i = 0; i < G; ++i){ int t = bsum[i]; bsum[i] = run; run += t; }
  }
}

__global__ void scan3(int* __restrict__ off, int* __restrict__ cursor,
                      const int* __restrict__ bsum, int n){
  int i = blockIdx.x * blockDim.x + threadIdx.x;
  if (i < n){ int o = off[i] + bsum[i / (256*SCAN_ITEMS)]; off[i] = o; cursor[i] = o; }
}

__global__ void fill_k(const int* __restrict__ rows, const int* __restrict__ cols,
                       const float* __restrict__ vals, int* __restrict__ cursor,
                       int* __restrict__ ecol, float* __restrict__ eval_, int e){
  int i = blockIdx.x * blockDim.x + threadIdx.x;
  if (i < e){
    int pos = atomicAdd(&cursor[rows[i]], 1);
    ecol[pos] = cols[i];
    eval_[pos] = vals[i];
  }
}

// --------------------------- seg-sum helper --------------------------------
__device__ __forceinline__ float2 seg_gather(const float* __restrict__ h,
                                             const int* __restrict__ off,
                                             const int* __restrict__ cnt,
                                             const int* __restrict__ ecol,
                                             const float* __restrict__ eval_,
                                             int row, int lane){
  float ax = 0.f, ay = 0.f, bx = 0.f, by = 0.f;
  int st = off[row], deg = cnt[row];
  const float2* __restrict__ hb = (const float2*)h + lane;  // row stride = 64 float2
  for (int b = 0; b < deg; b += 64){
    int k = b + lane;
    int cc = 0; float vv = 0.f;
    if (k < deg){ cc = ecol[st+k]; vv = eval_[st+k]; }
    int m = min(64, deg - b);
    for (int j = 0; j < m; j += 8){
      int   c0=__shfl(cc,j+0), c1=__shfl(cc,j+1), c2=__shfl(cc,j+2), c3=__shfl(cc,j+3);
      int   c4=__shfl(cc,j+4), c5=__shfl(cc,j+5), c6=__shfl(cc,j+6), c7=__shfl(cc,j+7);
      float v0=__shfl(vv,j+0), v1=__shfl(vv,j+1), v2=__shfl(vv,j+2), v3=__shfl(vv,j+3);
      float v4=__shfl(vv,j+4), v5=__shfl(vv,j+5), v6=__shfl(vv,j+6), v7=__shfl(vv,j+7);
      float2 h0 = hb[(size_t)c0*64];
      float2 h1 = hb[(size_t)c1*64];
      float2 h2 = hb[(size_t)c2*64];
      float2 h3 = hb[(size_t)c3*64];
      float2 h4 = hb[(size_t)c4*64];
      float2 h5 = hb[(size_t)c5*64];
      float2 h6 = hb[(size_t)c6*64];
      float2 h7 = hb[(size_t)c7*64];
      ax = fmaf(v0,h0.x,ax); ay = fmaf(v0,h0.y,ay);
      bx = fmaf(v1,h1.x,bx); by = fmaf(v1,h1.y,by);
      ax = fmaf(v2,h2.x,ax); ay = fmaf(v2,h2.y,ay);
      bx = fmaf(v3,h3.x,bx); by = fmaf(v3,h3.y,by);
      ax = fmaf(v4,h4.x,ax); ay = fmaf(v4,h4.y,ay);
      bx = fmaf(v5,h5.x,bx); by = fmaf(v5,h5.y,by);
      ax = fmaf(v6,h6.x,ax); ay = fmaf(v6,h6.y,ay);
      bx = fmaf(v7,h7.x,bx); by = fmaf(v7,h7.y,by);
    }
  }
  return make_float2(ax + bx, ay + by);
}

// --------------------------- seg_x1: Lx1 = (1-n)*segsum(h1) + n*loga1 -------
__global__ __launch_bounds__(256) void seg_x1(const float* __restrict__ h1,
                                              const int* __restrict__ off,
                                              const int* __restrict__ cnt,
                                              const int* __restrict__ ecol,
                                              const float* __restrict__ eval_,
                                              const float* __restrict__ loga1,
                                              const float* __restrict__ nparam,
                                              float* __restrict__ Lx1, int n){
  int row  = (int)((blockIdx.x * blockDim.x + threadIdx.x) >> 6);
  int lane = threadIdx.x & 63;
  if (row >= n) return;
  float2 acc = seg_gather(h1, off, cnt, ecol, eval_, row, lane);
  float nv = nparam[row];
  float2 la1 = *(const float2*)&loga1[(size_t)row*128 + 2*lane];
  float ox = (1.f-nv)*acc.x + nv*la1.x;
  float oy = (1.f-nv)*acc.y + nv*la1.y;
  *(float2*)&Lx1[(size_t)row*128 + 2*lane] = make_float2(ox, oy);
}

// --------------------------- seg_x2: Lx2 = segsum(h2) -----------------------
__global__ __launch_bounds__(256) void seg_x2(const float* __restrict__ h2,
                                              const int* __restrict__ off,
                                              const int* __restrict__ cnt,
                                              const int* __restrict__ ecol,
                                              const float* __restrict__ eval_,
                                              float* __restrict__ Lx2, int n){
  int row  = (int)((blockIdx.x * blockDim.x + threadIdx.x) >> 6);
  int lane = threadIdx.x & 63;
  if (row >= n) return;
  float2 acc = seg_gather(h2, off, cnt, ecol, eval_, row, lane);
  *(float2*)&Lx2[(size_t)row*128 + 2*lane] = acc;
}

// --------------------------- batch head ------------------------------------
__global__ __launch_bounds__(128) void batch_head(const float* __restrict__ Lx2,
                                                  const float* __restrict__ loga1,
                                                  const int* __restrict__ bidx,
                                                  const float* __restrict__ weight,
                                                  const float* __restrict__ weight2,
                                                  const float* __restrict__ c1w,
                                                  const float* __restrict__ c1b,
                                                  const float* __restrict__ c2w,
                                                  const float* __restrict__ c2b,
                                                  const float* __restrict__ cls,
                                                  const float* __restrict__ clsb,
                                                  float* __restrict__ out, int Bn){
  __shared__ float sg2[128], sg3[128], ssel[100], spre[5];
  __shared__ int sbi[50];
  __shared__ float sc1[50], sc2[50];
  int b = blockIdx.x, d = threadIdx.x;
  const int* bi = bidx + (size_t)b * 50;
  if (d < 50){ sbi[d] = bi[d]; sc1[d] = c1w[d]; sc2[d] = c2w[d]; }
  __syncthreads();
  float g2 = 0.f, g3 = 0.f;
  #pragma unroll
  for (int l = 0; l < 50; l += 5){
    int i0 = sbi[l+0], i1 = sbi[l+1], i2 = sbi[l+2], i3 = sbi[l+3], i4 = sbi[l+4];
    float a0 = Lx2[(size_t)i0*128 + d];
    float a1 = Lx2[(size_t)i1*128 + d];
    float a2 = Lx2[(size_t)i2*128 + d];
    float a3 = Lx2[(size_t)i3*128 + d];
    float a4 = Lx2[(size_t)i4*128 + d];
    float e0 = loga1[(size_t)i0*128 + d];
    float e1 = loga1[(size_t)i1*128 + d];
    float e2 = loga1[(size_t)i2*128 + d];
    float e3 = loga1[(size_t)i3*128 + d];
    float e4 = loga1[(size_t)i4*128 + d];
    g2 = fmaf(sc1[l+0], a0, g2); g3 = fmaf(sc2[l+0], e0, g3);
    g2 = fmaf(sc1[l+1], a1, g2); g3 = fmaf(sc2[l+1], e1, g3);
    g2 = fmaf(sc1[l+2], a2, g2); g3 = fmaf(sc2[l+2], e2, g3);
    g2 = fmaf(sc1[l+3], a3, g2); g3 = fmaf(sc2[l+3], e3, g3);
    g2 = fmaf(sc1[l+4], a4, g2); g3 = fmaf(sc2[l+4], e4, g3);
  }
  sg2[d] = g2; sg3[d] = g3;
  __syncthreads();
  if (d < 50){
    float s = 0.f;
    for (int k = 0; k < 128; ++k) s = fmaf(sg2[k], weight[k*50 + d], s);
    s += c1b[0];
    ssel[d] = s;
    out[(size_t)Bn + (size_t)b*100 + d] = s;
  } else if (d >= 64 && d < 114){
    int t = d - 64;
    float s = 0.f;
    for (int k = 0; k < 128; ++k) s = fmaf(sg3[k], weight2[k*50 + t], s);
    s += c2b[0];
    ssel[50 + t] = s;
    out[(size_t)Bn + (size_t)b*100 + 50 + t] = s;
  }
  __syncthreads();
  if (d < 5){
    float s = clsb[d];
    for (int j = 0; j < 100; ++j) s = fmaf(ssel[j], cls[j*5 + d], s);
    spre[d] = s;
  }
  __syncthreads();
  if (d == 0){
    int best = 0; float bv = spre[0];
    #pragma unroll
    for (int k = 1; k < 5; ++k) if (spre[k] > bv){ bv = spre[k]; best = k; }
    out[b] = (float)best;
  }
}

// ---------------------------------------------------------------------------
extern "C" void kernel_launch(void* const* d_in, const int* in_sizes, int n_in,
                              void* d_out, int out_size, void* d_ws, size_t ws_size,
                              hipStream_t stream) {
  const float* A1     = (const float*)d_in[0];
  const int*   rows   = (const int*)  d_in[1];
  const int*   cols   = (const int*)  d_in[2];
  const float* vals   = (const float*)d_in[3];
  const int*   bidx   = (const int*)  d_in[4];
  const float* raw_c  = (const float*)d_in[5];
  const float* nparam = (const float*)d_in[6];
  const float* Lin1   = (const float*)d_in[7];
  const float* Lin1_b = (const float*)d_in[8];
  const float* gc1_w  = (const float*)d_in[9];
  const float* gc1_b  = (const float*)d_in[10];
  const float* gc2_w  = (const float*)d_in[11];
  const float* gc2_b  = (const float*)d_in[12];
  const float* weight = (const float*)d_in[13];
  const float* weight2= (const float*)d_in[14];
  const float* c1w    = (const float*)d_in[15];
  const float* c1b    = (const float*)d_in[16];
  const float* c2w    = (const float*)d_in[17];
  const float* c2b    = (const float*)d_in[18];
  const float* cls    = (const float*)d_in[19];
  const float* clsb   = (const float*)d_in[20];

  int N  = in_sizes[0] / 129;
  int E  = in_sizes[1];
  int Bn = in_sizes[4] / 50;
  size_t NF = (size_t)N * 128;

  // workspace layout (fp32 slots reused across pipeline stages)
  float* S0 = (float*)d_ws;        // L -> h1 -> h2
  float* S1 = S0 + NF;             // T1 -> Lx1
  float* S2 = S1 + NF;             // Tg1 -> T2 -> Lx2
  float* S3 = S2 + NF;             // loga1 (lives to the end)
  int* cnt    = (int*)(S3 + NF);
  int* off    = cnt + N;
  int* cursor = off + N;
  int* bsum   = cursor + N;        // up to 4096 scan partials
  int* ecol   = bsum + 4096;
  float* eval_ = (float*)(ecol + E);

  int rowBlocks  = (N + 3) / 4;    // 4 waves (rows) per 256-thread block
  int gemmBlocks = (N + 127) / 128;
  int G = (N + 256*SCAN_ITEMS - 1) / (256*SCAN_ITEMS);

  hipMemsetAsync(cnt, 0, (size_t)N * sizeof(int), stream);
  stage_a<<<(int)((NF + 255)/256), 256, 0, stream>>>(A1, S0, N);

  hist_k<<<(E+255)/256, 256, 0, stream>>>(rows, cnt, E);
  scan1<<<G, 256, 0, stream>>>(cnt, off, bsum, N);
  scan2<<<1, 64, 0, stream>>>(bsum, G);
  scan3<<<(N+255)/256, 256, 0, stream>>>(off, cursor, bsum, N);
  fill_k<<<(E+255)/256, 256, 0, stream>>>(rows, cols, vals, cursor, ecol, eval_, E);

  // logmap0 col0 == 0  =>  (N,129) @ (129,128) reduces to L @ W[1:,:]
  gemm_tiled<<<gemmBlocks, 256, 0, stream>>>(S0, Lin1 + 128, S1, N);   // T1
  gemm_tiled<<<gemmBlocks, 256, 0, stream>>>(S0, gc1_w + 128, S2, N);  // Tg1
  stage_c<<<rowBlocks, 256, 0, stream>>>(S1, S2, Lin1_b, gc1_b, S3, S0, raw_c, N); // loga1->S3, h1->S0
  seg_x1<<<rowBlocks, 256, 0, stream>>>(S0, off, cnt, ecol, eval_, S3, nparam, S1, N); // Lx1->S1
  gemm_tiled<<<gemmBlocks, 256, 0, stream>>>(S1, gc2_w, S2, N);        // T2->S2
  stage_g<<<rowBlocks, 256, 0, stream>>>(S2, gc2_b, S0, raw_c, N);  // h2->S0
  seg_x2<<<rowBlocks, 256, 0, stream>>>(S0, off, cnt, ecol, eval_, S2, N); // Lx2->S2
  batch_head<<<Bn, 128, 0, stream>>>(S2, S3, bidx, weight, weight2, c1w, c1b,
                                     c2w, c2b, cls, clsb, (float*)d_out, Bn);
}

// Round 5
// 952.435 us; speedup vs baseline: 1.7212x; 1.0193x over previous
//
#include <hip/hip_runtime.h>
#include <math.h>

// ---------------------------------------------------------------------------
// Hyperbolic GCN forward, algebraically collapsed:
//   logmap0(proj(expmap0(u))) == u  (tangent-at-origin roundtrips cancel)
// The bias mobius_add chains are fully scalarized: only 2 wave reductions
// per chain (<t,t> and <t,u>); all other norms derived analytically.
// Wave(64)-per-row layout: lane holds dims (2*lane, 2*lane+1); dim0 = time.
// ---------------------------------------------------------------------------

__device__ __forceinline__ float wsum(float x){
  x += __shfl_xor(x, 32);
  x += __shfl_xor(x, 16);
  x += __shfl_xor(x, 8);
  x += __shfl_xor(x, 4);
  x += __shfl_xor(x, 2);
  x += __shfl_xor(x, 1);
  return x;
}

__device__ __forceinline__ void get_c(const float* rc, float& K, float& sK){
  float c = log1pf(expf(rc[0])) + 1e-5f;   // softplus(raw_c) + 1e-5 (once/wave)
  K  = 1.0f / c;
  sK = sqrtf(K);
}

// sinh(x)/x for x >= 0, HW exp + rcp, Taylor-guarded (x is wave-uniform).
__device__ __forceinline__ float sinhx_over_x(float x){
  if (x > 1e-3f){
    float e  = __expf(x);
    float em = __builtin_amdgcn_rcpf(e);
    return 0.5f*(e - em) * __builtin_amdgcn_rcpf(x);
  }
  return 1.0f + x*x*(1.0f/6.0f);
}

__device__ __forceinline__ float fcosh(float x){
  float e  = __expf(x);
  float em = __builtin_amdgcn_rcpf(e);
  return 0.5f*(e + em);
}

__device__ __forceinline__ float facosh(float x){   // x >= 1+1e-7
  return __logf(x + sqrtf(fmaxf(fmaf(x, x, -1.0f), 0.0f)));
}

// Fused logmap0(mobius_add(proj(expmap0(t)), bias)) given precomputed
// xn2 = ||t_sp||^2, S_tu = <t_sp, u_sp>, uu = ||u_sp||^2 (all wave-uniform).
// t, u must already have comp0 (lane 0 .x) zeroed.
__device__ __forceinline__ float2 chain_post(float2 t, float2 u, float xn2, float S_tu,
                                             float uu, float K, float sK){
  float xn  = fmaxf(sqrtf(xn2), 1e-15f);
  float th  = xn / sK;
  float f   = sinhx_over_x(th);            // expmap0 spatial factor
  float pn2 = f*f*xn2;                     // ||p_sp||^2 (proj keeps spatial)
  float p0  = sqrtf(fmaxf(K + pn2, 1e-7f));
  float S_yu = f * S_tu;                   // <p_sp, u_sp>
  float yn  = fmaxf(sqrtf(pn2), 1e-15f);
  float inv_yn = __builtin_amdgcn_rcpf(yn);
  float alpha = S_yu * inv_yn / sK;
  float coef  = alpha * (sK - p0);
  float cy  = coef * inv_yn;               // coef/yn
  float cyf = cy * f;
  float wx = u.x - cyf*t.x;                // w_sp = u - cy*p_sp
  float wy = u.y - cyf*t.y;
  float pdw  = S_yu - cy*pn2;              // <p_sp, w_sp>
  float spsq = uu - 2.f*cy*S_yu + cy*cy*pn2; // ||w_sp||^2
  float w0 = pdw / fmaxf(p0, 1e-7f);       // proj_tan comp0
  float md = spsq - w0*w0;                 // minkowski dot
  float normu = fminf(sqrtf(fmaxf(md, 1e-7f)), 1e6f);
  float th2 = fmaxf(normu / sK, 1e-15f);
  float ch = fcosh(th2);
  float g  = sinhx_over_x(th2);
  float chf = ch*f;
  float rx = chf*t.x + g*wx;               // result spatial
  float ry = chf*t.y + g*wy;
  float rn2 = ch*ch*pn2 + 2.f*ch*g*pdw + g*g*spsq;
  float r0 = sqrtf(fmaxf(K + rn2, 1e-7f)); // proj comp0
  float ynf = fmaxf(sqrtf(rn2), 1e-15f);
  float thf = fmaxf(r0/sK, 1.f+1e-7f);
  float rf = sK * facosh(thf) * __builtin_amdgcn_rcpf(ynf);
  return make_float2(rx*rf, ry*rf);        // logmap0 spatial (comp0 -> 0)
}

// --------------------------- uu prep: ||b_spatial||^2 for 3 biases ----------
__global__ void uu_prep(const float* __restrict__ b0, const float* __restrict__ b1,
                        const float* __restrict__ b2, float* __restrict__ uu3){
  int lane = threadIdx.x;  // 64
  const float* bs[3] = {b0, b1, b2};
  for (int k = 0; k < 3; ++k){
    float x = lane ? bs[k][2*lane] : 0.0f;
    float y = bs[k][2*lane+1];
    float s = wsum(x*x + y*y);
    if (lane == 0) uu3[k] = s;
  }
}

// --------------------------- stage A: L = A1[:,1:] --------------------------
__global__ __launch_bounds__(256) void stage_a(const float* __restrict__ A1,
                                               float* __restrict__ L, int n){
  size_t i = (size_t)blockIdx.x * 256 + threadIdx.x;
  size_t total = (size_t)n * 128;
  if (i < total){
    size_t row = i >> 7; int j = (int)(i & 127);
    L[i] = A1[row*129 + 1 + j];
  }
}

// --------------------------- GEMM  C = A(N,128) @ W(128,128) ---------------
__global__ __launch_bounds__(256) void gemm_tiled(const float* __restrict__ A,
                                                  const float* __restrict__ W,
                                                  float* __restrict__ C, int nrows){
  __shared__ float As[16][132];
  __shared__ float Ws[16][132];
  int tid = threadIdx.x;
  int r0  = blockIdx.x * 128;
  int tx  = tid & 15, ty = tid >> 4;
  float4 aA[2], aW[2];
  int rowA[2], kqA[2], kW[2], cqW[2];
  #pragma unroll
  for (int t = 0; t < 2; ++t){
    int f = tid + t*256;
    rowA[t] = f >> 2; kqA[t] = f & 3;
    kW[t]   = f >> 5; cqW[t] = f & 31;
  }

  auto loadA = [&](int kc){
    #pragma unroll
    for (int t = 0; t < 2; ++t){
      int rg = r0 + rowA[t];
      aA[t] = make_float4(0.f,0.f,0.f,0.f);
      if (rg < nrows) aA[t] = *(const float4*)&A[(size_t)rg*128 + kc*16 + kqA[t]*4];
    }
  };
  auto loadW = [&](int kc){
    #pragma unroll
    for (int t = 0; t < 2; ++t)
      aW[t] = *(const float4*)&W[(size_t)(kc*16 + kW[t])*128 + cqW[t]*4];
  };

  float acc[8][8];
  #pragma unroll
  for (int i = 0; i < 8; ++i)
    #pragma unroll
    for (int j = 0; j < 8; ++j) acc[i][j] = 0.f;

  loadA(0); loadW(0);
  for (int kc = 0; kc < 8; ++kc){
    __syncthreads();
    #pragma unroll
    for (int t = 0; t < 2; ++t){
      As[kqA[t]*4+0][rowA[t]] = aA[t].x;
      As[kqA[t]*4+1][rowA[t]] = aA[t].y;
      As[kqA[t]*4+2][rowA[t]] = aA[t].z;
      As[kqA[t]*4+3][rowA[t]] = aA[t].w;
      *(float4*)&Ws[kW[t]][cqW[t]*4] = aW[t];
    }
    __syncthreads();
    if (kc < 7){ loadA(kc+1); loadW(kc+1); }
    #pragma unroll
    for (int k = 0; k < 16; ++k){
      float4 a0 = *(const float4*)&As[k][ty*8];
      float4 a1 = *(const float4*)&As[k][ty*8+4];
      float4 w0 = *(const float4*)&Ws[k][tx*8];
      float4 w1 = *(const float4*)&Ws[k][tx*8+4];
      float av[8] = {a0.x,a0.y,a0.z,a0.w,a1.x,a1.y,a1.z,a1.w};
      float wv[8] = {w0.x,w0.y,w0.z,w0.w,w1.x,w1.y,w1.z,w1.w};
      #pragma unroll
      for (int i = 0; i < 8; ++i)
        #pragma unroll
        for (int j = 0; j < 8; ++j)
          acc[i][j] = fmaf(av[i], wv[j], acc[i][j]);
    }
  }
  #pragma unroll
  for (int i = 0; i < 8; ++i){
    int rg = r0 + ty*8 + i;
    if (rg < nrows){
      *(float4*)&C[(size_t)rg*128 + tx*8]     = make_float4(acc[i][0],acc[i][1],acc[i][2],acc[i][3]);
      *(float4*)&C[(size_t)rg*128 + tx*8 + 4] = make_float4(acc[i][4],acc[i][5],acc[i][6],acc[i][7]);
    }
  }
}

// --------------------------- stage C ---------------------------------------
// loga1 = chain(T1, bias_lin1); h1 = chain(Tg1, bias_gc1). 4 interleaved wsums.
__global__ __launch_bounds__(256) void stage_c(const float* __restrict__ T1,
                                               const float* __restrict__ Tg1,
                                               const float* __restrict__ bl,
                                               const float* __restrict__ bg,
                                               const float* __restrict__ uu3,
                                               float* __restrict__ loga1,
                                               float* __restrict__ h1,
                                               const float* __restrict__ raw_c, int n){
  int row  = (int)((blockIdx.x * blockDim.x + threadIdx.x) >> 6);
  int lane = threadIdx.x & 63;
  if (row >= n) return;
  float K, sK; get_c(raw_c, K, sK);
  float uul = uu3[0], uug = uu3[1];
  size_t base = (size_t)row*128 + 2*lane;
  float2 ul = *(const float2*)&bl[2*lane];  if (!lane) ul.x = 0.f;
  float2 ug = *(const float2*)&bg[2*lane];  if (!lane) ug.x = 0.f;
  float2 t1 = *(const float2*)&T1[base];    if (!lane) t1.x = 0.f;
  float2 tg = *(const float2*)&Tg1[base];   if (!lane) tg.x = 0.f;

  float a0 = t1.x*t1.x + t1.y*t1.y;
  float a1 = t1.x*ul.x + t1.y*ul.y;
  float a2 = tg.x*tg.x + tg.y*tg.y;
  float a3 = tg.x*ug.x + tg.y*ug.y;
  #pragma unroll
  for (int m = 32; m >= 1; m >>= 1){
    a0 += __shfl_xor(a0, m); a1 += __shfl_xor(a1, m);
    a2 += __shfl_xor(a2, m); a3 += __shfl_xor(a3, m);
  }

  float2 la = chain_post(t1, ul, a0, a1, uul, K, sK);
  *(float2*)&loga1[base] = la;
  float2 hh = chain_post(tg, ug, a2, a3, uug, K, sK);
  *(float2*)&h1[base] = hh;
}

// --------------------------- stage G ---------------------------------------
__global__ __launch_bounds__(256) void stage_g(const float* __restrict__ T2,
                                               const float* __restrict__ bg2,
                                               const float* __restrict__ uu3,
                                               float* __restrict__ h2,
                                               const float* __restrict__ raw_c, int n){
  int row  = (int)((blockIdx.x * blockDim.x + threadIdx.x) >> 6);
  int lane = threadIdx.x & 63;
  if (row >= n) return;
  float K, sK; get_c(raw_c, K, sK);
  float uug = uu3[2];
  size_t base = (size_t)row*128 + 2*lane;
  float2 ug = *(const float2*)&bg2[2*lane]; if (!lane) ug.x = 0.f;
  float2 t2 = *(const float2*)&T2[base];    if (!lane) t2.x = 0.f;

  float a0 = t2.x*t2.x + t2.y*t2.y;
  float a1 = t2.x*ug.x + t2.y*ug.y;
  #pragma unroll
  for (int m = 32; m >= 1; m >>= 1){
    a0 += __shfl_xor(a0, m); a1 += __shfl_xor(a1, m);
  }
  float2 hh = chain_post(t2, ug, a0, a1, uug, K, sK);
  *(float2*)&h2[base] = hh;
}

// --------------------------- CSR build -------------------------------------
__global__ void hist_k(const int* __restrict__ rows, int* __restrict__ cnt, int e){
  int i = blockIdx.x * blockDim.x + threadIdx.x;
  if (i < e) atomicAdd(&cnt[rows[i]], 1);
}

#define SCAN_ITEMS 4
__global__ __launch_bounds__(256) void scan1(const int* __restrict__ cnt,
                                             int* __restrict__ off,
                                             int* __restrict__ bsum, int n){
  __shared__ int sh[256];
  int tid = threadIdx.x;
  int base = blockIdx.x * 256 * SCAN_ITEMS + tid * SCAN_ITEMS;
  int v[SCAN_ITEMS]; int s = 0;
  #pragma unroll
  for (int i = 0; i < SCAN_ITEMS; ++i){ int idx = base+i; v[i] = (idx < n) ? cnt[idx] : 0; s += v[i]; }
  sh[tid] = s; __syncthreads();
  for (int o = 1; o < 256; o <<= 1){
    int t = (tid >= o) ? sh[tid - o] : 0; __syncthreads();
    sh[tid] += t; __syncthreads();
  }
  int excl = sh[tid] - s;
  if (tid == 255) bsum[blockIdx.x] = sh[tid];
  int run = excl;
  #pragma unroll
  for (int i = 0; i < SCAN_ITEMS; ++i){ int idx = base+i; if (idx < n) off[idx] = run; run += v[i]; }
}

__global__ void scan2(int* bsum, int G){
  if (threadIdx.x == 0 && blockIdx.x == 0){
    int run = 0;
    for (int i = 0; i < G; ++i){ int t = bsum[i]; bsum[i] = run; run += t; }
  }
}

__global__ void scan3(int* __restrict__ off, int* __restrict__ cursor,
                      const int* __restrict__ bsum, int n){
  int i = blockIdx.x * blockDim.x + threadIdx.x;
  if (i < n){ int o = off[i] + bsum[i / (256*SCAN_ITEMS)]; off[i] = o; cursor[i] = o; }
}

__global__ void fill_k(const int* __restrict__ rows, const int* __restrict__ cols,
                       const float* __restrict__ vals, int* __restrict__ cursor,
                       int* __restrict__ ecol, float* __restrict__ eval_, int e){
  int i = blockIdx.x * blockDim.x + threadIdx.x;
  if (i < e){
    int pos = atomicAdd(&cursor[rows[i]], 1);
    ecol[pos] = cols[i];
    eval_[pos] = vals[i];
  }
}

// --------------------------- seg-sum helper --------------------------------
__device__ __forceinline__ float2 seg_gather(const float* __restrict__ h,
                                             const int* __restrict__ off,
                                             const int* __restrict__ cnt,
                                             const int* __restrict__ ecol,
                                             const float* __restrict__ eval_,
                                             int row, int lane){
  float ax = 0.f, ay = 0.f, bx = 0.f, by = 0.f;
  int st = off[row], deg = cnt[row];
  const float2* __restrict__ hb = (const float2*)h + lane;
  for (int b = 0; b < deg; b += 64){
    int k = b + lane;
    int cc = 0; float vv = 0.f;
    if (k < deg){ cc = ecol[st+k]; vv = eval_[st+k]; }
    int m = min(64, deg - b);
    for (int j = 0; j < m; j += 8){
      int   c0=__shfl(cc,j+0), c1=__shfl(cc,j+1), c2=__shfl(cc,j+2), c3=__shfl(cc,j+3);
      int   c4=__shfl(cc,j+4), c5=__shfl(cc,j+5), c6=__shfl(cc,j+6), c7=__shfl(cc,j+7);
      float v0=__shfl(vv,j+0), v1=__shfl(vv,j+1), v2=__shfl(vv,j+2), v3=__shfl(vv,j+3);
      float v4=__shfl(vv,j+4), v5=__shfl(vv,j+5), v6=__shfl(vv,j+6), v7=__shfl(vv,j+7);
      float2 h0 = hb[(size_t)c0*64];
      float2 h1 = hb[(size_t)c1*64];
      float2 h2 = hb[(size_t)c2*64];
      float2 h3 = hb[(size_t)c3*64];
      float2 h4 = hb[(size_t)c4*64];
      float2 h5 = hb[(size_t)c5*64];
      float2 h6 = hb[(size_t)c6*64];
      float2 h7 = hb[(size_t)c7*64];
      ax = fmaf(v0,h0.x,ax); ay = fmaf(v0,h0.y,ay);
      bx = fmaf(v1,h1.x,bx); by = fmaf(v1,h1.y,by);
      ax = fmaf(v2,h2.x,ax); ay = fmaf(v2,h2.y,ay);
      bx = fmaf(v3,h3.x,bx); by = fmaf(v3,h3.y,by);
      ax = fmaf(v4,h4.x,ax); ay = fmaf(v4,h4.y,ay);
      bx = fmaf(v5,h5.x,bx); by = fmaf(v5,h5.y,by);
      ax = fmaf(v6,h6.x,ax); ay = fmaf(v6,h6.y,ay);
      bx = fmaf(v7,h7.x,bx); by = fmaf(v7,h7.y,by);
    }
  }
  return make_float2(ax + bx, ay + by);
}

// --------------------------- seg_x1: Lx1 = (1-n)*segsum(h1) + n*loga1 -------
__global__ __launch_bounds__(256) void seg_x1(const float* __restrict__ h1,
                                              const int* __restrict__ off,
                                              const int* __restrict__ cnt,
                                              const int* __restrict__ ecol,
                                              const float* __restrict__ eval_,
                                              const float* __restrict__ loga1,
                                              const float* __restrict__ nparam,
                                              float* __restrict__ Lx1, int n){
  int row  = (int)((blockIdx.x * blockDim.x + threadIdx.x) >> 6);
  int lane = threadIdx.x & 63;
  if (row >= n) return;
  float2 acc = seg_gather(h1, off, cnt, ecol, eval_, row, lane);
  float nv = nparam[row];
  float2 la1 = *(const float2*)&loga1[(size_t)row*128 + 2*lane];
  float ox = (1.f-nv)*acc.x + nv*la1.x;
  float oy = (1.f-nv)*acc.y + nv*la1.y;
  *(float2*)&Lx1[(size_t)row*128 + 2*lane] = make_float2(ox, oy);
}

// --------------------------- seg_x2: Lx2 = segsum(h2) -----------------------
__global__ __launch_bounds__(256) void seg_x2(const float* __restrict__ h2,
                                              const int* __restrict__ off,
                                              const int* __restrict__ cnt,
                                              const int* __restrict__ ecol,
                                              const float* __restrict__ eval_,
                                              float* __restrict__ Lx2, int n){
  int row  = (int)((blockIdx.x * blockDim.x + threadIdx.x) >> 6);
  int lane = threadIdx.x & 63;
  if (row >= n) return;
  float2 acc = seg_gather(h2, off, cnt, ecol, eval_, row, lane);
  *(float2*)&Lx2[(size_t)row*128 + 2*lane] = acc;
}

// --------------------------- batch head ------------------------------------
__global__ __launch_bounds__(128) void batch_head(const float* __restrict__ Lx2,
                                                  const float* __restrict__ loga1,
                                                  const int* __restrict__ bidx,
                                                  const float* __restrict__ weight,
                                                  const float* __restrict__ weight2,
                                                  const float* __restrict__ c1w,
                                                  const float* __restrict__ c1b,
                                                  const float* __restrict__ c2w,
                                                  const float* __restrict__ c2b,
                                                  const float* __restrict__ cls,
                                                  const float* __restrict__ clsb,
                                                  float* __restrict__ out, int Bn){
  __shared__ float sg2[128], sg3[128], ssel[100], spre[5];
  __shared__ int sbi[50];
  __shared__ float sc1[50], sc2[50];
  int b = blockIdx.x, d = threadIdx.x;
  const int* bi = bidx + (size_t)b * 50;
  if (d < 50){ sbi[d] = bi[d]; sc1[d] = c1w[d]; sc2[d] = c2w[d]; }
  __syncthreads();
  float g2 = 0.f, g3 = 0.f;
  #pragma unroll
  for (int l = 0; l < 50; l += 5){
    int i0 = sbi[l+0], i1 = sbi[l+1], i2 = sbi[l+2], i3 = sbi[l+3], i4 = sbi[l+4];
    float a0 = Lx2[(size_t)i0*128 + d];
    float a1 = Lx2[(size_t)i1*128 + d];
    float a2 = Lx2[(size_t)i2*128 + d];
    float a3 = Lx2[(size_t)i3*128 + d];
    float a4 = Lx2[(size_t)i4*128 + d];
    float e0 = loga1[(size_t)i0*128 + d];
    float e1 = loga1[(size_t)i1*128 + d];
    float e2 = loga1[(size_t)i2*128 + d];
    float e3 = loga1[(size_t)i3*128 + d];
    float e4 = loga1[(size_t)i4*128 + d];
    g2 = fmaf(sc1[l+0], a0, g2); g3 = fmaf(sc2[l+0], e0, g3);
    g2 = fmaf(sc1[l+1], a1, g2); g3 = fmaf(sc2[l+1], e1, g3);
    g2 = fmaf(sc1[l+2], a2, g2); g3 = fmaf(sc2[l+2], e2, g3);
    g2 = fmaf(sc1[l+3], a3, g2); g3 = fmaf(sc2[l+3], e3, g3);
    g2 = fmaf(sc1[l+4], a4, g2); g3 = fmaf(sc2[l+4], e4, g3);
  }
  sg2[d] = g2; sg3[d] = g3;
  __syncthreads();
  if (d < 50){
    float s = 0.f;
    for (int k = 0; k < 128; ++k) s = fmaf(sg2[k], weight[k*50 + d], s);
    s += c1b[0];
    ssel[d] = s;
    out[(size_t)Bn + (size_t)b*100 + d] = s;
  } else if (d >= 64 && d < 114){
    int t = d - 64;
    float s = 0.f;
    for (int k = 0; k < 128; ++k) s = fmaf(sg3[k], weight2[k*50 + t], s);
    s += c2b[0];
    ssel[50 + t] = s;
    out[(size_t)Bn + (size_t)b*100 + 50 + t] = s;
  }
  __syncthreads();
  if (d < 5){
    float s = clsb[d];
    for (int j = 0; j < 100; ++j) s = fmaf(ssel[j], cls[j*5 + d], s);
    spre[d] = s;
  }
  __syncthreads();
  if (d == 0){
    int best = 0; float bv = spre[0];
    #pragma unroll
    for (int k = 1; k < 5; ++k) if (spre[k] > bv){ bv = spre[k]; best = k; }
    out[b] = (float)best;
  }
}

// ---------------------------------------------------------------------------
extern "C" void kernel_launch(void* const* d_in, const int* in_sizes, int n_in,
                              void* d_out, int out_size, void* d_ws, size_t ws_size,
                              hipStream_t stream) {
  const float* A1     = (const float*)d_in[0];
  const int*   rows   = (const int*)  d_in[1];
  const int*   cols   = (const int*)  d_in[2];
  const float* vals   = (const float*)d_in[3];
  const int*   bidx   = (const int*)  d_in[4];
  const float* raw_c  = (const float*)d_in[5];
  const float* nparam = (const float*)d_in[6];
  const float* Lin1   = (const float*)d_in[7];
  const float* Lin1_b = (const float*)d_in[8];
  const float* gc1_w  = (const float*)d_in[9];
  const float* gc1_b  = (const float*)d_in[10];
  const float* gc2_w  = (const float*)d_in[11];
  const float* gc2_b  = (const float*)d_in[12];
  const float* weight = (const float*)d_in[13];
  const float* weight2= (const float*)d_in[14];
  const float* c1w    = (const float*)d_in[15];
  const float* c1b    = (const float*)d_in[16];
  const float* c2w    = (const float*)d_in[17];
  const float* c2b    = (const float*)d_in[18];
  const float* cls    = (const float*)d_in[19];
  const float* clsb   = (const float*)d_in[20];

  int N  = in_sizes[0] / 129;
  int E  = in_sizes[1];
  int Bn = in_sizes[4] / 50;
  size_t NF = (size_t)N * 128;

  // workspace layout (fp32 slots reused across pipeline stages)
  float* S0 = (float*)d_ws;        // L -> h1 -> h2
  float* S1 = S0 + NF;             // T1 -> Lx1
  float* S2 = S1 + NF;             // Tg1 -> T2 -> Lx2
  float* S3 = S2 + NF;             // loga1 (lives to the end)
  int* cnt    = (int*)(S3 + NF);
  int* off    = cnt + N;
  int* cursor = off + N;
  int* bsum   = cursor + N;        // up to 4096 scan partials
  int* ecol   = bsum + 4096;
  float* eval_ = (float*)(ecol + E);
  float* uu3   = eval_ + E;        // 3 floats: ||bias_sp||^2

  int rowBlocks  = (N + 3) / 4;    // 4 waves (rows) per 256-thread block
  int gemmBlocks = (N + 127) / 128;
  int G = (N + 256*SCAN_ITEMS - 1) / (256*SCAN_ITEMS);

  hipMemsetAsync(cnt, 0, (size_t)N * sizeof(int), stream);
  uu_prep<<<1, 64, 0, stream>>>(Lin1_b, gc1_b, gc2_b, uu3);
  stage_a<<<(int)((NF + 255)/256), 256, 0, stream>>>(A1, S0, N);

  hist_k<<<(E+255)/256, 256, 0, stream>>>(rows, cnt, E);
  scan1<<<G, 256, 0, stream>>>(cnt, off, bsum, N);
  scan2<<<1, 64, 0, stream>>>(bsum, G);
  scan3<<<(N+255)/256, 256, 0, stream>>>(off, cursor, bsum, N);
  fill_k<<<(E+255)/256, 256, 0, stream>>>(rows, cols, vals, cursor, ecol, eval_, E);

  // logmap0 col0 == 0  =>  (N,129) @ (129,128) reduces to L @ W[1:,:]
  gemm_tiled<<<gemmBlocks, 256, 0, stream>>>(S0, Lin1 + 128, S1, N);   // T1
  gemm_tiled<<<gemmBlocks, 256, 0, stream>>>(S0, gc1_w + 128, S2, N);  // Tg1
  stage_c<<<rowBlocks, 256, 0, stream>>>(S1, S2, Lin1_b, gc1_b, uu3, S3, S0, raw_c, N); // loga1->S3, h1->S0
  seg_x1<<<rowBlocks, 256, 0, stream>>>(S0, off, cnt, ecol, eval_, S3, nparam, S1, N); // Lx1->S1
  gemm_tiled<<<gemmBlocks, 256, 0, stream>>>(S1, gc2_w, S2, N);        // T2->S2
  stage_g<<<rowBlocks, 256, 0, stream>>>(S2, gc2_b, uu3, S0, raw_c, N);  // h2->S0
  seg_x2<<<rowBlocks, 256, 0, stream>>>(S0, off, cnt, ecol, eval_, S2, N); // Lx2->S2
  batch_head<<<Bn, 128, 0, stream>>>(S2, S3, bidx, weight, weight2, c1w, c1b,
                                     c2w, c2b, cls, clsb, (float*)d_out, Bn);
}

// Round 6
// 728.135 us; speedup vs baseline: 2.2514x; 1.3080x over previous
//
#include <hip/hip_runtime.h>
#include <math.h>

// ---------------------------------------------------------------------------
// Hyperbolic GCN forward, fully collapsed:
//  - logmap0(proj(expmap0(u))) == u  (tangent roundtrips cancel)
//  - the bias chain logmap0(mobius_add(proj(expmap0(t)),b)) is AFFINE per
//    component: out_j = At*t_j + Au*u_j with wave-uniform At,Au from <t,t>,
//    <t,u>. It is fused into the GEMM epilogue (no stage_c/stage_g kernels).
//  - h1/h2 (gather tables) stored as packed bf16: halves seg-gather traffic.
// ---------------------------------------------------------------------------

__device__ __forceinline__ float wsum(float x){
  x += __shfl_xor(x, 32);
  x += __shfl_xor(x, 16);
  x += __shfl_xor(x, 8);
  x += __shfl_xor(x, 4);
  x += __shfl_xor(x, 2);
  x += __shfl_xor(x, 1);
  return x;
}

__device__ __forceinline__ void get_c(const float* rc, float& K, float& sK){
  float c = log1pf(expf(rc[0])) + 1e-5f;   // softplus(raw_c) + 1e-5
  K  = 1.0f / c;
  sK = sqrtf(K);
}

__device__ __forceinline__ float sinhx_over_x(float x){
  if (x > 1e-3f){
    float e  = __expf(x);
    float em = __builtin_amdgcn_rcpf(e);
    return 0.5f*(e - em) * __builtin_amdgcn_rcpf(x);
  }
  return 1.0f + x*x*(1.0f/6.0f);
}

__device__ __forceinline__ float facosh(float x){   // x >= 1+1e-7
  return __logf(x + sqrtf(fmaxf(fmaf(x, x, -1.0f), 0.0f)));
}

// RNE pack of two floats into bf16x2 (lo = x, hi = y)
__device__ __forceinline__ unsigned int pack_bf16(float x, float y){
  unsigned int bx = __float_as_uint(x);
  unsigned int by = __float_as_uint(y);
  bx = (bx + 0x7fffu + ((bx >> 16) & 1u)) >> 16;
  by = (by + 0x7fffu + ((by >> 16) & 1u)) & 0xffff0000u;
  return bx | by;
}

// Chain scalars: given tt=<t,t>, tu=<t,u>, uu=<u,u> (wave-uniform), returns
// At, Au with out_j = At*t_j + Au*u_j  ==  logmap0(mobius_add(exp-chain)).
__device__ __forceinline__ void chain_scalars(float tt, float tu, float uu,
                                              float K, float sK,
                                              float& At, float& Au){
  float xn  = fmaxf(sqrtf(tt), 1e-15f);
  float th  = xn / sK;
  float f   = sinhx_over_x(th);
  float pn2 = f*f*tt;
  float p0  = sqrtf(fmaxf(K + pn2, 1e-7f));
  float S_yu = f * tu;
  float yn  = fmaxf(sqrtf(pn2), 1e-15f);
  float inv_yn = __builtin_amdgcn_rcpf(yn);
  float alpha = S_yu * inv_yn / sK;
  float coef  = alpha * (sK - p0);
  float cy  = coef * inv_yn;
  float cyf = cy * f;
  float pdw  = S_yu - cy*pn2;
  float spsq = uu - 2.f*cy*S_yu + cy*cy*pn2;
  float w0 = pdw / fmaxf(p0, 1e-7f);
  float md = spsq - w0*w0;
  float normu = fminf(sqrtf(fmaxf(md, 1e-7f)), 1e6f);
  float th2 = fmaxf(normu / sK, 1e-15f);
  float e  = __expf(th2);
  float em = __builtin_amdgcn_rcpf(e);
  float ch = 0.5f*(e + em);
  float g  = (th2 > 1e-3f) ? 0.5f*(e - em)*__builtin_amdgcn_rcpf(th2)
                           : 1.0f + th2*th2*(1.0f/6.0f);
  float rn2 = ch*ch*pn2 + 2.f*ch*g*pdw + g*g*spsq;
  float r0 = sqrtf(fmaxf(K + rn2, 1e-7f));
  float ynf = fmaxf(sqrtf(rn2), 1e-15f);
  float thf = fmaxf(r0/sK, 1.f+1e-7f);
  float rf = sK * facosh(thf) * __builtin_amdgcn_rcpf(ynf);
  At = rf*(ch*f - g*cyf);
  Au = rf*g;
}

// --------------------------- uu prep: ||b_spatial||^2 for 3 biases ----------
__global__ void uu_prep(const float* __restrict__ b0, const float* __restrict__ b1,
                        const float* __restrict__ b2, float* __restrict__ uu3){
  int lane = threadIdx.x;  // 64
  const float* bs[3] = {b0, b1, b2};
  for (int k = 0; k < 3; ++k){
    float x = lane ? bs[k][2*lane] : 0.0f;
    float y = bs[k][2*lane+1];
    float s = wsum(x*x + y*y);
    if (lane == 0) uu3[k] = s;
  }
}

// --------------------------- stage A: L = A1[:,1:] --------------------------
__global__ __launch_bounds__(256) void stage_a(const float* __restrict__ A1,
                                               float* __restrict__ L, int n){
  size_t i = (size_t)blockIdx.x * 256 + threadIdx.x;
  size_t total = (size_t)n * 128;
  if (i < total){
    size_t row = i >> 7; int j = (int)(i & 127);
    L[i] = A1[row*129 + 1 + j];
  }
}

// --------------------------- GEMM + fused chain epilogue --------------------
// C_tile = A(N,128) @ W(128,128), then out_j = At*C_j + Au*u_j per row.
// mode 0: write fp32 to outF; mode 1: write packed bf16 to outH.
__global__ __launch_bounds__(256) void gemm_chain(const float* __restrict__ A,
                                                  const float* __restrict__ W,
                                                  const float* __restrict__ bias,
                                                  const float* __restrict__ uu3, int uuidx,
                                                  const float* __restrict__ raw_c,
                                                  float* __restrict__ outF,
                                                  unsigned int* __restrict__ outH,
                                                  int mode, int nrows){
  __shared__ float As[16][132];
  __shared__ float Ws[16][132];
  int tid = threadIdx.x;
  int r0  = blockIdx.x * 128;
  int tx  = tid & 15, ty = tid >> 4;
  float4 aA[2], aW[2];
  int rowA[2], kqA[2], kW[2], cqW[2];
  #pragma unroll
  for (int t = 0; t < 2; ++t){
    int f = tid + t*256;
    rowA[t] = f >> 2; kqA[t] = f & 3;
    kW[t]   = f >> 5; cqW[t] = f & 31;
  }

  auto loadA = [&](int kc){
    #pragma unroll
    for (int t = 0; t < 2; ++t){
      int rg = r0 + rowA[t];
      aA[t] = make_float4(0.f,0.f,0.f,0.f);
      if (rg < nrows) aA[t] = *(const float4*)&A[(size_t)rg*128 + kc*16 + kqA[t]*4];
    }
  };
  auto loadW = [&](int kc){
    #pragma unroll
    for (int t = 0; t < 2; ++t)
      aW[t] = *(const float4*)&W[(size_t)(kc*16 + kW[t])*128 + cqW[t]*4];
  };

  float acc[8][8];
  #pragma unroll
  for (int i = 0; i < 8; ++i)
    #pragma unroll
    for (int j = 0; j < 8; ++j) acc[i][j] = 0.f;

  loadA(0); loadW(0);
  for (int kc = 0; kc < 8; ++kc){
    __syncthreads();
    #pragma unroll
    for (int t = 0; t < 2; ++t){
      As[kqA[t]*4+0][rowA[t]] = aA[t].x;
      As[kqA[t]*4+1][rowA[t]] = aA[t].y;
      As[kqA[t]*4+2][rowA[t]] = aA[t].z;
      As[kqA[t]*4+3][rowA[t]] = aA[t].w;
      *(float4*)&Ws[kW[t]][cqW[t]*4] = aW[t];
    }
    __syncthreads();
    if (kc < 7){ loadA(kc+1); loadW(kc+1); }
    #pragma unroll
    for (int k = 0; k < 16; ++k){
      float4 a0 = *(const float4*)&As[k][ty*8];
      float4 a1 = *(const float4*)&As[k][ty*8+4];
      float4 w0 = *(const float4*)&Ws[k][tx*8];
      float4 w1 = *(const float4*)&Ws[k][tx*8+4];
      float av[8] = {a0.x,a0.y,a0.z,a0.w,a1.x,a1.y,a1.z,a1.w};
      float wv[8] = {w0.x,w0.y,w0.z,w0.w,w1.x,w1.y,w1.z,w1.w};
      #pragma unroll
      for (int i = 0; i < 8; ++i)
        #pragma unroll
        for (int j = 0; j < 8; ++j)
          acc[i][j] = fmaf(av[i], wv[j], acc[i][j]);
    }
  }

  // ---- fused chain epilogue ----
  float K, sK; get_c(raw_c, K, sK);
  float uu = uu3[uuidx];
  float uv[8];
  #pragma unroll
  for (int j = 0; j < 8; ++j){
    int col = tx*8 + j;
    uv[j] = (col == 0) ? 0.f : bias[col];   // comp0 (time) dropped
  }
  if (tx == 0){
    #pragma unroll
    for (int i = 0; i < 8; ++i) acc[i][0] = 0.f;  // t comp0 dropped
  }
  #pragma unroll
  for (int i = 0; i < 8; ++i){
    float tt = 0.f, tu = 0.f;
    #pragma unroll
    for (int j = 0; j < 8; ++j){
      tt = fmaf(acc[i][j], acc[i][j], tt);
      tu = fmaf(acc[i][j], uv[j], tu);
    }
    #pragma unroll
    for (int m = 1; m <= 8; m <<= 1){        // reduce across the 16 row-threads
      tt += __shfl_xor(tt, m);
      tu += __shfl_xor(tu, m);
    }
    float At, Au; chain_scalars(tt, tu, uu, K, sK, At, Au);
    int rg = r0 + ty*8 + i;
    if (rg < nrows){
      float o[8];
      #pragma unroll
      for (int j = 0; j < 8; ++j) o[j] = fmaf(At, acc[i][j], Au*uv[j]);
      if (mode == 0){
        *(float4*)&outF[(size_t)rg*128 + tx*8]     = make_float4(o[0],o[1],o[2],o[3]);
        *(float4*)&outF[(size_t)rg*128 + tx*8 + 4] = make_float4(o[4],o[5],o[6],o[7]);
      } else {
        uint4 pk;
        pk.x = pack_bf16(o[0], o[1]);
        pk.y = pack_bf16(o[2], o[3]);
        pk.z = pack_bf16(o[4], o[5]);
        pk.w = pack_bf16(o[6], o[7]);
        *(uint4*)&outH[(size_t)rg*64 + tx*4] = pk;
      }
    }
  }
}

// --------------------------- CSR build -------------------------------------
__global__ void hist_k(const int* __restrict__ rows, int* __restrict__ cnt, int e){
  int i = blockIdx.x * blockDim.x + threadIdx.x;
  if (i < e) atomicAdd(&cnt[rows[i]], 1);
}

#define SCAN_ITEMS 4
__global__ __launch_bounds__(256) void scan1(const int* __restrict__ cnt,
                                             int* __restrict__ off,
                                             int* __restrict__ bsum, int n){
  __shared__ int sh[256];
  int tid = threadIdx.x;
  int base = blockIdx.x * 256 * SCAN_ITEMS + tid * SCAN_ITEMS;
  int v[SCAN_ITEMS]; int s = 0;
  #pragma unroll
  for (int i = 0; i < SCAN_ITEMS; ++i){ int idx = base+i; v[i] = (idx < n) ? cnt[idx] : 0; s += v[i]; }
  sh[tid] = s; __syncthreads();
  for (int o = 1; o < 256; o <<= 1){
    int t = (tid >= o) ? sh[tid - o] : 0; __syncthreads();
    sh[tid] += t; __syncthreads();
  }
  int excl = sh[tid] - s;
  if (tid == 255) bsum[blockIdx.x] = sh[tid];
  int run = excl;
  #pragma unroll
  for (int i = 0; i < SCAN_ITEMS; ++i){ int idx = base+i; if (idx < n) off[idx] = run; run += v[i]; }
}

__global__ void scan2(int* bsum, int G){
  if (threadIdx.x == 0 && blockIdx.x == 0){
    int run = 0;
    for (int i = 0; i < G; ++i){ int t = bsum[i]; bsum[i] = run; run += t; }
  }
}

__global__ void scan3(int* __restrict__ off, int* __restrict__ cursor,
                      const int* __restrict__ bsum, int n){
  int i = blockIdx.x * blockDim.x + threadIdx.x;
  if (i < n){ int o = off[i] + bsum[i / (256*SCAN_ITEMS)]; off[i] = o; cursor[i] = o; }
}

__global__ void fill_k(const int* __restrict__ rows, const int* __restrict__ cols,
                       const float* __restrict__ vals, int* __restrict__ cursor,
                       int* __restrict__ ecol, float* __restrict__ eval_, int e){
  int i = blockIdx.x * blockDim.x + threadIdx.x;
  if (i < e){
    int pos = atomicAdd(&cursor[rows[i]], 1);
    ecol[pos] = cols[i];
    eval_[pos] = vals[i];
  }
}

// --------------------------- seg-sum (bf16 table) ---------------------------
// 8-deep pipeline; padded lanes carry (c=0,v=0) so no tail (adds 0*row0).
__device__ __forceinline__ float2 seg_gather_bf16(const unsigned int* __restrict__ h,
                                                  const int* __restrict__ off,
                                                  const int* __restrict__ cnt,
                                                  const int* __restrict__ ecol,
                                                  const float* __restrict__ eval_,
                                                  int row, int lane){
  float ax = 0.f, ay = 0.f, bx = 0.f, by = 0.f;
  int st = off[row], deg = cnt[row];
  const unsigned int* __restrict__ hb = h + lane;   // row stride = 64 uints
  for (int b = 0; b < deg; b += 64){
    int k = b + lane;
    int cc = 0; float vv = 0.f;
    if (k < deg){ cc = ecol[st+k]; vv = eval_[st+k]; }
    int m = min(64, deg - b);
    for (int j = 0; j < m; j += 8){
      int   c0=__shfl(cc,j+0), c1=__shfl(cc,j+1), c2=__shfl(cc,j+2), c3=__shfl(cc,j+3);
      int   c4=__shfl(cc,j+4), c5=__shfl(cc,j+5), c6=__shfl(cc,j+6), c7=__shfl(cc,j+7);
      float v0=__shfl(vv,j+0), v1=__shfl(vv,j+1), v2=__shfl(vv,j+2), v3=__shfl(vv,j+3);
      float v4=__shfl(vv,j+4), v5=__shfl(vv,j+5), v6=__shfl(vv,j+6), v7=__shfl(vv,j+7);
      unsigned int p0 = hb[(size_t)c0*64];
      unsigned int p1 = hb[(size_t)c1*64];
      unsigned int p2 = hb[(size_t)c2*64];
      unsigned int p3 = hb[(size_t)c3*64];
      unsigned int p4 = hb[(size_t)c4*64];
      unsigned int p5 = hb[(size_t)c5*64];
      unsigned int p6 = hb[(size_t)c6*64];
      unsigned int p7 = hb[(size_t)c7*64];
      ax = fmaf(v0, __uint_as_float(p0<<16), ax); ay = fmaf(v0, __uint_as_float(p0&0xffff0000u), ay);
      bx = fmaf(v1, __uint_as_float(p1<<16), bx); by = fmaf(v1, __uint_as_float(p1&0xffff0000u), by);
      ax = fmaf(v2, __uint_as_float(p2<<16), ax); ay = fmaf(v2, __uint_as_float(p2&0xffff0000u), ay);
      bx = fmaf(v3, __uint_as_float(p3<<16), bx); by = fmaf(v3, __uint_as_float(p3&0xffff0000u), by);
      ax = fmaf(v4, __uint_as_float(p4<<16), ax); ay = fmaf(v4, __uint_as_float(p4&0xffff0000u), ay);
      bx = fmaf(v5, __uint_as_float(p5<<16), bx); by = fmaf(v5, __uint_as_float(p5&0xffff0000u), by);
      ax = fmaf(v6, __uint_as_float(p6<<16), ax); ay = fmaf(v6, __uint_as_float(p6&0xffff0000u), ay);
      bx = fmaf(v7, __uint_as_float(p7<<16), bx); by = fmaf(v7, __uint_as_float(p7&0xffff0000u), by);
    }
  }
  return make_float2(ax + bx, ay + by);
}

// --------------------------- seg_x1: Lx1 = (1-n)*segsum(h1) + n*loga1 -------
__global__ __launch_bounds__(256) void seg_x1(const unsigned int* __restrict__ h1,
                                              const int* __restrict__ off,
                                              const int* __restrict__ cnt,
                                              const int* __restrict__ ecol,
                                              const float* __restrict__ eval_,
                                              const float* __restrict__ loga1,
                                              const float* __restrict__ nparam,
                                              float* __restrict__ Lx1, int n){
  int row  = (int)((blockIdx.x * blockDim.x + threadIdx.x) >> 6);
  int lane = threadIdx.x & 63;
  if (row >= n) return;
  float2 acc = seg_gather_bf16(h1, off, cnt, ecol, eval_, row, lane);
  float nv = nparam[row];
  float2 la1 = *(const float2*)&loga1[(size_t)row*128 + 2*lane];
  float ox = (1.f-nv)*acc.x + nv*la1.x;
  float oy = (1.f-nv)*acc.y + nv*la1.y;
  *(float2*)&Lx1[(size_t)row*128 + 2*lane] = make_float2(ox, oy);
}

// --------------------------- seg_x2: Lx2 = segsum(h2) -----------------------
__global__ __launch_bounds__(256) void seg_x2(const unsigned int* __restrict__ h2,
                                              const int* __restrict__ off,
                                              const int* __restrict__ cnt,
                                              const int* __restrict__ ecol,
                                              const float* __restrict__ eval_,
                                              float* __restrict__ Lx2, int n){
  int row  = (int)((blockIdx.x * blockDim.x + threadIdx.x) >> 6);
  int lane = threadIdx.x & 63;
  if (row >= n) return;
  float2 acc = seg_gather_bf16(h2, off, cnt, ecol, eval_, row, lane);
  *(float2*)&Lx2[(size_t)row*128 + 2*lane] = acc;
}

// --------------------------- batch head ------------------------------------
__global__ __launch_bounds__(128) void batch_head(const float* __restrict__ Lx2,
                                                  const float* __restrict__ loga1,
                                                  const int* __restrict__ bidx,
                                                  const float* __restrict__ weight,
                                                  const float* __restrict__ weight2,
                                                  const float* __restrict__ c1w,
                                                  const float* __restrict__ c1b,
                                                  const float* __restrict__ c2w,
                                                  const float* __restrict__ c2b,
                                                  const float* __restrict__ cls,
                                                  const float* __restrict__ clsb,
                                                  float* __restrict__ out, int Bn){
  __shared__ float sg2[128], sg3[128], ssel[100], spre[5];
  __shared__ int sbi[50];
  __shared__ float sc1[50], sc2[50];
  int b = blockIdx.x, d = threadIdx.x;
  const int* bi = bidx + (size_t)b * 50;
  if (d < 50){ sbi[d] = bi[d]; sc1[d] = c1w[d]; sc2[d] = c2w[d]; }
  __syncthreads();
  float g2 = 0.f, g3 = 0.f;
  #pragma unroll
  for (int l = 0; l < 50; l += 5){
    int i0 = sbi[l+0], i1 = sbi[l+1], i2 = sbi[l+2], i3 = sbi[l+3], i4 = sbi[l+4];
    float a0 = Lx2[(size_t)i0*128 + d];
    float a1 = Lx2[(size_t)i1*128 + d];
    float a2 = Lx2[(size_t)i2*128 + d];
    float a3 = Lx2[(size_t)i3*128 + d];
    float a4 = Lx2[(size_t)i4*128 + d];
    float e0 = loga1[(size_t)i0*128 + d];
    float e1 = loga1[(size_t)i1*128 + d];
    float e2 = loga1[(size_t)i2*128 + d];
    float e3 = loga1[(size_t)i3*128 + d];
    float e4 = loga1[(size_t)i4*128 + d];
    g2 = fmaf(sc1[l+0], a0, g2); g3 = fmaf(sc2[l+0], e0, g3);
    g2 = fmaf(sc1[l+1], a1, g2); g3 = fmaf(sc2[l+1], e1, g3);
    g2 = fmaf(sc1[l+2], a2, g2); g3 = fmaf(sc2[l+2], e2, g3);
    g2 = fmaf(sc1[l+3], a3, g2); g3 = fmaf(sc2[l+3], e3, g3);
    g2 = fmaf(sc1[l+4], a4, g2); g3 = fmaf(sc2[l+4], e4, g3);
  }
  sg2[d] = g2; sg3[d] = g3;
  __syncthreads();
  if (d < 50){
    float s = 0.f;
    for (int k = 0; k < 128; ++k) s = fmaf(sg2[k], weight[k*50 + d], s);
    s += c1b[0];
    ssel[d] = s;
    out[(size_t)Bn + (size_t)b*100 + d] = s;
  } else if (d >= 64 && d < 114){
    int t = d - 64;
    float s = 0.f;
    for (int k = 0; k < 128; ++k) s = fmaf(sg3[k], weight2[k*50 + t], s);
    s += c2b[0];
    ssel[50 + t] = s;
    out[(size_t)Bn + (size_t)b*100 + 50 + t] = s;
  }
  __syncthreads();
  if (d < 5){
    float s = clsb[d];
    for (int j = 0; j < 100; ++j) s = fmaf(ssel[j], cls[j*5 + d], s);
    spre[d] = s;
  }
  __syncthreads();
  if (d == 0){
    int best = 0; float bv = spre[0];
    #pragma unroll
    for (int k = 1; k < 5; ++k) if (spre[k] > bv){ bv = spre[k]; best = k; }
    out[b] = (float)best;
  }
}

// ---------------------------------------------------------------------------
extern "C" void kernel_launch(void* const* d_in, const int* in_sizes, int n_in,
                              void* d_out, int out_size, void* d_ws, size_t ws_size,
                              hipStream_t stream) {
  const float* A1     = (const float*)d_in[0];
  const int*   rows   = (const int*)  d_in[1];
  const int*   cols   = (const int*)  d_in[2];
  const float* vals   = (const float*)d_in[3];
  const int*   bidx   = (const int*)  d_in[4];
  const float* raw_c  = (const float*)d_in[5];
  const float* nparam = (const float*)d_in[6];
  const float* Lin1   = (const float*)d_in[7];
  const float* Lin1_b = (const float*)d_in[8];
  const float* gc1_w  = (const float*)d_in[9];
  const float* gc1_b  = (const float*)d_in[10];
  const float* gc2_w  = (const float*)d_in[11];
  const float* gc2_b  = (const float*)d_in[12];
  const float* weight = (const float*)d_in[13];
  const float* weight2= (const float*)d_in[14];
  const float* c1w    = (const float*)d_in[15];
  const float* c1b    = (const float*)d_in[16];
  const float* c2w    = (const float*)d_in[17];
  const float* c2b    = (const float*)d_in[18];
  const float* cls    = (const float*)d_in[19];
  const float* clsb   = (const float*)d_in[20];

  int N  = in_sizes[0] / 129;
  int E  = in_sizes[1];
  int Bn = in_sizes[4] / 50;
  size_t NF = (size_t)N * 128;

  // workspace layout
  float* S0 = (float*)d_ws;            // L -> Lx2
  float* S1 = S0 + NF;                 // Lx1
  float* S3 = S1 + NF;                 // loga1 (lives to the end)
  unsigned int* Hb = (unsigned int*)(S3 + NF);  // bf16 h1 -> h2 (NF/2 uints)
  int* cnt    = (int*)(Hb + NF/2);
  int* off    = cnt + N;
  int* cursor = off + N;
  int* bsum   = cursor + N;            // up to 4096 scan partials
  int* ecol   = bsum + 4096;
  float* eval_ = (float*)(ecol + E);
  float* uu3   = eval_ + E;            // 3 floats: ||bias_sp||^2

  int rowBlocks  = (N + 3) / 4;        // 4 waves (rows) per 256-thread block
  int gemmBlocks = (N + 127) / 128;
  int G = (N + 256*SCAN_ITEMS - 1) / (256*SCAN_ITEMS);

  hipMemsetAsync(cnt, 0, (size_t)N * sizeof(int), stream);
  uu_prep<<<1, 64, 0, stream>>>(Lin1_b, gc1_b, gc2_b, uu3);
  stage_a<<<(int)((NF + 255)/256), 256, 0, stream>>>(A1, S0, N);

  hist_k<<<(E+255)/256, 256, 0, stream>>>(rows, cnt, E);
  scan1<<<G, 256, 0, stream>>>(cnt, off, bsum, N);
  scan2<<<1, 64, 0, stream>>>(bsum, G);
  scan3<<<(N+255)/256, 256, 0, stream>>>(off, cursor, bsum, N);
  fill_k<<<(E+255)/256, 256, 0, stream>>>(rows, cols, vals, cursor, ecol, eval_, E);

  // loga1 = chain(L@Lin1[1:,:], lin1_b)           (fp32)
  gemm_chain<<<gemmBlocks, 256, 0, stream>>>(S0, Lin1 + 128, Lin1_b, uu3, 0,
                                             raw_c, S3, (unsigned int*)nullptr, 0, N);
  // h1 = chain(L@gc1_w[1:,:], gc1_b)              (bf16)
  gemm_chain<<<gemmBlocks, 256, 0, stream>>>(S0, gc1_w + 128, gc1_b, uu3, 1,
                                             raw_c, (float*)nullptr, Hb, 1, N);
  seg_x1<<<rowBlocks, 256, 0, stream>>>(Hb, off, cnt, ecol, eval_, S3, nparam, S1, N);
  // h2 = chain(Lx1@gc2_w, gc2_b)                  (bf16; Lx1 comp0 == 0)
  gemm_chain<<<gemmBlocks, 256, 0, stream>>>(S1, gc2_w, gc2_b, uu3, 2,
                                             raw_c, (float*)nullptr, Hb, 1, N);
  seg_x2<<<rowBlocks, 256, 0, stream>>>(Hb, off, cnt, ecol, eval_, S0, N);  // Lx2 -> S0
  batch_head<<<Bn, 128, 0, stream>>>(S0, S3, bidx, weight, weight2, c1w, c1b,
                                     c2w, c2b, cls, clsb, (float*)d_out, Bn);
}

// Round 8
// 715.163 us; speedup vs baseline: 2.2922x; 1.0181x over previous
//
#include <hip/hip_runtime.h>
#include <math.h>

// ---------------------------------------------------------------------------
// Hyperbolic GCN forward, fully collapsed:
//  - logmap0(proj(expmap0(u))) == u  (tangent roundtrips cancel)
//  - bias chain logmap0(mobius_add(proj(expmap0(t)),b)) is AFFINE per
//    component: out_j = At*t_j + Au*u_j (At,Au wave-uniform from <t,t>,<t,u>)
//    fused into the GEMM epilogue.
//  - h1/h2 (segment-sum tables) packed bf16: error averages over the edge sum.
//    loga1 / Lx2 stay FP32 — they feed `sel` linearly; bf16 there flips argmax
//    (round 7 failure).
//  - CSR edge records packed int2 (col,val): one 8B store in fill, one 8B
//    load in gather (halves scatter write-amplification).
// ---------------------------------------------------------------------------

__device__ __forceinline__ float wsum(float x){
  x += __shfl_xor(x, 32);
  x += __shfl_xor(x, 16);
  x += __shfl_xor(x, 8);
  x += __shfl_xor(x, 4);
  x += __shfl_xor(x, 2);
  x += __shfl_xor(x, 1);
  return x;
}

__device__ __forceinline__ void get_c(const float* rc, float& K, float& sK){
  float c = log1pf(expf(rc[0])) + 1e-5f;   // softplus(raw_c) + 1e-5
  K  = 1.0f / c;
  sK = sqrtf(K);
}

__device__ __forceinline__ float sinhx_over_x(float x){
  if (x > 1e-3f){
    float e  = __expf(x);
    float em = __builtin_amdgcn_rcpf(e);
    return 0.5f*(e - em) * __builtin_amdgcn_rcpf(x);
  }
  return 1.0f + x*x*(1.0f/6.0f);
}

__device__ __forceinline__ float facosh(float x){   // x >= 1+1e-7
  return __logf(x + sqrtf(fmaxf(fmaf(x, x, -1.0f), 0.0f)));
}

// RNE pack of two floats into bf16x2 (lo = x, hi = y)
__device__ __forceinline__ unsigned int pack_bf16(float x, float y){
  unsigned int bx = __float_as_uint(x);
  unsigned int by = __float_as_uint(y);
  bx = (bx + 0x7fffu + ((bx >> 16) & 1u)) >> 16;
  by = (by + 0x7fffu + ((by >> 16) & 1u)) & 0xffff0000u;
  return bx | by;
}
__device__ __forceinline__ float bf_lo(unsigned int p){ return __uint_as_float(p << 16); }
__device__ __forceinline__ float bf_hi(unsigned int p){ return __uint_as_float(p & 0xffff0000u); }

// Chain scalars: out_j = At*t_j + Au*u_j == logmap0(mobius_add(exp-chain)).
__device__ __forceinline__ void chain_scalars(float tt, float tu, float uu,
                                              float K, float sK,
                                              float& At, float& Au){
  float xn  = fmaxf(sqrtf(tt), 1e-15f);
  float th  = xn / sK;
  float f   = sinhx_over_x(th);
  float pn2 = f*f*tt;
  float p0  = sqrtf(fmaxf(K + pn2, 1e-7f));
  float S_yu = f * tu;
  float yn  = fmaxf(sqrtf(pn2), 1e-15f);
  float inv_yn = __builtin_amdgcn_rcpf(yn);
  float alpha = S_yu * inv_yn / sK;
  float coef  = alpha * (sK - p0);
  float cy  = coef * inv_yn;
  float cyf = cy * f;
  float pdw  = S_yu - cy*pn2;
  float spsq = uu - 2.f*cy*S_yu + cy*cy*pn2;
  float w0 = pdw / fmaxf(p0, 1e-7f);
  float md = spsq - w0*w0;
  float normu = fminf(sqrtf(fmaxf(md, 1e-7f)), 1e6f);
  float th2 = fmaxf(normu / sK, 1e-15f);
  float e  = __expf(th2);
  float em = __builtin_amdgcn_rcpf(e);
  float ch = 0.5f*(e + em);
  float g  = (th2 > 1e-3f) ? 0.5f*(e - em)*__builtin_amdgcn_rcpf(th2)
                           : 1.0f + th2*th2*(1.0f/6.0f);
  float rn2 = ch*ch*pn2 + 2.f*ch*g*pdw + g*g*spsq;
  float r0 = sqrtf(fmaxf(K + rn2, 1e-7f));
  float ynf = fmaxf(sqrtf(rn2), 1e-15f);
  float thf = fmaxf(r0/sK, 1.f+1e-7f);
  float rf = sK * facosh(thf) * __builtin_amdgcn_rcpf(ynf);
  At = rf*(ch*f - g*cyf);
  Au = rf*g;
}

// --------------------------- stage A: L = A1[:,1:]; + cnt zero + uu_prep ----
__global__ __launch_bounds__(256) void stage_a(const float* __restrict__ A1,
                                               float* __restrict__ L,
                                               int* __restrict__ cnt,
                                               const float* __restrict__ b0,
                                               const float* __restrict__ b1,
                                               const float* __restrict__ b2,
                                               float* __restrict__ uu3, int n){
  size_t i = (size_t)blockIdx.x * 256 + threadIdx.x;
  size_t total = (size_t)n * 128;
  if (i < total){
    size_t row = i >> 7; int j = (int)(i & 127);
    L[i] = A1[row*129 + 1 + j];
  }
  if (i < (size_t)n) cnt[i] = 0;
  if (blockIdx.x == 0 && threadIdx.x < 64){
    int lane = threadIdx.x;
    const float* bs[3] = {b0, b1, b2};
    for (int k = 0; k < 3; ++k){
      float x = lane ? bs[k][2*lane] : 0.0f;
      float y = bs[k][2*lane+1];
      float s = wsum(x*x + y*y);
      if (lane == 0) uu3[k] = s;
    }
  }
}

// --------------------------- GEMM + fused chain epilogue --------------------
// mode 0: fp32 out to outF; mode 1: packed bf16 to outH.
__global__ __launch_bounds__(256) void gemm_chain(const float* __restrict__ A,
                                                  const float* __restrict__ W,
                                                  const float* __restrict__ bias,
                                                  const float* __restrict__ uu3, int uuidx,
                                                  const float* __restrict__ raw_c,
                                                  float* __restrict__ outF,
                                                  unsigned int* __restrict__ outH,
                                                  int mode, int nrows){
  __shared__ float As[16][132];
  __shared__ float Ws[16][132];
  int tid = threadIdx.x;
  int r0  = blockIdx.x * 128;
  int tx  = tid & 15, ty = tid >> 4;
  float4 aA[2], aW[2];
  int rowA[2], kqA[2], kW[2], cqW[2];
  #pragma unroll
  for (int t = 0; t < 2; ++t){
    int f = tid + t*256;
    rowA[t] = f >> 2; kqA[t] = f & 3;
    kW[t]   = f >> 5; cqW[t] = f & 31;
  }

  auto loadA = [&](int kc){
    #pragma unroll
    for (int t = 0; t < 2; ++t){
      int rg = r0 + rowA[t];
      aA[t] = make_float4(0.f,0.f,0.f,0.f);
      if (rg < nrows) aA[t] = *(const float4*)&A[(size_t)rg*128 + kc*16 + kqA[t]*4];
    }
  };
  auto loadW = [&](int kc){
    #pragma unroll
    for (int t = 0; t < 2; ++t)
      aW[t] = *(const float4*)&W[(size_t)(kc*16 + kW[t])*128 + cqW[t]*4];
  };

  float acc[8][8];
  #pragma unroll
  for (int i = 0; i < 8; ++i)
    #pragma unroll
    for (int j = 0; j < 8; ++j) acc[i][j] = 0.f;

  loadA(0); loadW(0);
  for (int kc = 0; kc < 8; ++kc){
    __syncthreads();
    #pragma unroll
    for (int t = 0; t < 2; ++t){
      As[kqA[t]*4+0][rowA[t]] = aA[t].x;
      As[kqA[t]*4+1][rowA[t]] = aA[t].y;
      As[kqA[t]*4+2][rowA[t]] = aA[t].z;
      As[kqA[t]*4+3][rowA[t]] = aA[t].w;
      *(float4*)&Ws[kW[t]][cqW[t]*4] = aW[t];
    }
    __syncthreads();
    if (kc < 7){ loadA(kc+1); loadW(kc+1); }
    #pragma unroll
    for (int k = 0; k < 16; ++k){
      float4 a0 = *(const float4*)&As[k][ty*8];
      float4 a1 = *(const float4*)&As[k][ty*8+4];
      float4 w0 = *(const float4*)&Ws[k][tx*8];
      float4 w1 = *(const float4*)&Ws[k][tx*8+4];
      float av[8] = {a0.x,a0.y,a0.z,a0.w,a1.x,a1.y,a1.z,a1.w};
      float wv[8] = {w0.x,w0.y,w0.z,w0.w,w1.x,w1.y,w1.z,w1.w};
      #pragma unroll
      for (int i = 0; i < 8; ++i)
        #pragma unroll
        for (int j = 0; j < 8; ++j)
          acc[i][j] = fmaf(av[i], wv[j], acc[i][j]);
    }
  }

  // ---- fused chain epilogue ----
  float K, sK; get_c(raw_c, K, sK);
  float uu = uu3[uuidx];
  float uv[8];
  #pragma unroll
  for (int j = 0; j < 8; ++j){
    int col = tx*8 + j;
    uv[j] = (col == 0) ? 0.f : bias[col];   // comp0 (time) dropped
  }
  if (tx == 0){
    #pragma unroll
    for (int i = 0; i < 8; ++i) acc[i][0] = 0.f;  // t comp0 dropped
  }
  #pragma unroll
  for (int i = 0; i < 8; ++i){
    float tt = 0.f, tu = 0.f;
    #pragma unroll
    for (int j = 0; j < 8; ++j){
      tt = fmaf(acc[i][j], acc[i][j], tt);
      tu = fmaf(acc[i][j], uv[j], tu);
    }
    #pragma unroll
    for (int m = 1; m <= 8; m <<= 1){        // reduce across the 16 row-threads
      tt += __shfl_xor(tt, m);
      tu += __shfl_xor(tu, m);
    }
    float At, Au; chain_scalars(tt, tu, uu, K, sK, At, Au);
    int rg = r0 + ty*8 + i;
    if (rg < nrows){
      float o[8];
      #pragma unroll
      for (int j = 0; j < 8; ++j) o[j] = fmaf(At, acc[i][j], Au*uv[j]);
      if (mode == 0){
        *(float4*)&outF[(size_t)rg*128 + tx*8]     = make_float4(o[0],o[1],o[2],o[3]);
        *(float4*)&outF[(size_t)rg*128 + tx*8 + 4] = make_float4(o[4],o[5],o[6],o[7]);
      } else {
        uint4 pk;
        pk.x = pack_bf16(o[0], o[1]);
        pk.y = pack_bf16(o[2], o[3]);
        pk.z = pack_bf16(o[4], o[5]);
        pk.w = pack_bf16(o[6], o[7]);
        *(uint4*)&outH[(size_t)rg*64 + tx*4] = pk;
      }
    }
  }
}

// --------------------------- CSR build -------------------------------------
__global__ void hist_k(const int* __restrict__ rows, int* __restrict__ cnt, int e){
  int i = blockIdx.x * blockDim.x + threadIdx.x;
  if (i < e) atomicAdd(&cnt[rows[i]], 1);
}

#define SCAN_ITEMS 4
__global__ __launch_bounds__(256) void scan1(const int* __restrict__ cnt,
                                             int* __restrict__ off,
                                             int* __restrict__ bsum, int n){
  __shared__ int sh[256];
  int tid = threadIdx.x;
  int base = blockIdx.x * 256 * SCAN_ITEMS + tid * SCAN_ITEMS;
  int v[SCAN_ITEMS]; int s = 0;
  #pragma unroll
  for (int i = 0; i < SCAN_ITEMS; ++i){ int idx = base+i; v[i] = (idx < n) ? cnt[idx] : 0; s += v[i]; }
  sh[tid] = s; __syncthreads();
  for (int o = 1; o < 256; o <<= 1){
    int t = (tid >= o) ? sh[tid - o] : 0; __syncthreads();
    sh[tid] += t; __syncthreads();
  }
  int excl = sh[tid] - s;
  if (tid == 255) bsum[blockIdx.x] = sh[tid];
  int run = excl;
  #pragma unroll
  for (int i = 0; i < SCAN_ITEMS; ++i){ int idx = base+i; if (idx < n) off[idx] = run; run += v[i]; }
}

__global__ void scan2(int* bsum, int G){
  if (threadIdx.x == 0 && blockIdx.x == 0){
    int run = 0;
    for (int i = 0; i < G; ++i){ int t = bsum[i]; bsum[i] = run; run += t; }
  }
}

__global__ void scan3(int* __restrict__ off, int* __restrict__ cursor,
                      const int* __restrict__ bsum, int n){
  int i = blockIdx.x * blockDim.x + threadIdx.x;
  if (i < n){ int o = off[i] + bsum[i / (256*SCAN_ITEMS)]; off[i] = o; cursor[i] = o; }
}

__global__ void fill_k(const int* __restrict__ rows, const int* __restrict__ cols,
                       const float* __restrict__ vals, int* __restrict__ cursor,
                       int2* __restrict__ ecv, int e){
  int i = blockIdx.x * blockDim.x + threadIdx.x;
  if (i < e){
    int pos = atomicAdd(&cursor[rows[i]], 1);
    ecv[pos] = make_int2(cols[i], __float_as_int(vals[i]));
  }
}

// --------------------------- seg-sum (bf16 table, int2 edges) ---------------
__device__ __forceinline__ float2 seg_gather_bf16(const unsigned int* __restrict__ h,
                                                  const int* __restrict__ off,
                                                  const int* __restrict__ cnt,
                                                  const int2* __restrict__ ecv,
                                                  int row, int lane){
  float ax = 0.f, ay = 0.f, bx = 0.f, by = 0.f;
  int st = off[row], deg = cnt[row];
  const unsigned int* __restrict__ hb = h + lane;   // row stride = 64 uints
  for (int b = 0; b < deg; b += 64){
    int k = b + lane;
    int cc = 0; float vv = 0.f;
    if (k < deg){ int2 e = ecv[st+k]; cc = e.x; vv = __int_as_float(e.y); }
    int m = min(64, deg - b);
    for (int j = 0; j < m; j += 8){
      int   c0=__shfl(cc,j+0), c1=__shfl(cc,j+1), c2=__shfl(cc,j+2), c3=__shfl(cc,j+3);
      int   c4=__shfl(cc,j+4), c5=__shfl(cc,j+5), c6=__shfl(cc,j+6), c7=__shfl(cc,j+7);
      float v0=__shfl(vv,j+0), v1=__shfl(vv,j+1), v2=__shfl(vv,j+2), v3=__shfl(vv,j+3);
      float v4=__shfl(vv,j+4), v5=__shfl(vv,j+5), v6=__shfl(vv,j+6), v7=__shfl(vv,j+7);
      unsigned int p0 = hb[(size_t)c0*64];
      unsigned int p1 = hb[(size_t)c1*64];
      unsigned int p2 = hb[(size_t)c2*64];
      unsigned int p3 = hb[(size_t)c3*64];
      unsigned int p4 = hb[(size_t)c4*64];
      unsigned int p5 = hb[(size_t)c5*64];
      unsigned int p6 = hb[(size_t)c6*64];
      unsigned int p7 = hb[(size_t)c7*64];
      ax = fmaf(v0, bf_lo(p0), ax); ay = fmaf(v0, bf_hi(p0), ay);
      bx = fmaf(v1, bf_lo(p1), bx); by = fmaf(v1, bf_hi(p1), by);
      ax = fmaf(v2, bf_lo(p2), ax); ay = fmaf(v2, bf_hi(p2), ay);
      bx = fmaf(v3, bf_lo(p3), bx); by = fmaf(v3, bf_hi(p3), by);
      ax = fmaf(v4, bf_lo(p4), ax); ay = fmaf(v4, bf_hi(p4), ay);
      bx = fmaf(v5, bf_lo(p5), bx); by = fmaf(v5, bf_hi(p5), by);
      ax = fmaf(v6, bf_lo(p6), ax); ay = fmaf(v6, bf_hi(p6), ay);
      bx = fmaf(v7, bf_lo(p7), bx); by = fmaf(v7, bf_hi(p7), by);
    }
  }
  return make_float2(ax + bx, ay + by);
}

// ------------------- seg_x1: Lx1 = (1-n)*segsum(h1) + n*loga1 (fp32) --------
__global__ __launch_bounds__(256) void seg_x1(const unsigned int* __restrict__ h1,
                                              const int* __restrict__ off,
                                              const int* __restrict__ cnt,
                                              const int2* __restrict__ ecv,
                                              const float* __restrict__ loga1,
                                              const float* __restrict__ nparam,
                                              float* __restrict__ Lx1, int n){
  int row  = (int)((blockIdx.x * blockDim.x + threadIdx.x) >> 6);
  int lane = threadIdx.x & 63;
  if (row >= n) return;
  float2 acc = seg_gather_bf16(h1, off, cnt, ecv, row, lane);
  float nv = nparam[row];
  float2 la1 = *(const float2*)&loga1[(size_t)row*128 + 2*lane];
  float ox = (1.f-nv)*acc.x + nv*la1.x;
  float oy = (1.f-nv)*acc.y + nv*la1.y;
  *(float2*)&Lx1[(size_t)row*128 + 2*lane] = make_float2(ox, oy);
}

// ------------------- seg_x2: Lx2 = segsum(h2)  (fp32 out) -------------------
__global__ __launch_bounds__(256) void seg_x2(const unsigned int* __restrict__ h2,
                                              const int* __restrict__ off,
                                              const int* __restrict__ cnt,
                                              const int2* __restrict__ ecv,
                                              float* __restrict__ Lx2, int n){
  int row  = (int)((blockIdx.x * blockDim.x + threadIdx.x) >> 6);
  int lane = threadIdx.x & 63;
  if (row >= n) return;
  float2 acc = seg_gather_bf16(h2, off, cnt, ecv, row, lane);
  *(float2*)&Lx2[(size_t)row*128 + 2*lane] = acc;
}

// --------------------------- batch head (fp32 tables) -----------------------
__global__ __launch_bounds__(128) void batch_head(const float* __restrict__ Lx2,
                                                  const float* __restrict__ loga1,
                                                  const int* __restrict__ bidx,
                                                  const float* __restrict__ weight,
                                                  const float* __restrict__ weight2,
                                                  const float* __restrict__ c1w,
                                                  const float* __restrict__ c1b,
                                                  const float* __restrict__ c2w,
                                                  const float* __restrict__ c2b,
                                                  const float* __restrict__ cls,
                                                  const float* __restrict__ clsb,
                                                  float* __restrict__ out, int Bn){
  __shared__ float sg2[128], sg3[128], ssel[100], spre[5];
  __shared__ int sbi[50];
  __shared__ float sc1[50], sc2[50];
  int b = blockIdx.x, d = threadIdx.x;
  const int* bi = bidx + (size_t)b * 50;
  if (d < 50){ sbi[d] = bi[d]; sc1[d] = c1w[d]; sc2[d] = c2w[d]; }
  __syncthreads();
  int lane = d & 63;
  bool lo = d < 64;
  const float* __restrict__ tab = lo ? Lx2 : loga1;
  const float* __restrict__ cw = lo ? sc1 : sc2;
  float gx = 0.f, gy = 0.f;
  const float2* __restrict__ t2 = (const float2*)tab + lane;  // row stride 64
  #pragma unroll
  for (int l = 0; l < 50; l += 5){
    int i0 = sbi[l+0], i1 = sbi[l+1], i2 = sbi[l+2], i3 = sbi[l+3], i4 = sbi[l+4];
    float2 p0 = t2[(size_t)i0*64];
    float2 p1 = t2[(size_t)i1*64];
    float2 p2 = t2[(size_t)i2*64];
    float2 p3 = t2[(size_t)i3*64];
    float2 p4 = t2[(size_t)i4*64];
    float w0 = cw[l+0], w1 = cw[l+1], w2 = cw[l+2], w3 = cw[l+3], w4 = cw[l+4];
    gx = fmaf(w0, p0.x, gx); gy = fmaf(w0, p0.y, gy);
    gx = fmaf(w1, p1.x, gx); gy = fmaf(w1, p1.y, gy);
    gx = fmaf(w2, p2.x, gx); gy = fmaf(w2, p2.y, gy);
    gx = fmaf(w3, p3.x, gx); gy = fmaf(w3, p3.y, gy);
    gx = fmaf(w4, p4.x, gx); gy = fmaf(w4, p4.y, gy);
  }
  if (lo){ sg2[2*lane] = gx; sg2[2*lane+1] = gy; }
  else   { sg3[2*lane] = gx; sg3[2*lane+1] = gy; }
  __syncthreads();
  if (d < 50){
    float s = 0.f;
    for (int k = 0; k < 128; ++k) s = fmaf(sg2[k], weight[k*50 + d], s);
    s += c1b[0];
    ssel[d] = s;
    out[(size_t)Bn + (size_t)b*100 + d] = s;
  } else if (d >= 64 && d < 114){
    int t = d - 64;
    float s = 0.f;
    for (int k = 0; k < 128; ++k) s = fmaf(sg3[k], weight2[k*50 + t], s);
    s += c2b[0];
    ssel[50 + t] = s;
    out[(size_t)Bn + (size_t)b*100 + 50 + t] = s;
  }
  __syncthreads();
  if (d < 5){
    float s = clsb[d];
    for (int j = 0; j < 100; ++j) s = fmaf(ssel[j], cls[j*5 + d], s);
    spre[d] = s;
  }
  __syncthreads();
  if (d == 0){
    int best = 0; float bv = spre[0];
    #pragma unroll
    for (int k = 1; k < 5; ++k) if (spre[k] > bv){ bv = spre[k]; best = k; }
    out[b] = (float)best;
  }
}

// ---------------------------------------------------------------------------
extern "C" void kernel_launch(void* const* d_in, const int* in_sizes, int n_in,
                              void* d_out, int out_size, void* d_ws, size_t ws_size,
                              hipStream_t stream) {
  const float* A1     = (const float*)d_in[0];
  const int*   rows   = (const int*)  d_in[1];
  const int*   cols   = (const int*)  d_in[2];
  const float* vals   = (const float*)d_in[3];
  const int*   bidx   = (const int*)  d_in[4];
  const float* raw_c  = (const float*)d_in[5];
  const float* nparam = (const float*)d_in[6];
  const float* Lin1   = (const float*)d_in[7];
  const float* Lin1_b = (const float*)d_in[8];
  const float* gc1_w  = (const float*)d_in[9];
  const float* gc1_b  = (const float*)d_in[10];
  const float* gc2_w  = (const float*)d_in[11];
  const float* gc2_b  = (const float*)d_in[12];
  const float* weight = (const float*)d_in[13];
  const float* weight2= (const float*)d_in[14];
  const float* c1w    = (const float*)d_in[15];
  const float* c1b    = (const float*)d_in[16];
  const float* c2w    = (const float*)d_in[17];
  const float* c2b    = (const float*)d_in[18];
  const float* cls    = (const float*)d_in[19];
  const float* clsb   = (const float*)d_in[20];

  int N  = in_sizes[0] / 129;
  int E  = in_sizes[1];
  int Bn = in_sizes[4] / 50;
  size_t NF = (size_t)N * 128;

  // workspace layout
  float* S0 = (float*)d_ws;                 // L -> Lx2 (fp32)
  float* S1 = S0 + NF;                      // Lx1 (fp32)
  float* S3 = S1 + NF;                      // loga1 (fp32, lives to the end)
  unsigned int* Hb = (unsigned int*)(S3 + NF);   // h1 -> h2 bf16 (NF/2 uints)
  int* cnt    = (int*)(Hb + NF/2);
  int* off    = cnt + N;
  int* cursor = off + N;
  int* bsum   = cursor + N;                 // up to 4096 scan partials
  int2* ecv   = (int2*)(bsum + 4096);       // packed (col, val) edge records
  float* uu3  = (float*)(ecv + E);          // 3 floats

  int rowBlocks  = (N + 3) / 4;
  int gemmBlocks = (N + 127) / 128;
  int G = (N + 256*SCAN_ITEMS - 1) / (256*SCAN_ITEMS);

  stage_a<<<(int)((NF + 255)/256), 256, 0, stream>>>(A1, S0, cnt, Lin1_b, gc1_b, gc2_b, uu3, N);

  hist_k<<<(E+255)/256, 256, 0, stream>>>(rows, cnt, E);
  scan1<<<G, 256, 0, stream>>>(cnt, off, bsum, N);
  scan2<<<1, 64, 0, stream>>>(bsum, G);
  scan3<<<(N+255)/256, 256, 0, stream>>>(off, cursor, bsum, N);
  fill_k<<<(E+255)/256, 256, 0, stream>>>(rows, cols, vals, cursor, ecv, E);

  // loga1 = chain(L@Lin1[1:,:], lin1_b)   -> S3 (fp32)
  gemm_chain<<<gemmBlocks, 256, 0, stream>>>(S0, Lin1 + 128, Lin1_b, uu3, 0, raw_c,
                                             S3, (unsigned int*)nullptr, 0, N);
  // h1 = chain(L@gc1_w[1:,:], gc1_b)      -> Hb (bf16)
  gemm_chain<<<gemmBlocks, 256, 0, stream>>>(S0, gc1_w + 128, gc1_b, uu3, 1, raw_c,
                                             (float*)nullptr, Hb, 1, N);
  seg_x1<<<rowBlocks, 256, 0, stream>>>(Hb, off, cnt, ecv, S3, nparam, S1, N);
  // h2 = chain(Lx1@gc2_w, gc2_b)          -> Hb (bf16; Lx1 comp0 == 0)
  gemm_chain<<<gemmBlocks, 256, 0, stream>>>(S1, gc2_w, gc2_b, uu3, 2, raw_c,
                                             (float*)nullptr, Hb, 1, N);
  seg_x2<<<rowBlocks, 256, 0, stream>>>(Hb, off, cnt, ecv, S0, N);  // Lx2 -> S0
  batch_head<<<Bn, 128, 0, stream>>>(S0, S3, bidx, weight, weight2, c1w, c1b,
                                     c2w, c2b, cls, clsb, (float*)d_out, Bn);
}

// Round 9
// 668.590 us; speedup vs baseline: 2.4519x; 1.0697x over previous
//
#include <hip/hip_runtime.h>
#include <math.h>

// ---------------------------------------------------------------------------
// Hyperbolic GCN forward, fully collapsed:
//  - logmap0(proj(expmap0(u))) == u  (tangent roundtrips cancel)
//  - bias chain logmap0(mobius_add(proj(expmap0(t)),b)) is AFFINE per
//    component: out_j = At*t_j + Au*u_j (At,Au wave-uniform from <t,t>,<t,u>)
//    fused into the GEMM epilogue.
//  - h1/h2 (segment-sum tables) packed bf16; loga1/Lx2 FP32 (sel path).
//  - CSR build: hist saves per-edge rank (atomic returns), fill is atomic-free
//    (pos = off[row] + rnk[i]), both 4-edge unrolled for MLP.
// ---------------------------------------------------------------------------

__device__ __forceinline__ float wsum(float x){
  x += __shfl_xor(x, 32);
  x += __shfl_xor(x, 16);
  x += __shfl_xor(x, 8);
  x += __shfl_xor(x, 4);
  x += __shfl_xor(x, 2);
  x += __shfl_xor(x, 1);
  return x;
}

__device__ __forceinline__ void get_c(const float* rc, float& K, float& sK){
  float c = log1pf(expf(rc[0])) + 1e-5f;   // softplus(raw_c) + 1e-5
  K  = 1.0f / c;
  sK = sqrtf(K);
}

__device__ __forceinline__ float sinhx_over_x(float x){
  if (x > 1e-3f){
    float e  = __expf(x);
    float em = __builtin_amdgcn_rcpf(e);
    return 0.5f*(e - em) * __builtin_amdgcn_rcpf(x);
  }
  return 1.0f + x*x*(1.0f/6.0f);
}

__device__ __forceinline__ float facosh(float x){   // x >= 1+1e-7
  return __logf(x + sqrtf(fmaxf(fmaf(x, x, -1.0f), 0.0f)));
}

// RNE pack of two floats into bf16x2 (lo = x, hi = y)
__device__ __forceinline__ unsigned int pack_bf16(float x, float y){
  unsigned int bx = __float_as_uint(x);
  unsigned int by = __float_as_uint(y);
  bx = (bx + 0x7fffu + ((bx >> 16) & 1u)) >> 16;
  by = (by + 0x7fffu + ((by >> 16) & 1u)) & 0xffff0000u;
  return bx | by;
}
__device__ __forceinline__ float bf_lo(unsigned int p){ return __uint_as_float(p << 16); }
__device__ __forceinline__ float bf_hi(unsigned int p){ return __uint_as_float(p & 0xffff0000u); }

// Chain scalars: out_j = At*t_j + Au*u_j == logmap0(mobius_add(exp-chain)).
__device__ __forceinline__ void chain_scalars(float tt, float tu, float uu,
                                              float K, float sK,
                                              float& At, float& Au){
  float xn  = fmaxf(sqrtf(tt), 1e-15f);
  float th  = xn / sK;
  float f   = sinhx_over_x(th);
  float pn2 = f*f*tt;
  float p0  = sqrtf(fmaxf(K + pn2, 1e-7f));
  float S_yu = f * tu;
  float yn  = fmaxf(sqrtf(pn2), 1e-15f);
  float inv_yn = __builtin_amdgcn_rcpf(yn);
  float alpha = S_yu * inv_yn / sK;
  float coef  = alpha * (sK - p0);
  float cy  = coef * inv_yn;
  float cyf = cy * f;
  float pdw  = S_yu - cy*pn2;
  float spsq = uu - 2.f*cy*S_yu + cy*cy*pn2;
  float w0 = pdw / fmaxf(p0, 1e-7f);
  float md = spsq - w0*w0;
  float normu = fminf(sqrtf(fmaxf(md, 1e-7f)), 1e6f);
  float th2 = fmaxf(normu / sK, 1e-15f);
  float e  = __expf(th2);
  float em = __builtin_amdgcn_rcpf(e);
  float ch = 0.5f*(e + em);
  float g  = (th2 > 1e-3f) ? 0.5f*(e - em)*__builtin_amdgcn_rcpf(th2)
                           : 1.0f + th2*th2*(1.0f/6.0f);
  float rn2 = ch*ch*pn2 + 2.f*ch*g*pdw + g*g*spsq;
  float r0 = sqrtf(fmaxf(K + rn2, 1e-7f));
  float ynf = fmaxf(sqrtf(rn2), 1e-15f);
  float thf = fmaxf(r0/sK, 1.f+1e-7f);
  float rf = sK * facosh(thf) * __builtin_amdgcn_rcpf(ynf);
  At = rf*(ch*f - g*cyf);
  Au = rf*g;
}

// --------------------------- stage A: L = A1[:,1:]; + cnt zero + uu_prep ----
__global__ __launch_bounds__(256) void stage_a(const float* __restrict__ A1,
                                               float* __restrict__ L,
                                               int* __restrict__ cnt,
                                               const float* __restrict__ b0,
                                               const float* __restrict__ b1,
                                               const float* __restrict__ b2,
                                               float* __restrict__ uu3, int n){
  size_t i = (size_t)blockIdx.x * 256 + threadIdx.x;
  size_t total = (size_t)n * 128;
  if (i < total){
    size_t row = i >> 7; int j = (int)(i & 127);
    L[i] = A1[row*129 + 1 + j];
  }
  if (i < (size_t)n) cnt[i] = 0;
  if (blockIdx.x == 0 && threadIdx.x < 64){
    int lane = threadIdx.x;
    const float* bs[3] = {b0, b1, b2};
    for (int k = 0; k < 3; ++k){
      float x = lane ? bs[k][2*lane] : 0.0f;
      float y = bs[k][2*lane+1];
      float s = wsum(x*x + y*y);
      if (lane == 0) uu3[k] = s;
    }
  }
}

// --------------------------- GEMM + fused chain epilogue --------------------
// mode 0: fp32 out to outF; mode 1: packed bf16 to outH.
__global__ __launch_bounds__(256) void gemm_chain(const float* __restrict__ A,
                                                  const float* __restrict__ W,
                                                  const float* __restrict__ bias,
                                                  const float* __restrict__ uu3, int uuidx,
                                                  const float* __restrict__ raw_c,
                                                  float* __restrict__ outF,
                                                  unsigned int* __restrict__ outH,
                                                  int mode, int nrows){
  __shared__ float As[16][132];
  __shared__ float Ws[16][132];
  int tid = threadIdx.x;
  int r0  = blockIdx.x * 128;
  int tx  = tid & 15, ty = tid >> 4;
  float4 aA[2], aW[2];
  int rowA[2], kqA[2], kW[2], cqW[2];
  #pragma unroll
  for (int t = 0; t < 2; ++t){
    int f = tid + t*256;
    rowA[t] = f >> 2; kqA[t] = f & 3;
    kW[t]   = f >> 5; cqW[t] = f & 31;
  }

  auto loadA = [&](int kc){
    #pragma unroll
    for (int t = 0; t < 2; ++t){
      int rg = r0 + rowA[t];
      aA[t] = make_float4(0.f,0.f,0.f,0.f);
      if (rg < nrows) aA[t] = *(const float4*)&A[(size_t)rg*128 + kc*16 + kqA[t]*4];
    }
  };
  auto loadW = [&](int kc){
    #pragma unroll
    for (int t = 0; t < 2; ++t)
      aW[t] = *(const float4*)&W[(size_t)(kc*16 + kW[t])*128 + cqW[t]*4];
  };

  float acc[8][8];
  #pragma unroll
  for (int i = 0; i < 8; ++i)
    #pragma unroll
    for (int j = 0; j < 8; ++j) acc[i][j] = 0.f;

  loadA(0); loadW(0);
  for (int kc = 0; kc < 8; ++kc){
    __syncthreads();
    #pragma unroll
    for (int t = 0; t < 2; ++t){
      As[kqA[t]*4+0][rowA[t]] = aA[t].x;
      As[kqA[t]*4+1][rowA[t]] = aA[t].y;
      As[kqA[t]*4+2][rowA[t]] = aA[t].z;
      As[kqA[t]*4+3][rowA[t]] = aA[t].w;
      *(float4*)&Ws[kW[t]][cqW[t]*4] = aW[t];
    }
    __syncthreads();
    if (kc < 7){ loadA(kc+1); loadW(kc+1); }
    #pragma unroll
    for (int k = 0; k < 16; ++k){
      float4 a0 = *(const float4*)&As[k][ty*8];
      float4 a1 = *(const float4*)&As[k][ty*8+4];
      float4 w0 = *(const float4*)&Ws[k][tx*8];
      float4 w1 = *(const float4*)&Ws[k][tx*8+4];
      float av[8] = {a0.x,a0.y,a0.z,a0.w,a1.x,a1.y,a1.z,a1.w};
      float wv[8] = {w0.x,w0.y,w0.z,w0.w,w1.x,w1.y,w1.z,w1.w};
      #pragma unroll
      for (int i = 0; i < 8; ++i)
        #pragma unroll
        for (int j = 0; j < 8; ++j)
          acc[i][j] = fmaf(av[i], wv[j], acc[i][j]);
    }
  }

  // ---- fused chain epilogue ----
  float K, sK; get_c(raw_c, K, sK);
  float uu = uu3[uuidx];
  float uv[8];
  #pragma unroll
  for (int j = 0; j < 8; ++j){
    int col = tx*8 + j;
    uv[j] = (col == 0) ? 0.f : bias[col];   // comp0 (time) dropped
  }
  if (tx == 0){
    #pragma unroll
    for (int i = 0; i < 8; ++i) acc[i][0] = 0.f;  // t comp0 dropped
  }
  #pragma unroll
  for (int i = 0; i < 8; ++i){
    float tt = 0.f, tu = 0.f;
    #pragma unroll
    for (int j = 0; j < 8; ++j){
      tt = fmaf(acc[i][j], acc[i][j], tt);
      tu = fmaf(acc[i][j], uv[j], tu);
    }
    #pragma unroll
    for (int m = 1; m <= 8; m <<= 1){        // reduce across the 16 row-threads
      tt += __shfl_xor(tt, m);
      tu += __shfl_xor(tu, m);
    }
    float At, Au; chain_scalars(tt, tu, uu, K, sK, At, Au);
    int rg = r0 + ty*8 + i;
    if (rg < nrows){
      float o[8];
      #pragma unroll
      for (int j = 0; j < 8; ++j) o[j] = fmaf(At, acc[i][j], Au*uv[j]);
      if (mode == 0){
        *(float4*)&outF[(size_t)rg*128 + tx*8]     = make_float4(o[0],o[1],o[2],o[3]);
        *(float4*)&outF[(size_t)rg*128 + tx*8 + 4] = make_float4(o[4],o[5],o[6],o[7]);
      } else {
        uint4 pk;
        pk.x = pack_bf16(o[0], o[1]);
        pk.y = pack_bf16(o[2], o[3]);
        pk.z = pack_bf16(o[4], o[5]);
        pk.w = pack_bf16(o[6], o[7]);
        *(uint4*)&outH[(size_t)rg*64 + tx*4] = pk;
      }
    }
  }
}

// --------------------------- CSR build -------------------------------------
// hist: count AND record each edge's rank within its row (4-edge unrolled:
// 4 returning atomics in flight per lane, rank written back coalesced).
__global__ __launch_bounds__(256) void hist_k(const int* __restrict__ rows,
                                              int* __restrict__ cnt,
                                              int* __restrict__ rnk, int e){
  int base = (blockIdx.x * 256 + threadIdx.x) * 4;
  if (base + 3 < e){
    int4 r = *(const int4*)&rows[base];
    int k0 = atomicAdd(&cnt[r.x], 1);
    int k1 = atomicAdd(&cnt[r.y], 1);
    int k2 = atomicAdd(&cnt[r.z], 1);
    int k3 = atomicAdd(&cnt[r.w], 1);
    *(int4*)&rnk[base] = make_int4(k0, k1, k2, k3);
  } else {
    for (int i = base; i < e; ++i) rnk[i] = atomicAdd(&cnt[rows[i]], 1);
  }
}

#define SCAN_ITEMS 4
__global__ __launch_bounds__(256) void scan1(const int* __restrict__ cnt,
                                             int* __restrict__ off,
                                             int* __restrict__ bsum, int n){
  __shared__ int sh[256];
  int tid = threadIdx.x;
  int base = blockIdx.x * 256 * SCAN_ITEMS + tid * SCAN_ITEMS;
  int v[SCAN_ITEMS]; int s = 0;
  #pragma unroll
  for (int i = 0; i < SCAN_ITEMS; ++i){ int idx = base+i; v[i] = (idx < n) ? cnt[idx] : 0; s += v[i]; }
  sh[tid] = s; __syncthreads();
  for (int o = 1; o < 256; o <<= 1){
    int t = (tid >= o) ? sh[tid - o] : 0; __syncthreads();
    sh[tid] += t; __syncthreads();
  }
  int excl = sh[tid] - s;
  if (tid == 255) bsum[blockIdx.x] = sh[tid];
  int run = excl;
  #pragma unroll
  for (int i = 0; i < SCAN_ITEMS; ++i){ int idx = base+i; if (idx < n) off[idx] = run; run += v[i]; }
}

__global__ void scan2(int* bsum, int G){
  if (threadIdx.x == 0 && blockIdx.x == 0){
    int run = 0;
    for (int i = 0; i < G; ++i){ int t = bsum[i]; bsum[i] = run; run += t; }
  }
}

__global__ void scan3(int* __restrict__ off, const int* __restrict__ bsum, int n){
  int i = blockIdx.x * blockDim.x + threadIdx.x;
  if (i < n) off[i] += bsum[i / (256*SCAN_ITEMS)];
}

// fill: atomic-free scatter, pos = off[row] + rnk[i], 4 edges/thread.
__global__ __launch_bounds__(256) void fill_k(const int* __restrict__ rows,
                                              const int* __restrict__ cols,
                                              const float* __restrict__ vals,
                                              const int* __restrict__ off,
                                              const int* __restrict__ rnk,
                                              int2* __restrict__ ecv, int e){
  int base = (blockIdx.x * 256 + threadIdx.x) * 4;
  if (base + 3 < e){
    int4   r = *(const int4*)&rows[base];
    int4   q = *(const int4*)&rnk[base];
    int4   c = *(const int4*)&cols[base];
    float4 v = *(const float4*)&vals[base];
    int o0 = off[r.x], o1 = off[r.y], o2 = off[r.z], o3 = off[r.w];
    ecv[o0 + q.x] = make_int2(c.x, __float_as_int(v.x));
    ecv[o1 + q.y] = make_int2(c.y, __float_as_int(v.y));
    ecv[o2 + q.z] = make_int2(c.z, __float_as_int(v.z));
    ecv[o3 + q.w] = make_int2(c.w, __float_as_int(v.w));
  } else {
    for (int i = base; i < e; ++i)
      ecv[off[rows[i]] + rnk[i]] = make_int2(cols[i], __float_as_int(vals[i]));
  }
}

// --------------------------- seg-sum (bf16 table, int2 edges) ---------------
__device__ __forceinline__ float2 seg_gather_bf16(const unsigned int* __restrict__ h,
                                                  const int* __restrict__ off,
                                                  const int* __restrict__ cnt,
                                                  const int2* __restrict__ ecv,
                                                  int row, int lane){
  float ax = 0.f, ay = 0.f, bx = 0.f, by = 0.f;
  int st = off[row], deg = cnt[row];
  const unsigned int* __restrict__ hb = h + lane;   // row stride = 64 uints
  for (int b = 0; b < deg; b += 64){
    int k = b + lane;
    int cc = 0; float vv = 0.f;
    if (k < deg){ int2 e = ecv[st+k]; cc = e.x; vv = __int_as_float(e.y); }
    int m = min(64, deg - b);
    for (int j = 0; j < m; j += 8){
      int   c0=__shfl(cc,j+0), c1=__shfl(cc,j+1), c2=__shfl(cc,j+2), c3=__shfl(cc,j+3);
      int   c4=__shfl(cc,j+4), c5=__shfl(cc,j+5), c6=__shfl(cc,j+6), c7=__shfl(cc,j+7);
      float v0=__shfl(vv,j+0), v1=__shfl(vv,j+1), v2=__shfl(vv,j+2), v3=__shfl(vv,j+3);
      float v4=__shfl(vv,j+4), v5=__shfl(vv,j+5), v6=__shfl(vv,j+6), v7=__shfl(vv,j+7);
      unsigned int p0 = hb[(size_t)c0*64];
      unsigned int p1 = hb[(size_t)c1*64];
      unsigned int p2 = hb[(size_t)c2*64];
      unsigned int p3 = hb[(size_t)c3*64];
      unsigned int p4 = hb[(size_t)c4*64];
      unsigned int p5 = hb[(size_t)c5*64];
      unsigned int p6 = hb[(size_t)c6*64];
      unsigned int p7 = hb[(size_t)c7*64];
      ax = fmaf(v0, bf_lo(p0), ax); ay = fmaf(v0, bf_hi(p0), ay);
      bx = fmaf(v1, bf_lo(p1), bx); by = fmaf(v1, bf_hi(p1), by);
      ax = fmaf(v2, bf_lo(p2), ax); ay = fmaf(v2, bf_hi(p2), ay);
      bx = fmaf(v3, bf_lo(p3), bx); by = fmaf(v3, bf_hi(p3), by);
      ax = fmaf(v4, bf_lo(p4), ax); ay = fmaf(v4, bf_hi(p4), ay);
      bx = fmaf(v5, bf_lo(p5), bx); by = fmaf(v5, bf_hi(p5), by);
      ax = fmaf(v6, bf_lo(p6), ax); ay = fmaf(v6, bf_hi(p6), ay);
      bx = fmaf(v7, bf_lo(p7), bx); by = fmaf(v7, bf_hi(p7), by);
    }
  }
  return make_float2(ax + bx, ay + by);
}

// ------------------- seg_x1: Lx1 = (1-n)*segsum(h1) + n*loga1 (fp32) --------
__global__ __launch_bounds__(256) void seg_x1(const unsigned int* __restrict__ h1,
                                              const int* __restrict__ off,
                                              const int* __restrict__ cnt,
                                              const int2* __restrict__ ecv,
                                              const float* __restrict__ loga1,
                                              const float* __restrict__ nparam,
                                              float* __restrict__ Lx1, int n){
  int row  = (int)((blockIdx.x * blockDim.x + threadIdx.x) >> 6);
  int lane = threadIdx.x & 63;
  if (row >= n) return;
  float2 acc = seg_gather_bf16(h1, off, cnt, ecv, row, lane);
  float nv = nparam[row];
  float2 la1 = *(const float2*)&loga1[(size_t)row*128 + 2*lane];
  float ox = (1.f-nv)*acc.x + nv*la1.x;
  float oy = (1.f-nv)*acc.y + nv*la1.y;
  *(float2*)&Lx1[(size_t)row*128 + 2*lane] = make_float2(ox, oy);
}

// ------------------- seg_x2: Lx2 = segsum(h2)  (fp32 out) -------------------
__global__ __launch_bounds__(256) void seg_x2(const unsigned int* __restrict__ h2,
                                              const int* __restrict__ off,
                                              const int* __restrict__ cnt,
                                              const int2* __restrict__ ecv,
                                              float* __restrict__ Lx2, int n){
  int row  = (int)((blockIdx.x * blockDim.x + threadIdx.x) >> 6);
  int lane = threadIdx.x & 63;
  if (row >= n) return;
  float2 acc = seg_gather_bf16(h2, off, cnt, ecv, row, lane);
  *(float2*)&Lx2[(size_t)row*128 + 2*lane] = acc;
}

// --------------------------- batch head (fp32 tables) -----------------------
__global__ __launch_bounds__(128) void batch_head(const float* __restrict__ Lx2,
                                                  const float* __restrict__ loga1,
                                                  const int* __restrict__ bidx,
                                                  const float* __restrict__ weight,
                                                  const float* __restrict__ weight2,
                                                  const float* __restrict__ c1w,
                                                  const float* __restrict__ c1b,
                                                  const float* __restrict__ c2w,
                                                  const float* __restrict__ c2b,
                                                  const float* __restrict__ cls,
                                                  const float* __restrict__ clsb,
                                                  float* __restrict__ out, int Bn){
  __shared__ float sg2[128], sg3[128], ssel[100], spre[5];
  __shared__ int sbi[50];
  __shared__ float sc1[50], sc2[50];
  int b = blockIdx.x, d = threadIdx.x;
  const int* bi = bidx + (size_t)b * 50;
  if (d < 50){ sbi[d] = bi[d]; sc1[d] = c1w[d]; sc2[d] = c2w[d]; }
  __syncthreads();
  int lane = d & 63;
  bool lo = d < 64;
  const float* __restrict__ tab = lo ? Lx2 : loga1;
  const float* __restrict__ cw = lo ? sc1 : sc2;
  float gx = 0.f, gy = 0.f;
  const float2* __restrict__ t2 = (const float2*)tab + lane;  // row stride 64
  #pragma unroll
  for (int l = 0; l < 50; l += 5){
    int i0 = sbi[l+0], i1 = sbi[l+1], i2 = sbi[l+2], i3 = sbi[l+3], i4 = sbi[l+4];
    float2 p0 = t2[(size_t)i0*64];
    float2 p1 = t2[(size_t)i1*64];
    float2 p2 = t2[(size_t)i2*64];
    float2 p3 = t2[(size_t)i3*64];
    float2 p4 = t2[(size_t)i4*64];
    float w0 = cw[l+0], w1 = cw[l+1], w2 = cw[l+2], w3 = cw[l+3], w4 = cw[l+4];
    gx = fmaf(w0, p0.x, gx); gy = fmaf(w0, p0.y, gy);
    gx = fmaf(w1, p1.x, gx); gy = fmaf(w1, p1.y, gy);
    gx = fmaf(w2, p2.x, gx); gy = fmaf(w2, p2.y, gy);
    gx = fmaf(w3, p3.x, gx); gy = fmaf(w3, p3.y, gy);
    gx = fmaf(w4, p4.x, gx); gy = fmaf(w4, p4.y, gy);
  }
  if (lo){ sg2[2*lane] = gx; sg2[2*lane+1] = gy; }
  else   { sg3[2*lane] = gx; sg3[2*lane+1] = gy; }
  __syncthreads();
  if (d < 50){
    float s = 0.f;
    for (int k = 0; k < 128; ++k) s = fmaf(sg2[k], weight[k*50 + d], s);
    s += c1b[0];
    ssel[d] = s;
    out[(size_t)Bn + (size_t)b*100 + d] = s;
  } else if (d >= 64 && d < 114){
    int t = d - 64;
    float s = 0.f;
    for (int k = 0; k < 128; ++k) s = fmaf(sg3[k], weight2[k*50 + t], s);
    s += c2b[0];
    ssel[50 + t] = s;
    out[(size_t)Bn + (size_t)b*100 + 50 + t] = s;
  }
  __syncthreads();
  if (d < 5){
    float s = clsb[d];
    for (int j = 0; j < 100; ++j) s = fmaf(ssel[j], cls[j*5 + d], s);
    spre[d] = s;
  }
  __syncthreads();
  if (d == 0){
    int best = 0; float bv = spre[0];
    #pragma unroll
    for (int k = 1; k < 5; ++k) if (spre[k] > bv){ bv = spre[k]; best = k; }
    out[b] = (float)best;
  }
}

// ---------------------------------------------------------------------------
extern "C" void kernel_launch(void* const* d_in, const int* in_sizes, int n_in,
                              void* d_out, int out_size, void* d_ws, size_t ws_size,
                              hipStream_t stream) {
  const float* A1     = (const float*)d_in[0];
  const int*   rows   = (const int*)  d_in[1];
  const int*   cols   = (const int*)  d_in[2];
  const float* vals   = (const float*)d_in[3];
  const int*   bidx   = (const int*)  d_in[4];
  const float* raw_c  = (const float*)d_in[5];
  const float* nparam = (const float*)d_in[6];
  const float* Lin1   = (const float*)d_in[7];
  const float* Lin1_b = (const float*)d_in[8];
  const float* gc1_w  = (const float*)d_in[9];
  const float* gc1_b  = (const float*)d_in[10];
  const float* gc2_w  = (const float*)d_in[11];
  const float* gc2_b  = (const float*)d_in[12];
  const float* weight = (const float*)d_in[13];
  const float* weight2= (const float*)d_in[14];
  const float* c1w    = (const float*)d_in[15];
  const float* c1b    = (const float*)d_in[16];
  const float* c2w    = (const float*)d_in[17];
  const float* c2b    = (const float*)d_in[18];
  const float* cls    = (const float*)d_in[19];
  const float* clsb   = (const float*)d_in[20];

  int N  = in_sizes[0] / 129;
  int E  = in_sizes[1];
  int Bn = in_sizes[4] / 50;
  size_t NF = (size_t)N * 128;

  // workspace layout
  float* S0 = (float*)d_ws;                 // L -> Lx2 (fp32)
  float* S1 = S0 + NF;                      // Lx1 (fp32)
  float* S3 = S1 + NF;                      // loga1 (fp32, lives to the end)
  unsigned int* Hb = (unsigned int*)(S3 + NF);   // h1 -> h2 bf16 (NF/2 uints)
  int* cnt    = (int*)(Hb + NF/2);
  int* off    = cnt + N;
  int* rnk    = off + N;                    // per-edge rank (E ints)
  int* bsum   = rnk + E;                    // up to 4096 scan partials
  int2* ecv   = (int2*)(bsum + 4096);       // packed (col, val) edge records
  float* uu3  = (float*)(ecv + E);          // 3 floats

  int rowBlocks  = (N + 3) / 4;
  int gemmBlocks = (N + 127) / 128;
  int G = (N + 256*SCAN_ITEMS - 1) / (256*SCAN_ITEMS);
  int eBlocks4 = (E/4 + 255) / 256 + 1;

  stage_a<<<(int)((NF + 255)/256), 256, 0, stream>>>(A1, S0, cnt, Lin1_b, gc1_b, gc2_b, uu3, N);

  hist_k<<<eBlocks4, 256, 0, stream>>>(rows, cnt, rnk, E);
  scan1<<<G, 256, 0, stream>>>(cnt, off, bsum, N);
  scan2<<<1, 64, 0, stream>>>(bsum, G);
  scan3<<<(N+255)/256, 256, 0, stream>>>(off, bsum, N);
  fill_k<<<eBlocks4, 256, 0, stream>>>(rows, cols, vals, off, rnk, ecv, E);

  // loga1 = chain(L@Lin1[1:,:], lin1_b)   -> S3 (fp32)
  gemm_chain<<<gemmBlocks, 256, 0, stream>>>(S0, Lin1 + 128, Lin1_b, uu3, 0, raw_c,
                                             S3, (unsigned int*)nullptr, 0, N);
  // h1 = chain(L@gc1_w[1:,:], gc1_b)      -> Hb (bf16)
  gemm_chain<<<gemmBlocks, 256, 0, stream>>>(S0, gc1_w + 128, gc1_b, uu3, 1, raw_c,
                                             (float*)nullptr, Hb, 1, N);
  seg_x1<<<rowBlocks, 256, 0, stream>>>(Hb, off, cnt, ecv, S3, nparam, S1, N);
  // h2 = chain(Lx1@gc2_w, gc2_b)          -> Hb (bf16; Lx1 comp0 == 0)
  gemm_chain<<<gemmBlocks, 256, 0, stream>>>(S1, gc2_w, gc2_b, uu3, 2, raw_c,
                                             (float*)nullptr, Hb, 1, N);
  seg_x2<<<rowBlocks, 256, 0, stream>>>(Hb, off, cnt, ecv, S0, N);  // Lx2 -> S0
  batch_head<<<Bn, 128, 0, stream>>>(S0, S3, bidx, weight, weight2, c1w, c1b,
                                     c2w, c2b, cls, clsb, (float*)d_out, Bn);
}

// Round 10
// 663.425 us; speedup vs baseline: 2.4710x; 1.0078x over previous
//
#include <hip/hip_runtime.h>
#include <math.h>

// ---------------------------------------------------------------------------
// Hyperbolic GCN forward, fully collapsed:
//  - logmap0(proj(expmap0(u))) == u  (tangent roundtrips cancel)
//  - bias chain logmap0(mobius_add(proj(expmap0(t)),b)) is AFFINE per
//    component: out_j = At*t_j + Au*u_j (At,Au wave-uniform from <t,t>,<t,u>)
//    fused into the GEMM epilogue.
//  - h1/h2 (segment-sum tables) packed bf16; loga1/Lx2 FP32 (sel path).
//  - CSR build: hist saves per-edge rank, fill is atomic-free, 4-edge unrolled.
//  - GEMMs: 512-thread blocks (8 waves) for occupancy; the two GEMMs sharing
//    input L are merged into one kernel (A staged once, 2x FMA per barrier).
// ---------------------------------------------------------------------------

__device__ __forceinline__ float wsum(float x){
  x += __shfl_xor(x, 32);
  x += __shfl_xor(x, 16);
  x += __shfl_xor(x, 8);
  x += __shfl_xor(x, 4);
  x += __shfl_xor(x, 2);
  x += __shfl_xor(x, 1);
  return x;
}

__device__ __forceinline__ void get_c(const float* rc, float& K, float& sK){
  float c = log1pf(expf(rc[0])) + 1e-5f;   // softplus(raw_c) + 1e-5
  K  = 1.0f / c;
  sK = sqrtf(K);
}

__device__ __forceinline__ float sinhx_over_x(float x){
  if (x > 1e-3f){
    float e  = __expf(x);
    float em = __builtin_amdgcn_rcpf(e);
    return 0.5f*(e - em) * __builtin_amdgcn_rcpf(x);
  }
  return 1.0f + x*x*(1.0f/6.0f);
}

__device__ __forceinline__ float facosh(float x){   // x >= 1+1e-7
  return __logf(x + sqrtf(fmaxf(fmaf(x, x, -1.0f), 0.0f)));
}

// RNE pack of two floats into bf16x2 (lo = x, hi = y)
__device__ __forceinline__ unsigned int pack_bf16(float x, float y){
  unsigned int bx = __float_as_uint(x);
  unsigned int by = __float_as_uint(y);
  bx = (bx + 0x7fffu + ((bx >> 16) & 1u)) >> 16;
  by = (by + 0x7fffu + ((by >> 16) & 1u)) & 0xffff0000u;
  return bx | by;
}
__device__ __forceinline__ float bf_lo(unsigned int p){ return __uint_as_float(p << 16); }
__device__ __forceinline__ float bf_hi(unsigned int p){ return __uint_as_float(p & 0xffff0000u); }

// Chain scalars: out_j = At*t_j + Au*u_j == logmap0(mobius_add(exp-chain)).
__device__ __forceinline__ void chain_scalars(float tt, float tu, float uu,
                                              float K, float sK,
                                              float& At, float& Au){
  float xn  = fmaxf(sqrtf(tt), 1e-15f);
  float th  = xn / sK;
  float f   = sinhx_over_x(th);
  float pn2 = f*f*tt;
  float p0  = sqrtf(fmaxf(K + pn2, 1e-7f));
  float S_yu = f * tu;
  float yn  = fmaxf(sqrtf(pn2), 1e-15f);
  float inv_yn = __builtin_amdgcn_rcpf(yn);
  float alpha = S_yu * inv_yn / sK;
  float coef  = alpha * (sK - p0);
  float cy  = coef * inv_yn;
  float cyf = cy * f;
  float pdw  = S_yu - cy*pn2;
  float spsq = uu - 2.f*cy*S_yu + cy*cy*pn2;
  float w0 = pdw / fmaxf(p0, 1e-7f);
  float md = spsq - w0*w0;
  float normu = fminf(sqrtf(fmaxf(md, 1e-7f)), 1e6f);
  float th2 = fmaxf(normu / sK, 1e-15f);
  float e  = __expf(th2);
  float em = __builtin_amdgcn_rcpf(e);
  float ch = 0.5f*(e + em);
  float g  = (th2 > 1e-3f) ? 0.5f*(e - em)*__builtin_amdgcn_rcpf(th2)
                           : 1.0f + th2*th2*(1.0f/6.0f);
  float rn2 = ch*ch*pn2 + 2.f*ch*g*pdw + g*g*spsq;
  float r0 = sqrtf(fmaxf(K + rn2, 1e-7f));
  float ynf = fmaxf(sqrtf(rn2), 1e-15f);
  float thf = fmaxf(r0/sK, 1.f+1e-7f);
  float rf = sK * facosh(thf) * __builtin_amdgcn_rcpf(ynf);
  At = rf*(ch*f - g*cyf);
  Au = rf*g;
}

// --------------------------- stage A: L = A1[:,1:]; + cnt zero + uu_prep ----
__global__ __launch_bounds__(256) void stage_a(const float* __restrict__ A1,
                                               float* __restrict__ L,
                                               int* __restrict__ cnt,
                                               const float* __restrict__ b0,
                                               const float* __restrict__ b1,
                                               const float* __restrict__ b2,
                                               float* __restrict__ uu3, int n){
  size_t i = (size_t)blockIdx.x * 256 + threadIdx.x;
  size_t total = (size_t)n * 128;
  if (i < total){
    size_t row = i >> 7; int j = (int)(i & 127);
    L[i] = A1[row*129 + 1 + j];
  }
  if (i < (size_t)n) cnt[i] = 0;
  if (blockIdx.x == 0 && threadIdx.x < 64){
    int lane = threadIdx.x;
    const float* bs[3] = {b0, b1, b2};
    for (int k = 0; k < 3; ++k){
      float x = lane ? bs[k][2*lane] : 0.0f;
      float y = bs[k][2*lane+1];
      float s = wsum(x*x + y*y);
      if (lane == 0) uu3[k] = s;
    }
  }
}

// ------------- merged GEMM: loga1 (fp32) + h1 (bf16) share A-tile -----------
// 512 threads, 128x128 tile, per-thread 4 rows x 8 cols x 2 accumulators.
__global__ __launch_bounds__(512) void gemm_chain2(const float* __restrict__ A,
                                                   const float* __restrict__ W1,
                                                   const float* __restrict__ W2,
                                                   const float* __restrict__ b1,
                                                   const float* __restrict__ b2,
                                                   const float* __restrict__ uu3,
                                                   const float* __restrict__ raw_c,
                                                   float* __restrict__ outF,
                                                   unsigned int* __restrict__ outH,
                                                   int nrows){
  __shared__ float As[16][132];
  __shared__ float W1s[16][132];
  __shared__ float W2s[16][132];
  int tid = threadIdx.x;
  int r0  = blockIdx.x * 128;
  int tx  = tid & 15, ty = tid >> 4;    // 16 x 32 thread grid
  int rowA = tid >> 2, kqA = tid & 3;   // A: 128 rows x 4 k-quads
  int kW   = tid >> 5, cqW = tid & 31;  // W: 16 k x 32 col-quads
  float4 aA, aW1, aW2;

  auto loadT = [&](int kc){
    int rg = r0 + rowA;
    aA = make_float4(0.f,0.f,0.f,0.f);
    if (rg < nrows) aA = *(const float4*)&A[(size_t)rg*128 + kc*16 + kqA*4];
    aW1 = *(const float4*)&W1[(size_t)(kc*16 + kW)*128 + cqW*4];
    aW2 = *(const float4*)&W2[(size_t)(kc*16 + kW)*128 + cqW*4];
  };

  float acc1[4][8], acc2[4][8];
  #pragma unroll
  for (int i = 0; i < 4; ++i)
    #pragma unroll
    for (int j = 0; j < 8; ++j){ acc1[i][j] = 0.f; acc2[i][j] = 0.f; }

  loadT(0);
  for (int kc = 0; kc < 8; ++kc){
    __syncthreads();
    As[kqA*4+0][rowA] = aA.x;
    As[kqA*4+1][rowA] = aA.y;
    As[kqA*4+2][rowA] = aA.z;
    As[kqA*4+3][rowA] = aA.w;
    *(float4*)&W1s[kW][cqW*4] = aW1;
    *(float4*)&W2s[kW][cqW*4] = aW2;
    __syncthreads();
    if (kc < 7) loadT(kc+1);
    #pragma unroll
    for (int k = 0; k < 16; ++k){
      float4 a  = *(const float4*)&As[k][ty*4];
      float4 p0 = *(const float4*)&W1s[k][tx*8];
      float4 p1 = *(const float4*)&W1s[k][tx*8+4];
      float4 q0 = *(const float4*)&W2s[k][tx*8];
      float4 q1 = *(const float4*)&W2s[k][tx*8+4];
      float av[4] = {a.x,a.y,a.z,a.w};
      float wv1[8] = {p0.x,p0.y,p0.z,p0.w,p1.x,p1.y,p1.z,p1.w};
      float wv2[8] = {q0.x,q0.y,q0.z,q0.w,q1.x,q1.y,q1.z,q1.w};
      #pragma unroll
      for (int i = 0; i < 4; ++i)
        #pragma unroll
        for (int j = 0; j < 8; ++j){
          acc1[i][j] = fmaf(av[i], wv1[j], acc1[i][j]);
          acc2[i][j] = fmaf(av[i], wv2[j], acc2[i][j]);
        }
    }
  }

  // ---- fused dual chain epilogue ----
  float K, sK; get_c(raw_c, K, sK);
  float uuA = uu3[0], uuB = uu3[1];
  float uv1[8], uv2[8];
  #pragma unroll
  for (int j = 0; j < 8; ++j){
    int col = tx*8 + j;
    uv1[j] = (col == 0) ? 0.f : b1[col];
    uv2[j] = (col == 0) ? 0.f : b2[col];
  }
  if (tx == 0){
    #pragma unroll
    for (int i = 0; i < 4; ++i){ acc1[i][0] = 0.f; acc2[i][0] = 0.f; }
  }
  #pragma unroll
  for (int i = 0; i < 4; ++i){
    float t1 = 0.f, u1 = 0.f, t2 = 0.f, u2 = 0.f;
    #pragma unroll
    for (int j = 0; j < 8; ++j){
      t1 = fmaf(acc1[i][j], acc1[i][j], t1);
      u1 = fmaf(acc1[i][j], uv1[j], u1);
      t2 = fmaf(acc2[i][j], acc2[i][j], t2);
      u2 = fmaf(acc2[i][j], uv2[j], u2);
    }
    #pragma unroll
    for (int m = 1; m <= 8; m <<= 1){   // reduce across the 16 tx-threads
      t1 += __shfl_xor(t1, m); u1 += __shfl_xor(u1, m);
      t2 += __shfl_xor(t2, m); u2 += __shfl_xor(u2, m);
    }
    float At1, Au1, At2, Au2;
    chain_scalars(t1, u1, uuA, K, sK, At1, Au1);
    chain_scalars(t2, u2, uuB, K, sK, At2, Au2);
    int rg = r0 + ty*4 + i;
    if (rg < nrows){
      float o1[8], o2[8];
      #pragma unroll
      for (int j = 0; j < 8; ++j){
        o1[j] = fmaf(At1, acc1[i][j], Au1*uv1[j]);
        o2[j] = fmaf(At2, acc2[i][j], Au2*uv2[j]);
      }
      *(float4*)&outF[(size_t)rg*128 + tx*8]     = make_float4(o1[0],o1[1],o1[2],o1[3]);
      *(float4*)&outF[(size_t)rg*128 + tx*8 + 4] = make_float4(o1[4],o1[5],o1[6],o1[7]);
      uint4 pk;
      pk.x = pack_bf16(o2[0], o2[1]);
      pk.y = pack_bf16(o2[2], o2[3]);
      pk.z = pack_bf16(o2[4], o2[5]);
      pk.w = pack_bf16(o2[6], o2[7]);
      *(uint4*)&outH[(size_t)rg*64 + tx*4] = pk;
    }
  }
}

// ---------------- single GEMM + chain (bf16 out), 512 threads ---------------
__global__ __launch_bounds__(512) void gemm_chain(const float* __restrict__ A,
                                                  const float* __restrict__ W,
                                                  const float* __restrict__ bias,
                                                  const float* __restrict__ uu3, int uuidx,
                                                  const float* __restrict__ raw_c,
                                                  unsigned int* __restrict__ outH,
                                                  int nrows){
  __shared__ float As[16][132];
  __shared__ float Ws[16][132];
  int tid = threadIdx.x;
  int r0  = blockIdx.x * 128;
  int tx  = tid & 15, ty = tid >> 4;
  int rowA = tid >> 2, kqA = tid & 3;
  int kW   = tid >> 5, cqW = tid & 31;
  float4 aA, aW;

  auto loadT = [&](int kc){
    int rg = r0 + rowA;
    aA = make_float4(0.f,0.f,0.f,0.f);
    if (rg < nrows) aA = *(const float4*)&A[(size_t)rg*128 + kc*16 + kqA*4];
    aW = *(const float4*)&W[(size_t)(kc*16 + kW)*128 + cqW*4];
  };

  float acc[4][8];
  #pragma unroll
  for (int i = 0; i < 4; ++i)
    #pragma unroll
    for (int j = 0; j < 8; ++j) acc[i][j] = 0.f;

  loadT(0);
  for (int kc = 0; kc < 8; ++kc){
    __syncthreads();
    As[kqA*4+0][rowA] = aA.x;
    As[kqA*4+1][rowA] = aA.y;
    As[kqA*4+2][rowA] = aA.z;
    As[kqA*4+3][rowA] = aA.w;
    *(float4*)&Ws[kW][cqW*4] = aW;
    __syncthreads();
    if (kc < 7) loadT(kc+1);
    #pragma unroll
    for (int k = 0; k < 16; ++k){
      float4 a  = *(const float4*)&As[k][ty*4];
      float4 w0 = *(const float4*)&Ws[k][tx*8];
      float4 w1 = *(const float4*)&Ws[k][tx*8+4];
      float av[4] = {a.x,a.y,a.z,a.w};
      float wv[8] = {w0.x,w0.y,w0.z,w0.w,w1.x,w1.y,w1.z,w1.w};
      #pragma unroll
      for (int i = 0; i < 4; ++i)
        #pragma unroll
        for (int j = 0; j < 8; ++j)
          acc[i][j] = fmaf(av[i], wv[j], acc[i][j]);
    }
  }

  float K, sK; get_c(raw_c, K, sK);
  float uu = uu3[uuidx];
  float uv[8];
  #pragma unroll
  for (int j = 0; j < 8; ++j){
    int col = tx*8 + j;
    uv[j] = (col == 0) ? 0.f : bias[col];
  }
  if (tx == 0){
    #pragma unroll
    for (int i = 0; i < 4; ++i) acc[i][0] = 0.f;
  }
  #pragma unroll
  for (int i = 0; i < 4; ++i){
    float tt = 0.f, tu = 0.f;
    #pragma unroll
    for (int j = 0; j < 8; ++j){
      tt = fmaf(acc[i][j], acc[i][j], tt);
      tu = fmaf(acc[i][j], uv[j], tu);
    }
    #pragma unroll
    for (int m = 1; m <= 8; m <<= 1){
      tt += __shfl_xor(tt, m);
      tu += __shfl_xor(tu, m);
    }
    float At, Au; chain_scalars(tt, tu, uu, K, sK, At, Au);
    int rg = r0 + ty*4 + i;
    if (rg < nrows){
      float o[8];
      #pragma unroll
      for (int j = 0; j < 8; ++j) o[j] = fmaf(At, acc[i][j], Au*uv[j]);
      uint4 pk;
      pk.x = pack_bf16(o[0], o[1]);
      pk.y = pack_bf16(o[2], o[3]);
      pk.z = pack_bf16(o[4], o[5]);
      pk.w = pack_bf16(o[6], o[7]);
      *(uint4*)&outH[(size_t)rg*64 + tx*4] = pk;
    }
  }
}

// --------------------------- CSR build -------------------------------------
__global__ __launch_bounds__(256) void hist_k(const int* __restrict__ rows,
                                              int* __restrict__ cnt,
                                              int* __restrict__ rnk, int e){
  int base = (blockIdx.x * 256 + threadIdx.x) * 4;
  if (base + 3 < e){
    int4 r = *(const int4*)&rows[base];
    int k0 = atomicAdd(&cnt[r.x], 1);
    int k1 = atomicAdd(&cnt[r.y], 1);
    int k2 = atomicAdd(&cnt[r.z], 1);
    int k3 = atomicAdd(&cnt[r.w], 1);
    *(int4*)&rnk[base] = make_int4(k0, k1, k2, k3);
  } else {
    for (int i = base; i < e; ++i) rnk[i] = atomicAdd(&cnt[rows[i]], 1);
  }
}

#define SCAN_ITEMS 4
__global__ __launch_bounds__(256) void scan1(const int* __restrict__ cnt,
                                             int* __restrict__ off,
                                             int* __restrict__ bsum, int n){
  __shared__ int sh[256];
  int tid = threadIdx.x;
  int base = blockIdx.x * 256 * SCAN_ITEMS + tid * SCAN_ITEMS;
  int v[SCAN_ITEMS]; int s = 0;
  #pragma unroll
  for (int i = 0; i < SCAN_ITEMS; ++i){ int idx = base+i; v[i] = (idx < n) ? cnt[idx] : 0; s += v[i]; }
  sh[tid] = s; __syncthreads();
  for (int o = 1; o < 256; o <<= 1){
    int t = (tid >= o) ? sh[tid - o] : 0; __syncthreads();
    sh[tid] += t; __syncthreads();
  }
  int excl = sh[tid] - s;
  if (tid == 255) bsum[blockIdx.x] = sh[tid];
  int run = excl;
  #pragma unroll
  for (int i = 0; i < SCAN_ITEMS; ++i){ int idx = base+i; if (idx < n) off[idx] = run; run += v[i]; }
}

__global__ void scan2(int* bsum, int G){
  if (threadIdx.x == 0 && blockIdx.x == 0){
    int run = 0;
    for (int i = 0; i < G; ++i){ int t = bsum[i]; bsum[i] = run; run += t; }
  }
}

__global__ void scan3(int* __restrict__ off, const int* __restrict__ bsum, int n){
  int i = blockIdx.x * blockDim.x + threadIdx.x;
  if (i < n) off[i] += bsum[i / (256*SCAN_ITEMS)];
}

__global__ __launch_bounds__(256) void fill_k(const int* __restrict__ rows,
                                              const int* __restrict__ cols,
                                              const float* __restrict__ vals,
                                              const int* __restrict__ off,
                                              const int* __restrict__ rnk,
                                              int2* __restrict__ ecv, int e){
  int base = (blockIdx.x * 256 + threadIdx.x) * 4;
  if (base + 3 < e){
    int4   r = *(const int4*)&rows[base];
    int4   q = *(const int4*)&rnk[base];
    int4   c = *(const int4*)&cols[base];
    float4 v = *(const float4*)&vals[base];
    int o0 = off[r.x], o1 = off[r.y], o2 = off[r.z], o3 = off[r.w];
    ecv[o0 + q.x] = make_int2(c.x, __float_as_int(v.x));
    ecv[o1 + q.y] = make_int2(c.y, __float_as_int(v.y));
    ecv[o2 + q.z] = make_int2(c.z, __float_as_int(v.z));
    ecv[o3 + q.w] = make_int2(c.w, __float_as_int(v.w));
  } else {
    for (int i = base; i < e; ++i)
      ecv[off[rows[i]] + rnk[i]] = make_int2(cols[i], __float_as_int(vals[i]));
  }
}

// --------------------------- seg-sum (bf16 table, int2 edges) ---------------
__device__ __forceinline__ float2 seg_gather_bf16(const unsigned int* __restrict__ h,
                                                  const int* __restrict__ off,
                                                  const int* __restrict__ cnt,
                                                  const int2* __restrict__ ecv,
                                                  int row, int lane){
  float ax = 0.f, ay = 0.f, bx = 0.f, by = 0.f;
  int st = off[row], deg = cnt[row];
  const unsigned int* __restrict__ hb = h + lane;   // row stride = 64 uints
  for (int b = 0; b < deg; b += 64){
    int k = b + lane;
    int cc = 0; float vv = 0.f;
    if (k < deg){ int2 e = ecv[st+k]; cc = e.x; vv = __int_as_float(e.y); }
    int m = min(64, deg - b);
    for (int j = 0; j < m; j += 8){
      int   c0=__shfl(cc,j+0), c1=__shfl(cc,j+1), c2=__shfl(cc,j+2), c3=__shfl(cc,j+3);
      int   c4=__shfl(cc,j+4), c5=__shfl(cc,j+5), c6=__shfl(cc,j+6), c7=__shfl(cc,j+7);
      float v0=__shfl(vv,j+0), v1=__shfl(vv,j+1), v2=__shfl(vv,j+2), v3=__shfl(vv,j+3);
      float v4=__shfl(vv,j+4), v5=__shfl(vv,j+5), v6=__shfl(vv,j+6), v7=__shfl(vv,j+7);
      unsigned int p0 = hb[(size_t)c0*64];
      unsigned int p1 = hb[(size_t)c1*64];
      unsigned int p2 = hb[(size_t)c2*64];
      unsigned int p3 = hb[(size_t)c3*64];
      unsigned int p4 = hb[(size_t)c4*64];
      unsigned int p5 = hb[(size_t)c5*64];
      unsigned int p6 = hb[(size_t)c6*64];
      unsigned int p7 = hb[(size_t)c7*64];
      ax = fmaf(v0, bf_lo(p0), ax); ay = fmaf(v0, bf_hi(p0), ay);
      bx = fmaf(v1, bf_lo(p1), bx); by = fmaf(v1, bf_hi(p1), by);
      ax = fmaf(v2, bf_lo(p2), ax); ay = fmaf(v2, bf_hi(p2), ay);
      bx = fmaf(v3, bf_lo(p3), bx); by = fmaf(v3, bf_hi(p3), by);
      ax = fmaf(v4, bf_lo(p4), ax); ay = fmaf(v4, bf_hi(p4), ay);
      bx = fmaf(v5, bf_lo(p5), bx); by = fmaf(v5, bf_hi(p5), by);
      ax = fmaf(v6, bf_lo(p6), ax); ay = fmaf(v6, bf_hi(p6), ay);
      bx = fmaf(v7, bf_lo(p7), bx); by = fmaf(v7, bf_hi(p7), by);
    }
  }
  return make_float2(ax + bx, ay + by);
}

// ------------------- seg_x1: Lx1 = (1-n)*segsum(h1) + n*loga1 (fp32) --------
__global__ __launch_bounds__(256) void seg_x1(const unsigned int* __restrict__ h1,
                                              const int* __restrict__ off,
                                              const int* __restrict__ cnt,
                                              const int2* __restrict__ ecv,
                                              const float* __restrict__ loga1,
                                              const float* __restrict__ nparam,
                                              float* __restrict__ Lx1, int n){
  int row  = (int)((blockIdx.x * blockDim.x + threadIdx.x) >> 6);
  int lane = threadIdx.x & 63;
  if (row >= n) return;
  float2 acc = seg_gather_bf16(h1, off, cnt, ecv, row, lane);
  float nv = nparam[row];
  float2 la1 = *(const float2*)&loga1[(size_t)row*128 + 2*lane];
  float ox = (1.f-nv)*acc.x + nv*la1.x;
  float oy = (1.f-nv)*acc.y + nv*la1.y;
  *(float2*)&Lx1[(size_t)row*128 + 2*lane] = make_float2(ox, oy);
}

// ------------------- seg_x2: Lx2 = segsum(h2)  (fp32 out) -------------------
__global__ __launch_bounds__(256) void seg_x2(const unsigned int* __restrict__ h2,
                                              const int* __restrict__ off,
                                              const int* __restrict__ cnt,
                                              const int2* __restrict__ ecv,
                                              float* __restrict__ Lx2, int n){
  int row  = (int)((blockIdx.x * blockDim.x + threadIdx.x) >> 6);
  int lane = threadIdx.x & 63;
  if (row >= n) return;
  float2 acc = seg_gather_bf16(h2, off, cnt, ecv, row, lane);
  *(float2*)&Lx2[(size_t)row*128 + 2*lane] = acc;
}

// --------------------------- batch head (fp32 tables) -----------------------
__global__ __launch_bounds__(128) void batch_head(const float* __restrict__ Lx2,
                                                  const float* __restrict__ loga1,
                                                  const int* __restrict__ bidx,
                                                  const float* __restrict__ weight,
                                                  const float* __restrict__ weight2,
                                                  const float* __restrict__ c1w,
                                                  const float* __restrict__ c1b,
                                                  const float* __restrict__ c2w,
                                                  const float* __restrict__ c2b,
                                                  const float* __restrict__ cls,
                                                  const float* __restrict__ clsb,
                                                  float* __restrict__ out, int Bn){
  __shared__ float sg2[128], sg3[128], ssel[100], spre[5];
  __shared__ int sbi[50];
  __shared__ float sc1[50], sc2[50];
  int b = blockIdx.x, d = threadIdx.x;
  const int* bi = bidx + (size_t)b * 50;
  if (d < 50){ sbi[d] = bi[d]; sc1[d] = c1w[d]; sc2[d] = c2w[d]; }
  __syncthreads();
  int lane = d & 63;
  bool lo = d < 64;
  const float* __restrict__ tab = lo ? Lx2 : loga1;
  const float* __restrict__ cw = lo ? sc1 : sc2;
  float gx = 0.f, gy = 0.f;
  const float2* __restrict__ t2 = (const float2*)tab + lane;  // row stride 64
  #pragma unroll
  for (int l = 0; l < 50; l += 5){
    int i0 = sbi[l+0], i1 = sbi[l+1], i2 = sbi[l+2], i3 = sbi[l+3], i4 = sbi[l+4];
    float2 p0 = t2[(size_t)i0*64];
    float2 p1 = t2[(size_t)i1*64];
    float2 p2 = t2[(size_t)i2*64];
    float2 p3 = t2[(size_t)i3*64];
    float2 p4 = t2[(size_t)i4*64];
    float w0 = cw[l+0], w1 = cw[l+1], w2 = cw[l+2], w3 = cw[l+3], w4 = cw[l+4];
    gx = fmaf(w0, p0.x, gx); gy = fmaf(w0, p0.y, gy);
    gx = fmaf(w1, p1.x, gx); gy = fmaf(w1, p1.y, gy);
    gx = fmaf(w2, p2.x, gx); gy = fmaf(w2, p2.y, gy);
    gx = fmaf(w3, p3.x, gx); gy = fmaf(w3, p3.y, gy);
    gx = fmaf(w4, p4.x, gx); gy = fmaf(w4, p4.y, gy);
  }
  if (lo){ sg2[2*lane] = gx; sg2[2*lane+1] = gy; }
  else   { sg3[2*lane] = gx; sg3[2*lane+1] = gy; }
  __syncthreads();
  if (d < 50){
    float s = 0.f;
    for (int k = 0; k < 128; ++k) s = fmaf(sg2[k], weight[k*50 + d], s);
    s += c1b[0];
    ssel[d] = s;
    out[(size_t)Bn + (size_t)b*100 + d] = s;
  } else if (d >= 64 && d < 114){
    int t = d - 64;
    float s = 0.f;
    for (int k = 0; k < 128; ++k) s = fmaf(sg3[k], weight2[k*50 + t], s);
    s += c2b[0];
    ssel[50 + t] = s;
    out[(size_t)Bn + (size_t)b*100 + 50 + t] = s;
  }
  __syncthreads();
  if (d < 5){
    float s = clsb[d];
    for (int j = 0; j < 100; ++j) s = fmaf(ssel[j], cls[j*5 + d], s);
    spre[d] = s;
  }
  __syncthreads();
  if (d == 0){
    int best = 0; float bv = spre[0];
    #pragma unroll
    for (int k = 1; k < 5; ++k) if (spre[k] > bv){ bv = spre[k]; best = k; }
    out[b] = (float)best;
  }
}

// ---------------------------------------------------------------------------
extern "C" void kernel_launch(void* const* d_in, const int* in_sizes, int n_in,
                              void* d_out, int out_size, void* d_ws, size_t ws_size,
                              hipStream_t stream) {
  const float* A1     = (const float*)d_in[0];
  const int*   rows   = (const int*)  d_in[1];
  const int*   cols   = (const int*)  d_in[2];
  const float* vals   = (const float*)d_in[3];
  const int*   bidx   = (const int*)  d_in[4];
  const float* raw_c  = (const float*)d_in[5];
  const float* nparam = (const float*)d_in[6];
  const float* Lin1   = (const float*)d_in[7];
  const float* Lin1_b = (const float*)d_in[8];
  const float* gc1_w  = (const float*)d_in[9];
  const float* gc1_b  = (const float*)d_in[10];
  const float* gc2_w  = (const float*)d_in[11];
  const float* gc2_b  = (const float*)d_in[12];
  const float* weight = (const float*)d_in[13];
  const float* weight2= (const float*)d_in[14];
  const float* c1w    = (const float*)d_in[15];
  const float* c1b    = (const float*)d_in[16];
  const float* c2w    = (const float*)d_in[17];
  const float* c2b    = (const float*)d_in[18];
  const float* cls    = (const float*)d_in[19];
  const float* clsb   = (const float*)d_in[20];

  int N  = in_sizes[0] / 129;
  int E  = in_sizes[1];
  int Bn = in_sizes[4] / 50;
  size_t NF = (size_t)N * 128;

  // workspace layout
  float* S0 = (float*)d_ws;                 // L -> Lx2 (fp32)
  float* S1 = S0 + NF;                      // Lx1 (fp32)
  float* S3 = S1 + NF;                      // loga1 (fp32, lives to the end)
  unsigned int* Hb = (unsigned int*)(S3 + NF);   // h1 -> h2 bf16 (NF/2 uints)
  int* cnt    = (int*)(Hb + NF/2);
  int* off    = cnt + N;
  int* rnk    = off + N;                    // per-edge rank (E ints)
  int* bsum   = rnk + E;                    // up to 4096 scan partials
  int2* ecv   = (int2*)(bsum + 4096);       // packed (col, val) edge records
  float* uu3  = (float*)(ecv + E);          // 3 floats

  int rowBlocks  = (N + 3) / 4;
  int gemmBlocks = (N + 127) / 128;
  int G = (N + 256*SCAN_ITEMS - 1) / (256*SCAN_ITEMS);
  int eBlocks4 = (E/4 + 255) / 256 + 1;

  stage_a<<<(int)((NF + 255)/256), 256, 0, stream>>>(A1, S0, cnt, Lin1_b, gc1_b, gc2_b, uu3, N);

  hist_k<<<eBlocks4, 256, 0, stream>>>(rows, cnt, rnk, E);
  scan1<<<G, 256, 0, stream>>>(cnt, off, bsum, N);
  scan2<<<1, 64, 0, stream>>>(bsum, G);
  scan3<<<(N+255)/256, 256, 0, stream>>>(off, bsum, N);
  fill_k<<<eBlocks4, 256, 0, stream>>>(rows, cols, vals, off, rnk, ecv, E);

  // loga1 = chain(L@Lin1[1:,:], lin1_b) -> S3 (fp32)
  // h1    = chain(L@gc1_w[1:,:], gc1_b) -> Hb (bf16)      [merged, shared A]
  gemm_chain2<<<gemmBlocks, 512, 0, stream>>>(S0, Lin1 + 128, gc1_w + 128,
                                              Lin1_b, gc1_b, uu3, raw_c, S3, Hb, N);
  seg_x1<<<rowBlocks, 256, 0, stream>>>(Hb, off, cnt, ecv, S3, nparam, S1, N);
  // h2 = chain(Lx1@gc2_w, gc2_b) -> Hb (bf16; Lx1 comp0 == 0)
  gemm_chain<<<gemmBlocks, 512, 0, stream>>>(S1, gc2_w, gc2_b, uu3, 2, raw_c, Hb, N);
  seg_x2<<<rowBlocks, 256, 0, stream>>>(Hb, off, cnt, ecv, S0, N);  // Lx2 -> S0
  batch_head<<<Bn, 128, 0, stream>>>(S0, S3, bidx, weight, weight2, c1w, c1b,
                                     c2w, c2b, cls, clsb, (float*)d_out, Bn);
}

// Round 11
// 656.914 us; speedup vs baseline: 2.4955x; 1.0099x over previous
//
#include <hip/hip_runtime.h>
#include <math.h>

// ---------------------------------------------------------------------------
// Hyperbolic GCN forward, fully collapsed:
//  - logmap0(proj(expmap0(u))) == u ; bias chain is affine (At,Au per row)
//  - ALL GEMMs on matrix cores via split-bf16 (x = hi + lo, 3 MFMA passes:
//    hi*hi + hi*lo + lo*hi, fp32 accum => ~2^-16 relative error, safe for the
//    sel path). 16x16x32 bf16 MFMA; wave computes a 16x128 strip; no LDS.
//  - h1/h2 tables bf16; loga1/Lx2 fp32; CSR: rank-saving hist + atomic-free fill.
// ---------------------------------------------------------------------------

typedef unsigned short ushort_t;
typedef __attribute__((ext_vector_type(8))) short short8;
typedef __attribute__((ext_vector_type(4))) float f32x4;

__device__ __forceinline__ float wsum(float x){
  x += __shfl_xor(x, 32);
  x += __shfl_xor(x, 16);
  x += __shfl_xor(x, 8);
  x += __shfl_xor(x, 4);
  x += __shfl_xor(x, 2);
  x += __shfl_xor(x, 1);
  return x;
}

__device__ __forceinline__ void get_c(const float* rc, float& K, float& sK){
  float c = log1pf(expf(rc[0])) + 1e-5f;   // softplus(raw_c) + 1e-5
  K  = 1.0f / c;
  sK = sqrtf(K);
}

__device__ __forceinline__ float sinhx_over_x(float x){
  if (x > 1e-3f){
    float e  = __expf(x);
    float em = __builtin_amdgcn_rcpf(e);
    return 0.5f*(e - em) * __builtin_amdgcn_rcpf(x);
  }
  return 1.0f + x*x*(1.0f/6.0f);
}

__device__ __forceinline__ float facosh(float x){   // x >= 1+1e-7
  return __logf(x + sqrtf(fmaxf(fmaf(x, x, -1.0f), 0.0f)));
}

__device__ __forceinline__ ushort_t bf16_rne(float x){
  unsigned int u = __float_as_uint(x);
  u += 0x7fffu + ((u >> 16) & 1u);
  return (ushort_t)(u >> 16);
}
__device__ __forceinline__ float bf2f(ushort_t h){
  return __uint_as_float(((unsigned int)h) << 16);
}
__device__ __forceinline__ unsigned int pack_bf16(float x, float y){
  unsigned int bx = __float_as_uint(x);
  unsigned int by = __float_as_uint(y);
  bx = (bx + 0x7fffu + ((bx >> 16) & 1u)) >> 16;
  by = (by + 0x7fffu + ((by >> 16) & 1u)) & 0xffff0000u;
  return bx | by;
}
__device__ __forceinline__ float bf_lo(unsigned int p){ return __uint_as_float(p << 16); }
__device__ __forceinline__ float bf_hi(unsigned int p){ return __uint_as_float(p & 0xffff0000u); }

// Chain scalars: out_j = At*t_j + Au*u_j == logmap0(mobius_add(exp-chain)).
__device__ __forceinline__ void chain_scalars(float tt, float tu, float uu,
                                              float K, float sK,
                                              float& At, float& Au){
  float xn  = fmaxf(sqrtf(tt), 1e-15f);
  float th  = xn / sK;
  float f   = sinhx_over_x(th);
  float pn2 = f*f*tt;
  float p0  = sqrtf(fmaxf(K + pn2, 1e-7f));
  float S_yu = f * tu;
  float yn  = fmaxf(sqrtf(pn2), 1e-15f);
  float inv_yn = __builtin_amdgcn_rcpf(yn);
  float alpha = S_yu * inv_yn / sK;
  float coef  = alpha * (sK - p0);
  float cy  = coef * inv_yn;
  float cyf = cy * f;
  float pdw  = S_yu - cy*pn2;
  float spsq = uu - 2.f*cy*S_yu + cy*cy*pn2;
  float w0 = pdw / fmaxf(p0, 1e-7f);
  float md = spsq - w0*w0;
  float normu = fminf(sqrtf(fmaxf(md, 1e-7f)), 1e6f);
  float th2 = fmaxf(normu / sK, 1e-15f);
  float e  = __expf(th2);
  float em = __builtin_amdgcn_rcpf(e);
  float ch = 0.5f*(e + em);
  float g  = (th2 > 1e-3f) ? 0.5f*(e - em)*__builtin_amdgcn_rcpf(th2)
                           : 1.0f + th2*th2*(1.0f/6.0f);
  float rn2 = ch*ch*pn2 + 2.f*ch*g*pdw + g*g*spsq;
  float r0 = sqrtf(fmaxf(K + rn2, 1e-7f));
  float ynf = fmaxf(sqrtf(rn2), 1e-15f);
  float thf = fmaxf(r0/sK, 1.f+1e-7f);
  float rf = sK * facosh(thf) * __builtin_amdgcn_rcpf(ynf);
  At = rf*(ch*f - g*cyf);
  Au = rf*g;
}

// ---------- stage A: split A1[:,1:] into bf16 hi/lo; cnt zero; uu_prep ------
__global__ __launch_bounds__(256) void stage_a(const float* __restrict__ A1,
                                               ushort_t* __restrict__ Lhi,
                                               ushort_t* __restrict__ Llo,
                                               int* __restrict__ cnt,
                                               const float* __restrict__ b0,
                                               const float* __restrict__ b1,
                                               const float* __restrict__ b2,
                                               float* __restrict__ uu3, int n){
  size_t i = (size_t)blockIdx.x * 256 + threadIdx.x;
  size_t total = (size_t)n * 128;
  if (i < total){
    size_t row = i >> 7; int j = (int)(i & 127);
    float v = A1[row*129 + 1 + j];
    ushort_t h = bf16_rne(v);
    Lhi[i] = h;
    Llo[i] = bf16_rne(v - bf2f(h));
  }
  if (i < (size_t)n) cnt[i] = 0;
  if (blockIdx.x == 0 && threadIdx.x < 64){
    int lane = threadIdx.x;
    const float* bs[3] = {b0, b1, b2};
    for (int k = 0; k < 3; ++k){
      float x = lane ? bs[k][2*lane] : 0.0f;
      float y = bs[k][2*lane+1];
      float s = wsum(x*x + y*y);
      if (lane == 0) uu3[k] = s;
    }
  }
}

// ---------- split + transpose one 128x128 weight: W[k][n] -> Wt{hi,lo}[n][k] -
__global__ __launch_bounds__(256) void split_w(const float* __restrict__ W,
                                               ushort_t* __restrict__ Whi,
                                               ushort_t* __restrict__ Wlo){
  int id = blockIdx.x * 256 + threadIdx.x;   // 0..16383
  int k = id >> 7, nn = id & 127;
  float v = W[(size_t)k*128 + nn];
  ushort_t h = bf16_rne(v);
  Whi[(size_t)nn*128 + k] = h;
  Wlo[(size_t)nn*128 + k] = bf16_rne(v - bf2f(h));
}

// ---------- MFMA GEMM (split-bf16 x3) + fused chain epilogue ----------------
// Wave computes rows [m0, m0+16) x all 128 cols. 16x16x32 bf16 MFMA.
// A-frag: A[m=lane&15][k=quad*8+j]; B-frag: Wt[n=lane&15][k=quad*8+j];
// C/D: col=lane&15, row=quad*4+reg.
// mode 0: fp32 out; mode 1: packed bf16 out.
__global__ __launch_bounds__(256) void mfma_chain(const ushort_t* __restrict__ Ahi,
                                                  const ushort_t* __restrict__ Alo,
                                                  const ushort_t* __restrict__ Whi,
                                                  const ushort_t* __restrict__ Wlo,
                                                  const float* __restrict__ bias,
                                                  const float* __restrict__ uu3, int uuidx,
                                                  const float* __restrict__ raw_c,
                                                  float* __restrict__ outF,
                                                  unsigned int* __restrict__ outH,
                                                  int mode, int n){
  int wave = blockIdx.x * 4 + (threadIdx.x >> 6);
  int m0 = wave * 16;
  if (m0 >= n) return;
  int lane = threadIdx.x & 63;
  int c = lane & 15, quad = lane >> 4;

  int ra = m0 + c; if (ra > n - 1) ra = n - 1;     // A-load row (clamped)
  short8 ahi[4], alo[4];
  #pragma unroll
  for (int kc = 0; kc < 4; ++kc){
    size_t aoff = (size_t)ra*128 + kc*32 + quad*8;
    ahi[kc] = *(const short8*)&Ahi[aoff];
    alo[kc] = *(const short8*)&Alo[aoff];
  }

  f32x4 acc[8];
  #pragma unroll
  for (int t = 0; t < 8; ++t){
    f32x4 z = {0.f, 0.f, 0.f, 0.f};
    acc[t] = z;
    size_t wrow = (size_t)(t*16 + c) * 128;
    #pragma unroll
    for (int kc = 0; kc < 4; ++kc){
      size_t woff = wrow + kc*32 + quad*8;
      short8 bhi = *(const short8*)&Whi[woff];
      short8 blo = *(const short8*)&Wlo[woff];
      acc[t] = __builtin_amdgcn_mfma_f32_16x16x32_bf16(ahi[kc], bhi, acc[t], 0, 0, 0);
      acc[t] = __builtin_amdgcn_mfma_f32_16x16x32_bf16(ahi[kc], blo, acc[t], 0, 0, 0);
      acc[t] = __builtin_amdgcn_mfma_f32_16x16x32_bf16(alo[kc], bhi, acc[t], 0, 0, 0);
    }
  }

  // chain epilogue
  float K, sK; get_c(raw_c, K, sK);
  float uu = uu3[uuidx];
  float uv[8];
  #pragma unroll
  for (int t = 0; t < 8; ++t){
    int col = t*16 + c;
    uv[t] = (col == 0) ? 0.f : bias[col];
  }
  if (c == 0){                       // output col 0 = time component, dropped
    f32x4 z = {0.f, 0.f, 0.f, 0.f};
    acc[0] = z;
  }
  #pragma unroll
  for (int r = 0; r < 4; ++r){
    float tt = 0.f, tu = 0.f;
    #pragma unroll
    for (int t = 0; t < 8; ++t){
      float v = acc[t][r];
      tt = fmaf(v, v, tt);
      tu = fmaf(v, uv[t], tu);
    }
    #pragma unroll
    for (int m = 1; m <= 8; m <<= 1){   // reduce across 16 lanes of the quad
      tt += __shfl_xor(tt, m);
      tu += __shfl_xor(tu, m);
    }
    float At, Au; chain_scalars(tt, tu, uu, K, sK, At, Au);
    int row = m0 + quad*4 + r;
    if (row < n){
      if (mode == 0){
        #pragma unroll
        for (int t = 0; t < 8; ++t){
          float o = fmaf(At, acc[t][r], Au*uv[t]);
          outF[(size_t)row*128 + t*16 + c] = o;
        }
      } else {
        #pragma unroll
        for (int t = 0; t < 8; ++t){
          float o  = fmaf(At, acc[t][r], Au*uv[t]);
          float on = __shfl_xor(o, 1);
          if (!(c & 1))
            outH[(size_t)row*64 + t*8 + (c >> 1)] = pack_bf16(o, on);
        }
      }
    } else {
      // keep shuffles uniform for dead rows
      #pragma unroll
      for (int t = 0; t < 8; ++t){ float o = 0.f; (void)__shfl_xor(o, 1); }
    }
  }
}

// --------------------------- CSR build -------------------------------------
__global__ __launch_bounds__(256) void hist_k(const int* __restrict__ rows,
                                              int* __restrict__ cnt,
                                              int* __restrict__ rnk, int e){
  int base = (blockIdx.x * 256 + threadIdx.x) * 4;
  if (base + 3 < e){
    int4 r = *(const int4*)&rows[base];
    int k0 = atomicAdd(&cnt[r.x], 1);
    int k1 = atomicAdd(&cnt[r.y], 1);
    int k2 = atomicAdd(&cnt[r.z], 1);
    int k3 = atomicAdd(&cnt[r.w], 1);
    *(int4*)&rnk[base] = make_int4(k0, k1, k2, k3);
  } else {
    for (int i = base; i < e; ++i) rnk[i] = atomicAdd(&cnt[rows[i]], 1);
  }
}

#define SCAN_ITEMS 4
__global__ __launch_bounds__(256) void scan1(const int* __restrict__ cnt,
                                             int* __restrict__ off,
                                             int* __restrict__ bsum, int n){
  __shared__ int sh[256];
  int tid = threadIdx.x;
  int base = blockIdx.x * 256 * SCAN_ITEMS + tid * SCAN_ITEMS;
  int v[SCAN_ITEMS]; int s = 0;
  #pragma unroll
  for (int i = 0; i < SCAN_ITEMS; ++i){ int idx = base+i; v[i] = (idx < n) ? cnt[idx] : 0; s += v[i]; }
  sh[tid] = s; __syncthreads();
  for (int o = 1; o < 256; o <<= 1){
    int t = (tid >= o) ? sh[tid - o] : 0; __syncthreads();
    sh[tid] += t; __syncthreads();
  }
  int excl = sh[tid] - s;
  if (tid == 255) bsum[blockIdx.x] = sh[tid];
  int run = excl;
  #pragma unroll
  for (int i = 0; i < SCAN_ITEMS; ++i){ int idx = base+i; if (idx < n) off[idx] = run; run += v[i]; }
}

__global__ void scan2(int* bsum, int G){
  if (threadIdx.x == 0 && blockIdx.x == 0){
    int run = 0;
    for (int i = 0; i < G; ++i){ int t = bsum[i]; bsum[i] = run; run += t; }
  }
}

__global__ void scan3(int* __restrict__ off, const int* __restrict__ bsum, int n){
  int i = blockIdx.x * blockDim.x + threadIdx.x;
  if (i < n) off[i] += bsum[i / (256*SCAN_ITEMS)];
}

__global__ __launch_bounds__(256) void fill_k(const int* __restrict__ rows,
                                              const int* __restrict__ cols,
                                              const float* __restrict__ vals,
                                              const int* __restrict__ off,
                                              const int* __restrict__ rnk,
                                              int2* __restrict__ ecv, int e){
  int base = (blockIdx.x * 256 + threadIdx.x) * 4;
  if (base + 3 < e){
    int4   r = *(const int4*)&rows[base];
    int4   q = *(const int4*)&rnk[base];
    int4   c = *(const int4*)&cols[base];
    float4 v = *(const float4*)&vals[base];
    int o0 = off[r.x], o1 = off[r.y], o2 = off[r.z], o3 = off[r.w];
    ecv[o0 + q.x] = make_int2(c.x, __float_as_int(v.x));
    ecv[o1 + q.y] = make_int2(c.y, __float_as_int(v.y));
    ecv[o2 + q.z] = make_int2(c.z, __float_as_int(v.z));
    ecv[o3 + q.w] = make_int2(c.w, __float_as_int(v.w));
  } else {
    for (int i = base; i < e; ++i)
      ecv[off[rows[i]] + rnk[i]] = make_int2(cols[i], __float_as_int(vals[i]));
  }
}

// --------------------------- seg-sum (bf16 table, int2 edges) ---------------
__device__ __forceinline__ float2 seg_gather_bf16(const unsigned int* __restrict__ h,
                                                  const int* __restrict__ off,
                                                  const int* __restrict__ cnt,
                                                  const int2* __restrict__ ecv,
                                                  int row, int lane){
  float ax = 0.f, ay = 0.f, bx = 0.f, by = 0.f;
  int st = off[row], deg = cnt[row];
  const unsigned int* __restrict__ hb = h + lane;   // row stride = 64 uints
  for (int b = 0; b < deg; b += 64){
    int k = b + lane;
    int cc = 0; float vv = 0.f;
    if (k < deg){ int2 e = ecv[st+k]; cc = e.x; vv = __int_as_float(e.y); }
    int m = min(64, deg - b);
    for (int j = 0; j < m; j += 8){
      int   c0=__shfl(cc,j+0), c1=__shfl(cc,j+1), c2=__shfl(cc,j+2), c3=__shfl(cc,j+3);
      int   c4=__shfl(cc,j+4), c5=__shfl(cc,j+5), c6=__shfl(cc,j+6), c7=__shfl(cc,j+7);
      float v0=__shfl(vv,j+0), v1=__shfl(vv,j+1), v2=__shfl(vv,j+2), v3=__shfl(vv,j+3);
      float v4=__shfl(vv,j+4), v5=__shfl(vv,j+5), v6=__shfl(vv,j+6), v7=__shfl(vv,j+7);
      unsigned int p0 = hb[(size_t)c0*64];
      unsigned int p1 = hb[(size_t)c1*64];
      unsigned int p2 = hb[(size_t)c2*64];
      unsigned int p3 = hb[(size_t)c3*64];
      unsigned int p4 = hb[(size_t)c4*64];
      unsigned int p5 = hb[(size_t)c5*64];
      unsigned int p6 = hb[(size_t)c6*64];
      unsigned int p7 = hb[(size_t)c7*64];
      ax = fmaf(v0, bf_lo(p0), ax); ay = fmaf(v0, bf_hi(p0), ay);
      bx = fmaf(v1, bf_lo(p1), bx); by = fmaf(v1, bf_hi(p1), by);
      ax = fmaf(v2, bf_lo(p2), ax); ay = fmaf(v2, bf_hi(p2), ay);
      bx = fmaf(v3, bf_lo(p3), bx); by = fmaf(v3, bf_hi(p3), by);
      ax = fmaf(v4, bf_lo(p4), ax); ay = fmaf(v4, bf_hi(p4), ay);
      bx = fmaf(v5, bf_lo(p5), bx); by = fmaf(v5, bf_hi(p5), by);
      ax = fmaf(v6, bf_lo(p6), ax); ay = fmaf(v6, bf_hi(p6), ay);
      bx = fmaf(v7, bf_lo(p7), bx); by = fmaf(v7, bf_hi(p7), by);
    }
  }
  return make_float2(ax + bx, ay + by);
}

// ------ seg_x1: Lx1 = (1-n)*segsum(h1) + n*loga1 -> bf16 hi/lo split --------
__global__ __launch_bounds__(256) void seg_x1(const unsigned int* __restrict__ h1,
                                              const int* __restrict__ off,
                                              const int* __restrict__ cnt,
                                              const int2* __restrict__ ecv,
                                              const float* __restrict__ loga1,
                                              const float* __restrict__ nparam,
                                              unsigned int* __restrict__ X1hi,
                                              unsigned int* __restrict__ X1lo, int n){
  int row  = (int)((blockIdx.x * blockDim.x + threadIdx.x) >> 6);
  int lane = threadIdx.x & 63;
  if (row >= n) return;
  float2 acc = seg_gather_bf16(h1, off, cnt, ecv, row, lane);
  float nv = nparam[row];
  float2 la1 = *(const float2*)&loga1[(size_t)row*128 + 2*lane];
  float ox = (1.f-nv)*acc.x + nv*la1.x;
  float oy = (1.f-nv)*acc.y + nv*la1.y;
  unsigned int hp = pack_bf16(ox, oy);
  X1hi[(size_t)row*64 + lane] = hp;
  X1lo[(size_t)row*64 + lane] = pack_bf16(ox - bf_lo(hp), oy - bf_hi(hp));
}

// ------------------- seg_x2: Lx2 = segsum(h2)  (fp32 out) -------------------
__global__ __launch_bounds__(256) void seg_x2(const unsigned int* __restrict__ h2,
                                              const int* __restrict__ off,
                                              const int* __restrict__ cnt,
                                              const int2* __restrict__ ecv,
                                              float* __restrict__ Lx2, int n){
  int row  = (int)((blockIdx.x * blockDim.x + threadIdx.x) >> 6);
  int lane = threadIdx.x & 63;
  if (row >= n) return;
  float2 acc = seg_gather_bf16(h2, off, cnt, ecv, row, lane);
  *(float2*)&Lx2[(size_t)row*128 + 2*lane] = acc;
}

// --------------------------- batch head (fp32 tables) -----------------------
__global__ __launch_bounds__(128) void batch_head(const float* __restrict__ Lx2,
                                                  const float* __restrict__ loga1,
                                                  const int* __restrict__ bidx,
                                                  const float* __restrict__ weight,
                                                  const float* __restrict__ weight2,
                                                  const float* __restrict__ c1w,
                                                  const float* __restrict__ c1b,
                                                  const float* __restrict__ c2w,
                                                  const float* __restrict__ c2b,
                                                  const float* __restrict__ cls,
                                                  const float* __restrict__ clsb,
                                                  float* __restrict__ out, int Bn){
  __shared__ float sg2[128], sg3[128], ssel[100], spre[5];
  __shared__ int sbi[50];
  __shared__ float sc1[50], sc2[50];
  int b = blockIdx.x, d = threadIdx.x;
  const int* bi = bidx + (size_t)b * 50;
  if (d < 50){ sbi[d] = bi[d]; sc1[d] = c1w[d]; sc2[d] = c2w[d]; }
  __syncthreads();
  int lane = d & 63;
  bool lo = d < 64;
  const float* __restrict__ tab = lo ? Lx2 : loga1;
  const float* __restrict__ cw = lo ? sc1 : sc2;
  float gx = 0.f, gy = 0.f;
  const float2* __restrict__ t2 = (const float2*)tab + lane;  // row stride 64
  #pragma unroll
  for (int l = 0; l < 50; l += 5){
    int i0 = sbi[l+0], i1 = sbi[l+1], i2 = sbi[l+2], i3 = sbi[l+3], i4 = sbi[l+4];
    float2 p0 = t2[(size_t)i0*64];
    float2 p1 = t2[(size_t)i1*64];
    float2 p2 = t2[(size_t)i2*64];
    float2 p3 = t2[(size_t)i3*64];
    float2 p4 = t2[(size_t)i4*64];
    float w0 = cw[l+0], w1 = cw[l+1], w2 = cw[l+2], w3 = cw[l+3], w4 = cw[l+4];
    gx = fmaf(w0, p0.x, gx); gy = fmaf(w0, p0.y, gy);
    gx = fmaf(w1, p1.x, gx); gy = fmaf(w1, p1.y, gy);
    gx = fmaf(w2, p2.x, gx); gy = fmaf(w2, p2.y, gy);
    gx = fmaf(w3, p3.x, gx); gy = fmaf(w3, p3.y, gy);
    gx = fmaf(w4, p4.x, gx); gy = fmaf(w4, p4.y, gy);
  }
  if (lo){ sg2[2*lane] = gx; sg2[2*lane+1] = gy; }
  else   { sg3[2*lane] = gx; sg3[2*lane+1] = gy; }
  __syncthreads();
  if (d < 50){
    float s = 0.f;
    for (int k = 0; k < 128; ++k) s = fmaf(sg2[k], weight[k*50 + d], s);
    s += c1b[0];
    ssel[d] = s;
    out[(size_t)Bn + (size_t)b*100 + d] = s;
  } else if (d >= 64 && d < 114){
    int t = d - 64;
    float s = 0.f;
    for (int k = 0; k < 128; ++k) s = fmaf(sg3[k], weight2[k*50 + t], s);
    s += c2b[0];
    ssel[50 + t] = s;
    out[(size_t)Bn + (size_t)b*100 + 50 + t] = s;
  }
  __syncthreads();
  if (d < 5){
    float s = clsb[d];
    for (int j = 0; j < 100; ++j) s = fmaf(ssel[j], cls[j*5 + d], s);
    spre[d] = s;
  }
  __syncthreads();
  if (d == 0){
    int best = 0; float bv = spre[0];
    #pragma unroll
    for (int k = 1; k < 5; ++k) if (spre[k] > bv){ bv = spre[k]; best = k; }
    out[b] = (float)best;
  }
}

// ---------------------------------------------------------------------------
extern "C" void kernel_launch(void* const* d_in, const int* in_sizes, int n_in,
                              void* d_out, int out_size, void* d_ws, size_t ws_size,
                              hipStream_t stream) {
  const float* A1     = (const float*)d_in[0];
  const int*   rows   = (const int*)  d_in[1];
  const int*   cols   = (const int*)  d_in[2];
  const float* vals   = (const float*)d_in[3];
  const int*   bidx   = (const int*)  d_in[4];
  const float* raw_c  = (const float*)d_in[5];
  const float* nparam = (const float*)d_in[6];
  const float* Lin1   = (const float*)d_in[7];
  const float* Lin1_b = (const float*)d_in[8];
  const float* gc1_w  = (const float*)d_in[9];
  const float* gc1_b  = (const float*)d_in[10];
  const float* gc2_w  = (const float*)d_in[11];
  const float* gc2_b  = (const float*)d_in[12];
  const float* weight = (const float*)d_in[13];
  const float* weight2= (const float*)d_in[14];
  const float* c1w    = (const float*)d_in[15];
  const float* c1b    = (const float*)d_in[16];
  const float* c2w    = (const float*)d_in[17];
  const float* c2b    = (const float*)d_in[18];
  const float* cls    = (const float*)d_in[19];
  const float* clsb   = (const float*)d_in[20];

  int N  = in_sizes[0] / 129;
  int E  = in_sizes[1];
  int Bn = in_sizes[4] / 50;
  size_t NF = (size_t)N * 128;

  // workspace layout (region A: Lhi/Llo early, reused as fp32 Lx2 late)
  ushort_t* Lhi = (ushort_t*)d_ws;              // 2NF B
  ushort_t* Llo = Lhi + NF;                     // 2NF B
  float*    S0  = (float*)d_ws;                 // Lx2 fp32 (aliases Lhi/Llo)
  float*    S3  = (float*)(Llo + NF);           // loga1 fp32, 4NF B
  unsigned int* Hb   = (unsigned int*)(S3 + NF);  // h1/h2 bf16, 2NF B
  unsigned int* X1hi = Hb + NF/2;               // Lx1 hi, 2NF B
  unsigned int* X1lo = X1hi + NF/2;             // Lx1 lo, 2NF B
  ushort_t* Wb = (ushort_t*)(X1lo + NF/2);      // 6 x 16384 ushorts
  ushort_t* W1h = Wb,           *W1l = Wb + 16384;
  ushort_t* W2h = Wb + 2*16384, *W2l = Wb + 3*16384;
  ushort_t* W3h = Wb + 4*16384, *W3l = Wb + 5*16384;
  int* cnt    = (int*)(Wb + 6*16384);
  int* off    = cnt + N;
  int* rnk    = off + N;
  int* bsum   = rnk + E;
  int2* ecv   = (int2*)(bsum + 4096);
  float* uu3  = (float*)(ecv + E);

  int rowBlocks  = (N + 3) / 4;
  int strips     = (N + 15) / 16;
  int mBlocks    = (strips + 3) / 4;
  int G = (N + 256*SCAN_ITEMS - 1) / (256*SCAN_ITEMS);
  int eBlocks4 = (E/4 + 255) / 256 + 1;

  stage_a<<<(int)((NF + 255)/256), 256, 0, stream>>>(A1, Lhi, Llo, cnt,
                                                     Lin1_b, gc1_b, gc2_b, uu3, N);
  split_w<<<64, 256, 0, stream>>>(Lin1 + 128, W1h, W1l);
  split_w<<<64, 256, 0, stream>>>(gc1_w + 128, W2h, W2l);
  split_w<<<64, 256, 0, stream>>>(gc2_w, W3h, W3l);

  hist_k<<<eBlocks4, 256, 0, stream>>>(rows, cnt, rnk, E);
  scan1<<<G, 256, 0, stream>>>(cnt, off, bsum, N);
  scan2<<<1, 64, 0, stream>>>(bsum, G);
  scan3<<<(N+255)/256, 256, 0, stream>>>(off, bsum, N);
  fill_k<<<eBlocks4, 256, 0, stream>>>(rows, cols, vals, off, rnk, ecv, E);

  // loga1 = chain(L@Lin1[1:,:], lin1_b) -> S3 (fp32)
  mfma_chain<<<mBlocks, 256, 0, stream>>>(Lhi, Llo, W1h, W1l, Lin1_b, uu3, 0, raw_c,
                                          S3, (unsigned int*)nullptr, 0, N);
  // h1 = chain(L@gc1_w[1:,:], gc1_b) -> Hb (bf16)
  mfma_chain<<<mBlocks, 256, 0, stream>>>(Lhi, Llo, W2h, W2l, gc1_b, uu3, 1, raw_c,
                                          (float*)nullptr, Hb, 1, N);
  seg_x1<<<rowBlocks, 256, 0, stream>>>(Hb, off, cnt, ecv, S3, nparam, X1hi, X1lo, N);
  // h2 = chain(Lx1@gc2_w, gc2_b) -> Hb (bf16)
  mfma_chain<<<mBlocks, 256, 0, stream>>>((const ushort_t*)X1hi, (const ushort_t*)X1lo,
                                          W3h, W3l, gc2_b, uu3, 2, raw_c,
                                          (float*)nullptr, Hb, 1, N);
  seg_x2<<<rowBlocks, 256, 0, stream>>>(Hb, off, cnt, ecv, S0, N);  // Lx2 -> S0
  batch_head<<<Bn, 128, 0, stream>>>(S0, S3, bidx, weight, weight2, c1w, c1b,
                                     c2w, c2b, cls, clsb, (float*)d_out, Bn);
}

// Round 12
// 622.365 us; speedup vs baseline: 2.6340x; 1.0555x over previous
//
#include <hip/hip_runtime.h>
#include <math.h>

// ---------------------------------------------------------------------------
// Hyperbolic GCN forward, fully collapsed:
//  - logmap0(proj(expmap0(u))) == u ; bias chain is affine (At,Au per row)
//  - ALL GEMMs on matrix cores via split-bf16 (x = hi + lo, 3 MFMA passes:
//    hi*hi + hi*lo + lo*hi, fp32 accum => ~2^-16 relative error).
//  - W (hi+lo, 64 KB) staged in LDS once per block; 512 persistent blocks
//    grid-stride over 16-row strips -> W global traffic 400 MB -> 32 MB,
//    ds_read_b128 replaces ~200cy L2 hits (round 11 was latency-bound,
//    MfmaUtil 4.8% / VALU 23% / VGPR 52 = no loads in flight).
//  - h1/h2 tables bf16; loga1/Lx2 fp32; CSR: rank-saving hist + atomic-free fill.
// ---------------------------------------------------------------------------

typedef unsigned short ushort_t;
typedef __attribute__((ext_vector_type(8))) short short8;
typedef __attribute__((ext_vector_type(4))) float f32x4;

__device__ __forceinline__ float wsum(float x){
  x += __shfl_xor(x, 32);
  x += __shfl_xor(x, 16);
  x += __shfl_xor(x, 8);
  x += __shfl_xor(x, 4);
  x += __shfl_xor(x, 2);
  x += __shfl_xor(x, 1);
  return x;
}

__device__ __forceinline__ void get_c(const float* rc, float& K, float& sK){
  float c = log1pf(expf(rc[0])) + 1e-5f;   // softplus(raw_c) + 1e-5
  K  = 1.0f / c;
  sK = sqrtf(K);
}

__device__ __forceinline__ float sinhx_over_x(float x){
  if (x > 1e-3f){
    float e  = __expf(x);
    float em = __builtin_amdgcn_rcpf(e);
    return 0.5f*(e - em) * __builtin_amdgcn_rcpf(x);
  }
  return 1.0f + x*x*(1.0f/6.0f);
}

__device__ __forceinline__ float facosh(float x){   // x >= 1+1e-7
  return __logf(x + sqrtf(fmaxf(fmaf(x, x, -1.0f), 0.0f)));
}

__device__ __forceinline__ ushort_t bf16_rne(float x){
  unsigned int u = __float_as_uint(x);
  u += 0x7fffu + ((u >> 16) & 1u);
  return (ushort_t)(u >> 16);
}
__device__ __forceinline__ float bf2f(ushort_t h){
  return __uint_as_float(((unsigned int)h) << 16);
}
__device__ __forceinline__ unsigned int pack_bf16(float x, float y){
  unsigned int bx = __float_as_uint(x);
  unsigned int by = __float_as_uint(y);
  bx = (bx + 0x7fffu + ((bx >> 16) & 1u)) >> 16;
  by = (by + 0x7fffu + ((by >> 16) & 1u)) & 0xffff0000u;
  return bx | by;
}
__device__ __forceinline__ float bf_lo(unsigned int p){ return __uint_as_float(p << 16); }
__device__ __forceinline__ float bf_hi(unsigned int p){ return __uint_as_float(p & 0xffff0000u); }

// Chain scalars: out_j = At*t_j + Au*u_j == logmap0(mobius_add(exp-chain)).
__device__ __forceinline__ void chain_scalars(float tt, float tu, float uu,
                                              float K, float sK,
                                              float& At, float& Au){
  float xn  = fmaxf(sqrtf(tt), 1e-15f);
  float th  = xn / sK;
  float f   = sinhx_over_x(th);
  float pn2 = f*f*tt;
  float p0  = sqrtf(fmaxf(K + pn2, 1e-7f));
  float S_yu = f * tu;
  float yn  = fmaxf(sqrtf(pn2), 1e-15f);
  float inv_yn = __builtin_amdgcn_rcpf(yn);
  float alpha = S_yu * inv_yn / sK;
  float coef  = alpha * (sK - p0);
  float cy  = coef * inv_yn;
  float cyf = cy * f;
  float pdw  = S_yu - cy*pn2;
  float spsq = uu - 2.f*cy*S_yu + cy*cy*pn2;
  float w0 = pdw / fmaxf(p0, 1e-7f);
  float md = spsq - w0*w0;
  float normu = fminf(sqrtf(fmaxf(md, 1e-7f)), 1e6f);
  float th2 = fmaxf(normu / sK, 1e-15f);
  float e  = __expf(th2);
  float em = __builtin_amdgcn_rcpf(e);
  float ch = 0.5f*(e + em);
  float g  = (th2 > 1e-3f) ? 0.5f*(e - em)*__builtin_amdgcn_rcpf(th2)
                           : 1.0f + th2*th2*(1.0f/6.0f);
  float rn2 = ch*ch*pn2 + 2.f*ch*g*pdw + g*g*spsq;
  float r0 = sqrtf(fmaxf(K + rn2, 1e-7f));
  float ynf = fmaxf(sqrtf(rn2), 1e-15f);
  float thf = fmaxf(r0/sK, 1.f+1e-7f);
  float rf = sK * facosh(thf) * __builtin_amdgcn_rcpf(ynf);
  At = rf*(ch*f - g*cyf);
  Au = rf*g;
}

// ---------- stage A: split A1[:,1:] into bf16 hi/lo; cnt zero; uu_prep ------
__global__ __launch_bounds__(256) void stage_a(const float* __restrict__ A1,
                                               ushort_t* __restrict__ Lhi,
                                               ushort_t* __restrict__ Llo,
                                               int* __restrict__ cnt,
                                               const float* __restrict__ b0,
                                               const float* __restrict__ b1,
                                               const float* __restrict__ b2,
                                               float* __restrict__ uu3, int n){
  size_t i = (size_t)blockIdx.x * 256 + threadIdx.x;
  size_t total = (size_t)n * 128;
  if (i < total){
    size_t row = i >> 7; int j = (int)(i & 127);
    float v = A1[row*129 + 1 + j];
    ushort_t h = bf16_rne(v);
    Lhi[i] = h;
    Llo[i] = bf16_rne(v - bf2f(h));
  }
  if (i < (size_t)n) cnt[i] = 0;
  if (blockIdx.x == 0 && threadIdx.x < 64){
    int lane = threadIdx.x;
    const float* bs[3] = {b0, b1, b2};
    for (int k = 0; k < 3; ++k){
      float x = lane ? bs[k][2*lane] : 0.0f;
      float y = bs[k][2*lane+1];
      float s = wsum(x*x + y*y);
      if (lane == 0) uu3[k] = s;
    }
  }
}

// ---------- split + transpose one 128x128 weight: W[k][n] -> Wt{hi,lo}[n][k] -
__global__ __launch_bounds__(256) void split_w(const float* __restrict__ W,
                                               ushort_t* __restrict__ Whi,
                                               ushort_t* __restrict__ Wlo){
  int id = blockIdx.x * 256 + threadIdx.x;   // 0..16383
  int k = id >> 7, nn = id & 127;
  float v = W[(size_t)k*128 + nn];
  ushort_t h = bf16_rne(v);
  Whi[(size_t)nn*128 + k] = h;
  Wlo[(size_t)nn*128 + k] = bf16_rne(v - bf2f(h));
}

// ---------- MFMA GEMM (split-bf16 x3), W staged in LDS, grid-stride strips --
// Wave computes rows [m0, m0+16) x all 128 cols per strip. 16x16x32 bf16 MFMA.
// A-frag: A[m=lane&15][k=quad*8+j]; B-frag: Wt[n=lane&15][k=quad*8+j];
// C/D: col=lane&15, row=quad*4+reg.   mode 0: fp32 out; 1: packed bf16 out.
__global__ __launch_bounds__(256) void mfma_chain(const ushort_t* __restrict__ Ahi,
                                                  const ushort_t* __restrict__ Alo,
                                                  const ushort_t* __restrict__ Whi,
                                                  const ushort_t* __restrict__ Wlo,
                                                  const float* __restrict__ bias,
                                                  const float* __restrict__ uu3, int uuidx,
                                                  const float* __restrict__ raw_c,
                                                  float* __restrict__ outF,
                                                  unsigned int* __restrict__ outH,
                                                  int mode, int n, int nWaves){
  __shared__ ushort_t Wsh[2][128*128];   // 64 KB: [0]=hi, [1]=lo, Wt[n][k]
  int tid = threadIdx.x;
  {
    const uint4* gh = (const uint4*)Whi;
    const uint4* gl = (const uint4*)Wlo;
    uint4* sh = (uint4*)Wsh[0];
    uint4* sl = (uint4*)Wsh[1];
    #pragma unroll
    for (int i = 0; i < 8; ++i){ sh[tid + 256*i] = gh[tid + 256*i]; }
    #pragma unroll
    for (int i = 0; i < 8; ++i){ sl[tid + 256*i] = gl[tid + 256*i]; }
  }
  __syncthreads();

  int lane = tid & 63;
  int c = lane & 15, quad = lane >> 4;
  int wid = blockIdx.x * 4 + (tid >> 6);
  int nStrips = (n + 15) >> 4;

  float K, sK; get_c(raw_c, K, sK);
  float uu = uu3[uuidx];
  float uv[8];
  #pragma unroll
  for (int t = 0; t < 8; ++t){
    int col = t*16 + c;
    uv[t] = (col == 0) ? 0.f : bias[col];
  }

  for (int strip = wid; strip < nStrips; strip += nWaves){
    int m0 = strip * 16;
    int ra = m0 + c; if (ra > n - 1) ra = n - 1;
    short8 ahi[4], alo[4];
    #pragma unroll
    for (int kc = 0; kc < 4; ++kc){
      size_t aoff = (size_t)ra*128 + kc*32 + quad*8;
      ahi[kc] = *(const short8*)&Ahi[aoff];
      alo[kc] = *(const short8*)&Alo[aoff];
    }

    f32x4 acc[8];
    #pragma unroll
    for (int t = 0; t < 8; ++t){
      f32x4 z = {0.f, 0.f, 0.f, 0.f};
      acc[t] = z;
      int wrow = (t*16 + c) * 128;
      #pragma unroll
      for (int kc = 0; kc < 4; ++kc){
        int woff = wrow + kc*32 + quad*8;
        short8 bhi = *(const short8*)&Wsh[0][woff];
        short8 blo = *(const short8*)&Wsh[1][woff];
        acc[t] = __builtin_amdgcn_mfma_f32_16x16x32_bf16(ahi[kc], bhi, acc[t], 0, 0, 0);
        acc[t] = __builtin_amdgcn_mfma_f32_16x16x32_bf16(ahi[kc], blo, acc[t], 0, 0, 0);
        acc[t] = __builtin_amdgcn_mfma_f32_16x16x32_bf16(alo[kc], bhi, acc[t], 0, 0, 0);
      }
    }

    if (c == 0){                     // output col 0 = time component, dropped
      f32x4 z = {0.f, 0.f, 0.f, 0.f};
      acc[0] = z;
    }
    #pragma unroll
    for (int r = 0; r < 4; ++r){
      float tt = 0.f, tu = 0.f;
      #pragma unroll
      for (int t = 0; t < 8; ++t){
        float v = acc[t][r];
        tt = fmaf(v, v, tt);
        tu = fmaf(v, uv[t], tu);
      }
      #pragma unroll
      for (int m = 1; m <= 8; m <<= 1){   // reduce across 16 lanes of the quad
        tt += __shfl_xor(tt, m);
        tu += __shfl_xor(tu, m);
      }
      float At, Au; chain_scalars(tt, tu, uu, K, sK, At, Au);
      int row = m0 + quad*4 + r;
      if (mode == 0){
        if (row < n){
          #pragma unroll
          for (int t = 0; t < 8; ++t){
            float o = fmaf(At, acc[t][r], Au*uv[t]);
            outF[(size_t)row*128 + t*16 + c] = o;
          }
        }
      } else {
        #pragma unroll
        for (int t = 0; t < 8; ++t){
          float o  = fmaf(At, acc[t][r], Au*uv[t]);
          float on = __shfl_xor(o, 1);
          if (row < n && !(c & 1))
            outH[(size_t)row*64 + t*8 + (c >> 1)] = pack_bf16(o, on);
        }
      }
    }
  }
}

// --------------------------- CSR build -------------------------------------
__global__ __launch_bounds__(256) void hist_k(const int* __restrict__ rows,
                                              int* __restrict__ cnt,
                                              int* __restrict__ rnk, int e){
  int base = (blockIdx.x * 256 + threadIdx.x) * 4;
  if (base + 3 < e){
    int4 r = *(const int4*)&rows[base];
    int k0 = atomicAdd(&cnt[r.x], 1);
    int k1 = atomicAdd(&cnt[r.y], 1);
    int k2 = atomicAdd(&cnt[r.z], 1);
    int k3 = atomicAdd(&cnt[r.w], 1);
    *(int4*)&rnk[base] = make_int4(k0, k1, k2, k3);
  } else {
    for (int i = base; i < e; ++i) rnk[i] = atomicAdd(&cnt[rows[i]], 1);
  }
}

#define SCAN_ITEMS 4
__global__ __launch_bounds__(256) void scan1(const int* __restrict__ cnt,
                                             int* __restrict__ off,
                                             int* __restrict__ bsum, int n){
  __shared__ int sh[256];
  int tid = threadIdx.x;
  int base = blockIdx.x * 256 * SCAN_ITEMS + tid * SCAN_ITEMS;
  int v[SCAN_ITEMS]; int s = 0;
  #pragma unroll
  for (int i = 0; i < SCAN_ITEMS; ++i){ int idx = base+i; v[i] = (idx < n) ? cnt[idx] : 0; s += v[i]; }
  sh[tid] = s; __syncthreads();
  for (int o = 1; o < 256; o <<= 1){
    int t = (tid >= o) ? sh[tid - o] : 0; __syncthreads();
    sh[tid] += t; __syncthreads();
  }
  int excl = sh[tid] - s;
  if (tid == 255) bsum[blockIdx.x] = sh[tid];
  int run = excl;
  #pragma unroll
  for (int i = 0; i < SCAN_ITEMS; ++i){ int idx = base+i; if (idx < n) off[idx] = run; run += v[i]; }
}

__global__ void scan2(int* bsum, int G){
  if (threadIdx.x == 0 && blockIdx.x == 0){
    int run = 0;
    for (int i = 0; i < G; ++i){ int t = bsum[i]; bsum[i] = run; run += t; }
  }
}

__global__ void scan3(int* __restrict__ off, const int* __restrict__ bsum, int n){
  int i = blockIdx.x * blockDim.x + threadIdx.x;
  if (i < n) off[i] += bsum[i / (256*SCAN_ITEMS)];
}

__global__ __launch_bounds__(256) void fill_k(const int* __restrict__ rows,
                                              const int* __restrict__ cols,
                                              const float* __restrict__ vals,
                                              const int* __restrict__ off,
                                              const int* __restrict__ rnk,
                                              int2* __restrict__ ecv, int e){
  int base = (blockIdx.x * 256 + threadIdx.x) * 4;
  if (base + 3 < e){
    int4   r = *(const int4*)&rows[base];
    int4   q = *(const int4*)&rnk[base];
    int4   c = *(const int4*)&cols[base];
    float4 v = *(const float4*)&vals[base];
    int o0 = off[r.x], o1 = off[r.y], o2 = off[r.z], o3 = off[r.w];
    ecv[o0 + q.x] = make_int2(c.x, __float_as_int(v.x));
    ecv[o1 + q.y] = make_int2(c.y, __float_as_int(v.y));
    ecv[o2 + q.z] = make_int2(c.z, __float_as_int(v.z));
    ecv[o3 + q.w] = make_int2(c.w, __float_as_int(v.w));
  } else {
    for (int i = base; i < e; ++i)
      ecv[off[rows[i]] + rnk[i]] = make_int2(cols[i], __float_as_int(vals[i]));
  }
}

// --------------------------- seg-sum (bf16 table, int2 edges) ---------------
__device__ __forceinline__ float2 seg_gather_bf16(const unsigned int* __restrict__ h,
                                                  const int* __restrict__ off,
                                                  const int* __restrict__ cnt,
                                                  const int2* __restrict__ ecv,
                                                  int row, int lane){
  float ax = 0.f, ay = 0.f, bx = 0.f, by = 0.f;
  int st = off[row], deg = cnt[row];
  const unsigned int* __restrict__ hb = h + lane;   // row stride = 64 uints
  for (int b = 0; b < deg; b += 64){
    int k = b + lane;
    int cc = 0; float vv = 0.f;
    if (k < deg){ int2 e = ecv[st+k]; cc = e.x; vv = __int_as_float(e.y); }
    int m = min(64, deg - b);
    for (int j = 0; j < m; j += 8){
      int   c0=__shfl(cc,j+0), c1=__shfl(cc,j+1), c2=__shfl(cc,j+2), c3=__shfl(cc,j+3);
      int   c4=__shfl(cc,j+4), c5=__shfl(cc,j+5), c6=__shfl(cc,j+6), c7=__shfl(cc,j+7);
      float v0=__shfl(vv,j+0), v1=__shfl(vv,j+1), v2=__shfl(vv,j+2), v3=__shfl(vv,j+3);
      float v4=__shfl(vv,j+4), v5=__shfl(vv,j+5), v6=__shfl(vv,j+6), v7=__shfl(vv,j+7);
      unsigned int p0 = hb[(size_t)c0*64];
      unsigned int p1 = hb[(size_t)c1*64];
      unsigned int p2 = hb[(size_t)c2*64];
      unsigned int p3 = hb[(size_t)c3*64];
      unsigned int p4 = hb[(size_t)c4*64];
      unsigned int p5 = hb[(size_t)c5*64];
      unsigned int p6 = hb[(size_t)c6*64];
      unsigned int p7 = hb[(size_t)c7*64];
      ax = fmaf(v0, bf_lo(p0), ax); ay = fmaf(v0, bf_hi(p0), ay);
      bx = fmaf(v1, bf_lo(p1), bx); by = fmaf(v1, bf_hi(p1), by);
      ax = fmaf(v2, bf_lo(p2), ax); ay = fmaf(v2, bf_hi(p2), ay);
      bx = fmaf(v3, bf_lo(p3), bx); by = fmaf(v3, bf_hi(p3), by);
      ax = fmaf(v4, bf_lo(p4), ax); ay = fmaf(v4, bf_hi(p4), ay);
      bx = fmaf(v5, bf_lo(p5), bx); by = fmaf(v5, bf_hi(p5), by);
      ax = fmaf(v6, bf_lo(p6), ax); ay = fmaf(v6, bf_hi(p6), ay);
      bx = fmaf(v7, bf_lo(p7), bx); by = fmaf(v7, bf_hi(p7), by);
    }
  }
  return make_float2(ax + bx, ay + by);
}

// ------ seg_x1: Lx1 = (1-n)*segsum(h1) + n*loga1 -> bf16 hi/lo split --------
__global__ __launch_bounds__(256) void seg_x1(const unsigned int* __restrict__ h1,
                                              const int* __restrict__ off,
                                              const int* __restrict__ cnt,
                                              const int2* __restrict__ ecv,
                                              const float* __restrict__ loga1,
                                              const float* __restrict__ nparam,
                                              unsigned int* __restrict__ X1hi,
                                              unsigned int* __restrict__ X1lo, int n){
  int row  = (int)((blockIdx.x * blockDim.x + threadIdx.x) >> 6);
  int lane = threadIdx.x & 63;
  if (row >= n) return;
  float2 acc = seg_gather_bf16(h1, off, cnt, ecv, row, lane);
  float nv = nparam[row];
  float2 la1 = *(const float2*)&loga1[(size_t)row*128 + 2*lane];
  float ox = (1.f-nv)*acc.x + nv*la1.x;
  float oy = (1.f-nv)*acc.y + nv*la1.y;
  unsigned int hp = pack_bf16(ox, oy);
  X1hi[(size_t)row*64 + lane] = hp;
  X1lo[(size_t)row*64 + lane] = pack_bf16(ox - bf_lo(hp), oy - bf_hi(hp));
}

// ------------------- seg_x2: Lx2 = segsum(h2)  (fp32 out) -------------------
__global__ __launch_bounds__(256) void seg_x2(const unsigned int* __restrict__ h2,
                                              const int* __restrict__ off,
                                              const int* __restrict__ cnt,
                                              const int2* __restrict__ ecv,
                                              float* __restrict__ Lx2, int n){
  int row  = (int)((blockIdx.x * blockDim.x + threadIdx.x) >> 6);
  int lane = threadIdx.x & 63;
  if (row >= n) return;
  float2 acc = seg_gather_bf16(h2, off, cnt, ecv, row, lane);
  *(float2*)&Lx2[(size_t)row*128 + 2*lane] = acc;
}

// --------------------------- batch head (fp32 tables) -----------------------
__global__ __launch_bounds__(128) void batch_head(const float* __restrict__ Lx2,
                                                  const float* __restrict__ loga1,
                                                  const int* __restrict__ bidx,
                                                  const float* __restrict__ weight,
                                                  const float* __restrict__ weight2,
                                                  const float* __restrict__ c1w,
                                                  const float* __restrict__ c1b,
                                                  const float* __restrict__ c2w,
                                                  const float* __restrict__ c2b,
                                                  const float* __restrict__ cls,
                                                  const float* __restrict__ clsb,
                                                  float* __restrict__ out, int Bn){
  __shared__ float sg2[128], sg3[128], ssel[100], spre[5];
  __shared__ int sbi[50];
  __shared__ float sc1[50], sc2[50];
  int b = blockIdx.x, d = threadIdx.x;
  const int* bi = bidx + (size_t)b * 50;
  if (d < 50){ sbi[d] = bi[d]; sc1[d] = c1w[d]; sc2[d] = c2w[d]; }
  __syncthreads();
  int lane = d & 63;
  bool lo = d < 64;
  const float* __restrict__ tab = lo ? Lx2 : loga1;
  const float* __restrict__ cw = lo ? sc1 : sc2;
  float gx = 0.f, gy = 0.f;
  const float2* __restrict__ t2 = (const float2*)tab + lane;  // row stride 64
  #pragma unroll
  for (int l = 0; l < 50; l += 5){
    int i0 = sbi[l+0], i1 = sbi[l+1], i2 = sbi[l+2], i3 = sbi[l+3], i4 = sbi[l+4];
    float2 p0 = t2[(size_t)i0*64];
    float2 p1 = t2[(size_t)i1*64];
    float2 p2 = t2[(size_t)i2*64];
    float2 p3 = t2[(size_t)i3*64];
    float2 p4 = t2[(size_t)i4*64];
    float w0 = cw[l+0], w1 = cw[l+1], w2 = cw[l+2], w3 = cw[l+3], w4 = cw[l+4];
    gx = fmaf(w0, p0.x, gx); gy = fmaf(w0, p0.y, gy);
    gx = fmaf(w1, p1.x, gx); gy = fmaf(w1, p1.y, gy);
    gx = fmaf(w2, p2.x, gx); gy = fmaf(w2, p2.y, gy);
    gx = fmaf(w3, p3.x, gx); gy = fmaf(w3, p3.y, gy);
    gx = fmaf(w4, p4.x, gx); gy = fmaf(w4, p4.y, gy);
  }
  if (lo){ sg2[2*lane] = gx; sg2[2*lane+1] = gy; }
  else   { sg3[2*lane] = gx; sg3[2*lane+1] = gy; }
  __syncthreads();
  if (d < 50){
    float s = 0.f;
    for (int k = 0; k < 128; ++k) s = fmaf(sg2[k], weight[k*50 + d], s);
    s += c1b[0];
    ssel[d] = s;
    out[(size_t)Bn + (size_t)b*100 + d] = s;
  } else if (d >= 64 && d < 114){
    int t = d - 64;
    float s = 0.f;
    for (int k = 0; k < 128; ++k) s = fmaf(sg3[k], weight2[k*50 + t], s);
    s += c2b[0];
    ssel[50 + t] = s;
    out[(size_t)Bn + (size_t)b*100 + 50 + t] = s;
  }
  __syncthreads();
  if (d < 5){
    float s = clsb[d];
    for (int j = 0; j < 100; ++j) s = fmaf(ssel[j], cls[j*5 + d], s);
    spre[d] = s;
  }
  __syncthreads();
  if (d == 0){
    int best = 0; float bv = spre[0];
    #pragma unroll
    for (int k = 1; k < 5; ++k) if (spre[k] > bv){ bv = spre[k]; best = k; }
    out[b] = (float)best;
  }
}

// ---------------------------------------------------------------------------
extern "C" void kernel_launch(void* const* d_in, const int* in_sizes, int n_in,
                              void* d_out, int out_size, void* d_ws, size_t ws_size,
                              hipStream_t stream) {
  const float* A1     = (const float*)d_in[0];
  const int*   rows   = (const int*)  d_in[1];
  const int*   cols   = (const int*)  d_in[2];
  const float* vals   = (const float*)d_in[3];
  const int*   bidx   = (const int*)  d_in[4];
  const float* raw_c  = (const float*)d_in[5];
  const float* nparam = (const float*)d_in[6];
  const float* Lin1   = (const float*)d_in[7];
  const float* Lin1_b = (const float*)d_in[8];
  const float* gc1_w  = (const float*)d_in[9];
  const float* gc1_b  = (const float*)d_in[10];
  const float* gc2_w  = (const float*)d_in[11];
  const float* gc2_b  = (const float*)d_in[12];
  const float* weight = (const float*)d_in[13];
  const float* weight2= (const float*)d_in[14];
  const float* c1w    = (const float*)d_in[15];
  const float* c1b    = (const float*)d_in[16];
  const float* c2w    = (const float*)d_in[17];
  const float* c2b    = (const float*)d_in[18];
  const float* cls    = (const float*)d_in[19];
  const float* clsb   = (const float*)d_in[20];

  int N  = in_sizes[0] / 129;
  int E  = in_sizes[1];
  int Bn = in_sizes[4] / 50;
  size_t NF = (size_t)N * 128;

  // workspace layout (region A: Lhi/Llo early, reused as fp32 Lx2 late)
  ushort_t* Lhi = (ushort_t*)d_ws;              // 2NF B
  ushort_t* Llo = Lhi + NF;                     // 2NF B
  float*    S0  = (float*)d_ws;                 // Lx2 fp32 (aliases Lhi/Llo)
  float*    S3  = (float*)(Llo + NF);           // loga1 fp32, 4NF B
  unsigned int* Hb   = (unsigned int*)(S3 + NF);  // h1/h2 bf16, 2NF B
  unsigned int* X1hi = Hb + NF/2;               // Lx1 hi, 2NF B
  unsigned int* X1lo = X1hi + NF/2;             // Lx1 lo, 2NF B
  ushort_t* Wb = (ushort_t*)(X1lo + NF/2);      // 6 x 16384 ushorts
  ushort_t* W1h = Wb,           *W1l = Wb + 16384;
  ushort_t* W2h = Wb + 2*16384, *W2l = Wb + 3*16384;
  ushort_t* W3h = Wb + 4*16384, *W3l = Wb + 5*16384;
  int* cnt    = (int*)(Wb + 6*16384);
  int* off    = cnt + N;
  int* rnk    = off + N;
  int* bsum   = rnk + E;
  int2* ecv   = (int2*)(bsum + 4096);
  float* uu3  = (float*)(ecv + E);

  int rowBlocks  = (N + 3) / 4;
  int G = (N + 256*SCAN_ITEMS - 1) / (256*SCAN_ITEMS);
  int eBlocks4 = (E/4 + 255) / 256 + 1;
  int mBlocks = 512;                 // 2 blocks/CU (64 KB LDS each)
  int nWaves  = mBlocks * 4;

  stage_a<<<(int)((NF + 255)/256), 256, 0, stream>>>(A1, Lhi, Llo, cnt,
                                                     Lin1_b, gc1_b, gc2_b, uu3, N);
  split_w<<<64, 256, 0, stream>>>(Lin1 + 128, W1h, W1l);
  split_w<<<64, 256, 0, stream>>>(gc1_w + 128, W2h, W2l);
  split_w<<<64, 256, 0, stream>>>(gc2_w, W3h, W3l);

  hist_k<<<eBlocks4, 256, 0, stream>>>(rows, cnt, rnk, E);
  scan1<<<G, 256, 0, stream>>>(cnt, off, bsum, N);
  scan2<<<1, 64, 0, stream>>>(bsum, G);
  scan3<<<(N+255)/256, 256, 0, stream>>>(off, bsum, N);
  fill_k<<<eBlocks4, 256, 0, stream>>>(rows, cols, vals, off, rnk, ecv, E);

  // loga1 = chain(L@Lin1[1:,:], lin1_b) -> S3 (fp32)
  mfma_chain<<<mBlocks, 256, 0, stream>>>(Lhi, Llo, W1h, W1l, Lin1_b, uu3, 0, raw_c,
                                          S3, (unsigned int*)nullptr, 0, N, nWaves);
  // h1 = chain(L@gc1_w[1:,:], gc1_b) -> Hb (bf16)
  mfma_chain<<<mBlocks, 256, 0, stream>>>(Lhi, Llo, W2h, W2l, gc1_b, uu3, 1, raw_c,
                                          (float*)nullptr, Hb, 1, N, nWaves);
  seg_x1<<<rowBlocks, 256, 0, stream>>>(Hb, off, cnt, ecv, S3, nparam, X1hi, X1lo, N);
  // h2 = chain(Lx1@gc2_w, gc2_b) -> Hb (bf16)
  mfma_chain<<<mBlocks, 256, 0, stream>>>((const ushort_t*)X1hi, (const ushort_t*)X1lo,
                                          W3h, W3l, gc2_b, uu3, 2, raw_c,
                                          (float*)nullptr, Hb, 1, N, nWaves);
  seg_x2<<<rowBlocks, 256, 0, stream>>>(Hb, off, cnt, ecv, S0, N);  // Lx2 -> S0
  batch_head<<<Bn, 128, 0, stream>>>(S0, S3, bidx, weight, weight2, c1w, c1b,
                                     c2w, c2b, cls, clsb, (float*)d_out, Bn);
}